// Round 1
// baseline (11995.071 us; speedup 1.0000x reference)
//
#include <hip/hip_runtime.h>
#include <cstdint>
#include <cstddef>

// ---- problem constants ----
#define BB    32
#define CC    384
#define NHH   12
#define HDD   32
#define WSS   7
#define HKK   8
#define NBB   2
#define HIDD  1536
#define NTT   50          // tokens per window (1 cls + 49 patch)
#define NWW   2048        // B*HK*HK windows
#define LDOUT 19200       // 50*384
#define N3    1152        // 3*C

static __device__ __forceinline__ float gelu_f(float x) {
    return 0.5f * x * (1.0f + erff(x * 0.70710678118654752440f));
}

// ---------------- pack / unpack ----------------
// out buffer layout: [win=2048][tok=50][c=384] fp32
// win = b*64 + hky*8 + hkx ; tok 0 = cls ; tok = 1 + wsy*7 + wsx

__global__ void pack_cls_kernel(const float* __restrict__ cls, float* __restrict__ out) {
    // grid: B*6 blocks; block handles (b, c0=cc*64), LDS transpose
    __shared__ float lds[64][65];
    int bid = blockIdx.x;
    int b = bid / 6, cc = bid % 6, c0 = cc * 64;
    int tid = threadIdx.x;
    for (int idx = tid; idx < 64 * 64; idx += 256) {
        int k = idx & 63, cl = idx >> 6;
        lds[cl][k] = cls[((size_t)b * CC + c0 + cl) * 64 + k];
    }
    __syncthreads();
    for (int idx = tid; idx < 64 * 64; idx += 256) {
        int cl = idx & 63, k = idx >> 6;
        out[(size_t)(b * 64 + k) * LDOUT + c0 + cl] = lds[cl][k];
    }
}

__global__ void pack_patch_kernel(const float* __restrict__ patch, float* __restrict__ out) {
    // grid: B*56*6 ; block = (b, y, c0)
    __shared__ float lds[64][57];
    int bid = blockIdx.x;
    int b = bid / 336, rem = bid % 336;
    int y = rem / 6, cc = rem % 6, c0 = cc * 64;
    int tid = threadIdx.x;
    for (int idx = tid; idx < 64 * 56; idx += 256) {
        int cl = idx / 56, x = idx % 56;
        lds[cl][x] = patch[(((size_t)b * CC + c0 + cl) * 56 + y) * 56 + x];
    }
    __syncthreads();
    int wsy = y % 7, hky = y / 7;
    for (int idx = tid; idx < 64 * 56; idx += 256) {
        int cl = idx & 63, x = idx >> 6;
        int tok = 1 + wsy * 7 + (x % 7);
        int win = b * 64 + hky * 8 + (x / 7);
        out[((size_t)win * NTT + tok) * CC + c0 + cl] = lds[cl][x];
    }
}

__global__ void unpack_cls_kernel(const float* __restrict__ out, float* __restrict__ cls_out) {
    __shared__ float lds[64][65];
    int bid = blockIdx.x;
    int b = bid / 6, cc = bid % 6, c0 = cc * 64;
    int tid = threadIdx.x;
    for (int idx = tid; idx < 64 * 64; idx += 256) {
        int cl = idx & 63, k = idx >> 6;
        lds[cl][k] = out[(size_t)(b * 64 + k) * LDOUT + c0 + cl];
    }
    __syncthreads();
    for (int idx = tid; idx < 64 * 64; idx += 256) {
        int k = idx & 63, cl = idx >> 6;
        cls_out[((size_t)b * CC + c0 + cl) * 64 + k] = lds[cl][k];
    }
}

__global__ void unpack_patch_kernel(const float* __restrict__ out, float* __restrict__ patch_out) {
    __shared__ float lds[64][57];
    int bid = blockIdx.x;
    int b = bid / 336, rem = bid % 336;
    int y = rem / 6, cc = rem % 6, c0 = cc * 64;
    int tid = threadIdx.x;
    int wsy = y % 7, hky = y / 7;
    for (int idx = tid; idx < 64 * 56; idx += 256) {
        int cl = idx & 63, x = idx >> 6;
        int tok = 1 + wsy * 7 + (x % 7);
        int win = b * 64 + hky * 8 + (x / 7);
        lds[cl][x] = out[((size_t)win * NTT + tok) * CC + c0 + cl];
    }
    __syncthreads();
    for (int idx = tid; idx < 64 * 56; idx += 256) {
        int cl = idx / 56, x = idx % 56;
        patch_out[((size_t)b * CC + c0 + cl) * 3136 + y * 56 + x] = lds[cl][x];
    }
}

// ---------------- LayerNorm ----------------
// one wave per row of 384; block = 4 rows
__global__ void ln_kernel(const float* __restrict__ x, int ldx,
                          const float* __restrict__ w, const float* __restrict__ b,
                          float* __restrict__ y, int ldy, int M) {
    int wave = threadIdx.x >> 6, lane = threadIdx.x & 63;
    int row = blockIdx.x * 4 + wave;
    if (row >= M) return;
    const float* xr = x + (size_t)row * ldx;
    float vals[6];
    float s = 0.f;
#pragma unroll
    for (int j = 0; j < 6; ++j) { vals[j] = xr[lane + j * 64]; s += vals[j]; }
#pragma unroll
    for (int off = 32; off > 0; off >>= 1) s += __shfl_xor(s, off);
    float mean = s * (1.0f / 384.0f);
    float vs = 0.f;
#pragma unroll
    for (int j = 0; j < 6; ++j) { float d = vals[j] - mean; vs += d * d; }
#pragma unroll
    for (int off = 32; off > 0; off >>= 1) vs += __shfl_xor(vs, off);
    float inv = rsqrtf(vs * (1.0f / 384.0f) + 1e-6f);
    float* yr = y + (size_t)row * ldy;
#pragma unroll
    for (int j = 0; j < 6; ++j) {
        int c = lane + j * 64;
        yr[c] = (vals[j] - mean) * inv * w[c] + b[c];
    }
}

// ---------------- GEMM: Y = X[M,K] @ W[N,K]^T (+bias)(+gelu)(+=Y) ----------------
template <int BIAS, int GELU, int ACC>
__global__ __launch_bounds__(256) void gemm_kernel(
    const float* __restrict__ X, int ldx,
    const float* __restrict__ W,
    const float* __restrict__ bias,
    float* __restrict__ Y, int ldy,
    int M, int N, int K) {
    __shared__ float As[16][68];
    __shared__ float Bs[16][68];
    int tid = threadIdx.x;
    int tx = tid & 15, ty = tid >> 4;
    int row0 = blockIdx.y * 64, col0 = blockIdx.x * 64;
    int lr = tid >> 2;
    int lk = (tid & 3) * 4;
    const float* Xp = X + (size_t)(row0 + lr) * ldx + lk;
    const float* Wp = W + (size_t)(col0 + lr) * K + lk;
    float acc[4][4] = {};
    for (int k0 = 0; k0 < K; k0 += 16) {
        float4 av = *(const float4*)(Xp + k0);
        float4 bv = *(const float4*)(Wp + k0);
        As[lk + 0][lr] = av.x; As[lk + 1][lr] = av.y; As[lk + 2][lr] = av.z; As[lk + 3][lr] = av.w;
        Bs[lk + 0][lr] = bv.x; Bs[lk + 1][lr] = bv.y; Bs[lk + 2][lr] = bv.z; Bs[lk + 3][lr] = bv.w;
        __syncthreads();
#pragma unroll
        for (int kk = 0; kk < 16; ++kk) {
            float4 a4 = *(const float4*)&As[kk][ty * 4];
            float4 b4 = *(const float4*)&Bs[kk][tx * 4];
            float a[4] = {a4.x, a4.y, a4.z, a4.w};
            float bb[4] = {b4.x, b4.y, b4.z, b4.w};
#pragma unroll
            for (int i = 0; i < 4; ++i)
#pragma unroll
                for (int j = 0; j < 4; ++j)
                    acc[i][j] = fmaf(a[i], bb[j], acc[i][j]);
        }
        __syncthreads();
    }
    float bv4[4] = {0.f, 0.f, 0.f, 0.f};
    if (BIAS) {
#pragma unroll
        for (int j = 0; j < 4; ++j) bv4[j] = bias[col0 + tx * 4 + j];
    }
#pragma unroll
    for (int i = 0; i < 4; ++i) {
        float r[4];
#pragma unroll
        for (int j = 0; j < 4; ++j) {
            r[j] = acc[i][j];
            if (BIAS) r[j] += bv4[j];
            if (GELU) r[j] = gelu_f(r[j]);
        }
        float* yp = Y + (size_t)(row0 + ty * 4 + i) * ldy + col0 + tx * 4;
        if (ACC) {
            float4 o = *(const float4*)yp;
            r[0] += o.x; r[1] += o.y; r[2] += o.z; r[3] += o.w;
        }
        float4 st = {r[0], r[1], r[2], r[3]};
        *(float4*)yp = st;
    }
}

// ---------------- attention: one block per (problem p, head h) ----------------
// qkv rows: (p*T + t) * 1152, col = s*384 + h*32 + d ; o rows: (p*T + t)*384 + h*32 + d
__global__ __launch_bounds__(256) void attn_kernel(
    const float* __restrict__ qkv,
    const float* __restrict__ relpos,   // base for this block i: [NH][169], or nullptr
    float* __restrict__ o,
    int T, float scale) {
    __shared__ float q[64][33], k[64][33], v[64][33];
    __shared__ float S[64][65];
    int p = blockIdx.x, h = blockIdx.y;
    int tid = threadIdx.x;
    for (int idx = tid; idx < T * 32; idx += 256) {
        int t = idx >> 5, d = idx & 31;
        const float* row = qkv + ((size_t)p * T + t) * N3 + h * 32 + d;
        q[t][d] = row[0];
        k[t][d] = row[384];
        v[t][d] = row[768];
    }
    __syncthreads();
    for (int idx = tid; idx < T * T; idx += 256) {
        int qt = idx / T, kt = idx % T;
        float acc = 0.f;
#pragma unroll
        for (int d = 0; d < 32; ++d) acc = fmaf(q[qt][d], k[kt][d], acc);
        acc *= scale;
        if (relpos != nullptr && qt > 0 && kt > 0) {
            int qp = qt - 1, kp = kt - 1;
            int qy = qp / 7, qx = qp - qy * 7;
            int ky = kp / 7, kx = kp - ky * 7;
            int ridx = ((ky - qy + 16) % 13) * 13 + ((kx - qx + 16) % 13);
            acc += relpos[h * 169 + ridx];
        }
        S[qt][kt] = acc;
    }
    __syncthreads();
    if (tid < T) {
        float m = -1e30f;
        for (int j = 0; j < T; ++j) m = fmaxf(m, S[tid][j]);
        float sum = 0.f;
        for (int j = 0; j < T; ++j) {
            float e = __expf(S[tid][j] - m);
            S[tid][j] = e;
            sum += e;
        }
        float inv = 1.0f / sum;
        for (int j = 0; j < T; ++j) S[tid][j] *= inv;
    }
    __syncthreads();
    for (int idx = tid; idx < T * 32; idx += 256) {
        int t = idx >> 5, d = idx & 31;
        float acc = 0.f;
        for (int j = 0; j < T; ++j) acc = fmaf(S[t][j], v[j][d], acc);
        o[((size_t)p * T + t) * CC + h * 32 + d] = acc;
    }
}

// ---------------- host ----------------
extern "C" void kernel_launch(void* const* d_in, const int* in_sizes, int n_in,
                              void* d_out, int out_size, void* d_ws, size_t ws_size,
                              hipStream_t stream) {
    const float* cls_in   = (const float*)d_in[0];
    const float* patch_in = (const float*)d_in[1];
    const float* qkv_w    = (const float*)d_in[2];
    const float* qkv_b    = (const float*)d_in[3];
    const float* proj_w   = (const float*)d_in[4];
    const float* proj_b   = (const float*)d_in[5];
    const float* rel_pos  = (const float*)d_in[6];
    const float* ln0w = (const float*)d_in[7];
    const float* ln0b = (const float*)d_in[8];
    const float* ln1w = (const float*)d_in[9];
    const float* ln1b = (const float*)d_in[10];
    const float* ln2w = (const float*)d_in[11];
    const float* ln2b = (const float*)d_in[12];
    const float* w1 = (const float*)d_in[13];
    const float* b1 = (const float*)d_in[14];
    const float* w2 = (const float*)d_in[15];
    const float* b2 = (const float*)d_in[16];

    float* OUT = (float*)d_ws;
    size_t avail = ws_size / 4;
    int cw = 2048;
    // per-window: X 19200 floats + Q 76800 floats
    while (cw > 64 && (size_t)39321600 + (size_t)cw * 96000 > avail) cw >>= 1;
    float* Xb = OUT + (size_t)39321600;
    float* Qb = Xb + (size_t)cw * 19200;
    const float scale = 0.17677669529663687f;

    pack_cls_kernel<<<dim3(BB * 6), dim3(256), 0, stream>>>(cls_in, OUT);
    pack_patch_kernel<<<dim3(BB * 56 * 6), dim3(256), 0, stream>>>(patch_in, OUT);

    for (int i = 0; i < NBB; ++i) {
        const float* qw = qkv_w + (size_t)i * N3 * CC;
        const float* qb = qkv_b + (size_t)i * N3;
        const float* pw = proj_w + (size_t)i * CC * CC;
        const float* pb = proj_b + (size_t)i * CC;
        const float* rp = rel_pos + (size_t)i * NHH * 169;
        const float* w1i = w1 + (size_t)i * HIDD * CC;
        const float* b1i = b1 + (size_t)i * HIDD;
        const float* w2i = w2 + (size_t)i * CC * HIDD;
        const float* b2i = b2 + (size_t)i * CC;

        // ---- stage A: cls-token attention across the 64 windows of each image ----
        ln_kernel<<<dim3(2048 / 4), dim3(256), 0, stream>>>(OUT, LDOUT, ln0w + i * CC, ln0b + i * CC, Xb, CC, 2048);
        gemm_kernel<1, 0, 0><<<dim3(N3 / 64, 2048 / 64), dim3(256), 0, stream>>>(
            Xb, CC, qw, qb, Qb, N3, 2048, N3, CC);
        attn_kernel<<<dim3(BB, NHH), dim3(256), 0, stream>>>(Qb, nullptr, Xb, 64, scale);
        gemm_kernel<1, 0, 1><<<dim3(CC / 64, 2048 / 64), dim3(256), 0, stream>>>(
            Xb, CC, pw, pb, OUT, LDOUT, 2048, CC, CC);

        // ---- stage B: windowed attention with rel-pos bias ----
        for (int w0 = 0; w0 < NWW; w0 += cw) {
            float* outc = OUT + (size_t)w0 * LDOUT;
            int Mr = cw * NTT;
            ln_kernel<<<dim3(Mr / 4), dim3(256), 0, stream>>>(outc, CC, ln1w + i * CC, ln1b + i * CC, Xb, CC, Mr);
            gemm_kernel<1, 0, 0><<<dim3(N3 / 64, Mr / 64), dim3(256), 0, stream>>>(
                Xb, CC, qw, qb, Qb, N3, Mr, N3, CC);
            attn_kernel<<<dim3(cw, NHH), dim3(256), 0, stream>>>(Qb, rp, Xb, NTT, scale);
            gemm_kernel<1, 0, 1><<<dim3(CC / 64, Mr / 64), dim3(256), 0, stream>>>(
                Xb, CC, pw, pb, outc, CC, Mr, CC, CC);
        }

        // ---- stage C: MLP ----
        for (int w0 = 0; w0 < NWW; w0 += cw) {
            float* outc = OUT + (size_t)w0 * LDOUT;
            int Mr = cw * NTT;
            ln_kernel<<<dim3(Mr / 4), dim3(256), 0, stream>>>(outc, CC, ln2w + i * CC, ln2b + i * CC, Xb, CC, Mr);
            gemm_kernel<1, 1, 0><<<dim3(HIDD / 64, Mr / 64), dim3(256), 0, stream>>>(
                Xb, CC, w1i, b1i, Qb, HIDD, Mr, HIDD, CC);
            gemm_kernel<1, 0, 1><<<dim3(CC / 64, Mr / 64), dim3(256), 0, stream>>>(
                Qb, HIDD, w2i, b2i, outc, CC, Mr, CC, HIDD);
        }
    }

    unpack_cls_kernel<<<dim3(BB * 6), dim3(256), 0, stream>>>(OUT, (float*)d_out);
    unpack_patch_kernel<<<dim3(BB * 56 * 6), dim3(256), 0, stream>>>(OUT, (float*)d_out + 786432);
}

// Round 2
// 3797.871 us; speedup vs baseline: 3.1584x; 3.1584x over previous
//
#include <hip/hip_runtime.h>
#include <hip/hip_bf16.h>
#include <cstdint>
#include <cstddef>

// ---- problem constants ----
#define BB    32
#define CC    384
#define NHH   12
#define HDD   32
#define WSS   7
#define HKK   8
#define NBB   2
#define HIDD  1536
#define NTT   50          // tokens per window (1 cls + 49 patch)
#define NWW   2048        // B*HK*HK windows
#define LDOUT 19200       // 50*384
#define N3    1152        // 3*C

typedef __attribute__((ext_vector_type(8))) short short8v;
typedef __attribute__((ext_vector_type(4))) float f32x4;

static __device__ __forceinline__ float gelu_f(float x) {
    return 0.5f * x * (1.0f + erff(x * 0.70710678118654752440f));
}

// ---------------- pack / unpack (unchanged, fp32) ----------------
__global__ void pack_cls_kernel(const float* __restrict__ cls, float* __restrict__ out) {
    __shared__ float lds[64][65];
    int bid = blockIdx.x;
    int b = bid / 6, cc = bid % 6, c0 = cc * 64;
    int tid = threadIdx.x;
    for (int idx = tid; idx < 64 * 64; idx += 256) {
        int k = idx & 63, cl = idx >> 6;
        lds[cl][k] = cls[((size_t)b * CC + c0 + cl) * 64 + k];
    }
    __syncthreads();
    for (int idx = tid; idx < 64 * 64; idx += 256) {
        int cl = idx & 63, k = idx >> 6;
        out[(size_t)(b * 64 + k) * LDOUT + c0 + cl] = lds[cl][k];
    }
}

__global__ void pack_patch_kernel(const float* __restrict__ patch, float* __restrict__ out) {
    __shared__ float lds[64][57];
    int bid = blockIdx.x;
    int b = bid / 336, rem = bid % 336;
    int y = rem / 6, cc = rem % 6, c0 = cc * 64;
    int tid = threadIdx.x;
    for (int idx = tid; idx < 64 * 56; idx += 256) {
        int cl = idx / 56, x = idx % 56;
        lds[cl][x] = patch[(((size_t)b * CC + c0 + cl) * 56 + y) * 56 + x];
    }
    __syncthreads();
    int wsy = y % 7, hky = y / 7;
    for (int idx = tid; idx < 64 * 56; idx += 256) {
        int cl = idx & 63, x = idx >> 6;
        int tok = 1 + wsy * 7 + (x % 7);
        int win = b * 64 + hky * 8 + (x / 7);
        out[((size_t)win * NTT + tok) * CC + c0 + cl] = lds[cl][x];
    }
}

__global__ void unpack_cls_kernel(const float* __restrict__ out, float* __restrict__ cls_out) {
    __shared__ float lds[64][65];
    int bid = blockIdx.x;
    int b = bid / 6, cc = bid % 6, c0 = cc * 64;
    int tid = threadIdx.x;
    for (int idx = tid; idx < 64 * 64; idx += 256) {
        int cl = idx & 63, k = idx >> 6;
        lds[cl][k] = out[(size_t)(b * 64 + k) * LDOUT + c0 + cl];
    }
    __syncthreads();
    for (int idx = tid; idx < 64 * 64; idx += 256) {
        int k = idx & 63, cl = idx >> 6;
        cls_out[((size_t)b * CC + c0 + cl) * 64 + k] = lds[cl][k];
    }
}

__global__ void unpack_patch_kernel(const float* __restrict__ out, float* __restrict__ patch_out) {
    __shared__ float lds[64][57];
    int bid = blockIdx.x;
    int b = bid / 336, rem = bid % 336;
    int y = rem / 6, cc = rem % 6, c0 = cc * 64;
    int tid = threadIdx.x;
    int wsy = y % 7, hky = y / 7;
    for (int idx = tid; idx < 64 * 56; idx += 256) {
        int cl = idx & 63, x = idx >> 6;
        int tok = 1 + wsy * 7 + (x % 7);
        int win = b * 64 + hky * 8 + (x / 7);
        lds[cl][x] = out[((size_t)win * NTT + tok) * CC + c0 + cl];
    }
    __syncthreads();
    for (int idx = tid; idx < 64 * 56; idx += 256) {
        int cl = idx / 56, x = idx % 56;
        patch_out[((size_t)b * CC + c0 + cl) * 3136 + y * 56 + x] = lds[cl][x];
    }
}

// ---------------- fp32 -> bf16 weight conversion ----------------
__global__ void f2bf_kernel(const float* __restrict__ in, __hip_bfloat16* __restrict__ out, int n) {
    int i = (blockIdx.x * 256 + threadIdx.x) * 4;
    if (i + 3 < n) {
        float4 v = *(const float4*)(in + i);
        out[i + 0] = __float2bfloat16(v.x);
        out[i + 1] = __float2bfloat16(v.y);
        out[i + 2] = __float2bfloat16(v.z);
        out[i + 3] = __float2bfloat16(v.w);
    } else {
        for (; i < n; ++i) out[i] = __float2bfloat16(in[i]);
    }
}

// ---------------- LayerNorm -> bf16 ----------------
__global__ void ln_kernel(const float* __restrict__ x, int ldx,
                          const float* __restrict__ w, const float* __restrict__ b,
                          __hip_bfloat16* __restrict__ y, int ldy, int M) {
    int wave = threadIdx.x >> 6, lane = threadIdx.x & 63;
    int row = blockIdx.x * 4 + wave;
    if (row >= M) return;
    const float* xr = x + (size_t)row * ldx;
    float vals[6];
    float s = 0.f;
#pragma unroll
    for (int j = 0; j < 6; ++j) { vals[j] = xr[lane + j * 64]; s += vals[j]; }
#pragma unroll
    for (int off = 32; off > 0; off >>= 1) s += __shfl_xor(s, off);
    float mean = s * (1.0f / 384.0f);
    float vs = 0.f;
#pragma unroll
    for (int j = 0; j < 6; ++j) { float d = vals[j] - mean; vs += d * d; }
#pragma unroll
    for (int off = 32; off > 0; off >>= 1) vs += __shfl_xor(vs, off);
    float inv = rsqrtf(vs * (1.0f / 384.0f) + 1e-6f);
    __hip_bfloat16* yr = y + (size_t)row * ldy;
#pragma unroll
    for (int j = 0; j < 6; ++j) {
        int c = lane + j * 64;
        yr[c] = __float2bfloat16((vals[j] - mean) * inv * w[c] + b[c]);
    }
}

// ---------------- bf16 MFMA GEMM: Y = A[M,K] @ W[N,K]^T ----------------
// 128x128 tile, 4 waves (2x2), each wave 64x64 = 4x4 fragments of 16x16, BK=32.
// A, W bf16; accum fp32. Epilogue: +bias, gelu, += fp32 Y or store bf16 Yb.
template <int BIAS, int GELU, int ACC, int OUTBF>
__global__ __launch_bounds__(256) void gemm_bf16_kernel(
    const __hip_bfloat16* __restrict__ A, int lda,
    const __hip_bfloat16* __restrict__ W,
    const float* __restrict__ bias,
    float* __restrict__ Y, int ldy,
    __hip_bfloat16* __restrict__ Yb, int ldyb,
    int M, int N, int K) {
    // rows padded to 40 bf16 (80B stride -> worst 2-way bank aliasing = free)
    __shared__ short As[128 * 40];
    __shared__ short Bs[128 * 40];
    int tid = threadIdx.x;
    int lane = tid & 63;
    int wid = tid >> 6;
    int wr = wid >> 1, wc = wid & 1;
    int row0 = blockIdx.y * 128, col0 = blockIdx.x * 128;

    // staging addressing: thread covers short8 at (row, k) twice (p=0,1)
    int srow = tid >> 2;             // 0..63
    int sk = (tid & 3) * 8;          // 0,8,16,24
    const short* Ag = (const short*)A + (size_t)(row0 + srow) * lda + sk;
    const short* Wg = (const short*)W + (size_t)(col0 + srow) * K + sk;
    size_t astep = (size_t)64 * lda;
    size_t wstep = (size_t)64 * K;

    f32x4 acc[4][4] = {};
    int frow_a = wr * 64 + (lane & 15);
    int frow_b = wc * 64 + (lane & 15);
    int fk = (lane >> 4) * 8;

    for (int k0 = 0; k0 < K; k0 += 32) {
        *(short8v*)&As[(srow)      * 40 + sk] = *(const short8v*)(Ag + k0);
        *(short8v*)&As[(srow + 64) * 40 + sk] = *(const short8v*)(Ag + astep + k0);
        *(short8v*)&Bs[(srow)      * 40 + sk] = *(const short8v*)(Wg + k0);
        *(short8v*)&Bs[(srow + 64) * 40 + sk] = *(const short8v*)(Wg + wstep + k0);
        __syncthreads();
        short8v a[4], b[4];
#pragma unroll
        for (int m = 0; m < 4; ++m) a[m] = *(const short8v*)&As[(frow_a + m * 16) * 40 + fk];
#pragma unroll
        for (int n = 0; n < 4; ++n) b[n] = *(const short8v*)&Bs[(frow_b + n * 16) * 40 + fk];
#pragma unroll
        for (int m = 0; m < 4; ++m)
#pragma unroll
            for (int n = 0; n < 4; ++n)
                acc[m][n] = __builtin_amdgcn_mfma_f32_16x16x32_bf16(a[m], b[n], acc[m][n], 0, 0, 0);
        __syncthreads();
    }

    // C/D layout: col = lane&15, row = (lane>>4)*4 + j
    int lr = (lane >> 4) * 4;
    int lc = lane & 15;
    int crow0 = row0 + wr * 64;
    int ccol0 = col0 + wc * 64;
#pragma unroll
    for (int n = 0; n < 4; ++n) {
        int c = ccol0 + n * 16 + lc;
        float bv = BIAS ? bias[c] : 0.0f;
#pragma unroll
        for (int m = 0; m < 4; ++m) {
#pragma unroll
            for (int j = 0; j < 4; ++j) {
                int r = crow0 + m * 16 + lr + j;
                float v = acc[m][n][j] + bv;
                if (GELU) v = gelu_f(v);
                if (OUTBF) {
                    Yb[(size_t)r * ldyb + c] = __float2bfloat16(v);
                } else {
                    float* yp = Y + (size_t)r * ldy + c;
                    if (ACC) v += *yp;
                    *yp = v;
                }
            }
        }
    }
}

// ---------------- attention: one block per (problem p, head h) ----------------
// qkv rows fp32: (p*T + t) * 1152, col = s*384 + h*32 + d ; o rows bf16: (p*T+t)*384 + h*32 + d
__global__ __launch_bounds__(256) void attn_kernel(
    const float* __restrict__ qkv,
    const float* __restrict__ relpos,   // base for this block i: [NH][169], or nullptr
    __hip_bfloat16* __restrict__ o,
    int T, float scale) {
    __shared__ float q[64][33], k[64][33], v[64][33];
    __shared__ float S[64][65];
    int p = blockIdx.x, h = blockIdx.y;
    int tid = threadIdx.x;
    for (int idx = tid; idx < T * 32; idx += 256) {
        int t = idx >> 5, d = idx & 31;
        const float* row = qkv + ((size_t)p * T + t) * N3 + h * 32 + d;
        q[t][d] = row[0];
        k[t][d] = row[384];
        v[t][d] = row[768];
    }
    __syncthreads();
    for (int idx = tid; idx < T * T; idx += 256) {
        int qt = idx / T, kt = idx % T;
        float acc = 0.f;
#pragma unroll
        for (int d = 0; d < 32; ++d) acc = fmaf(q[qt][d], k[kt][d], acc);
        acc *= scale;
        if (relpos != nullptr && qt > 0 && kt > 0) {
            int qp = qt - 1, kp = kt - 1;
            int qy = qp / 7, qx = qp - qy * 7;
            int ky = kp / 7, kx = kp - ky * 7;
            int ridx = ((ky - qy + 16) % 13) * 13 + ((kx - qx + 16) % 13);
            acc += relpos[h * 169 + ridx];
        }
        S[qt][kt] = acc;
    }
    __syncthreads();
    if (tid < T) {
        float m = -1e30f;
        for (int j = 0; j < T; ++j) m = fmaxf(m, S[tid][j]);
        float sum = 0.f;
        for (int j = 0; j < T; ++j) {
            float e = __expf(S[tid][j] - m);
            S[tid][j] = e;
            sum += e;
        }
        float inv = 1.0f / sum;
        for (int j = 0; j < T; ++j) S[tid][j] *= inv;
    }
    __syncthreads();
    for (int idx = tid; idx < T * 32; idx += 256) {
        int t = idx >> 5, d = idx & 31;
        float acc = 0.f;
        for (int j = 0; j < T; ++j) acc = fmaf(S[t][j], v[j][d], acc);
        o[((size_t)p * T + t) * CC + h * 32 + d] = __float2bfloat16(acc);
    }
}

// ---------------- host ----------------
extern "C" void kernel_launch(void* const* d_in, const int* in_sizes, int n_in,
                              void* d_out, int out_size, void* d_ws, size_t ws_size,
                              hipStream_t stream) {
    const float* cls_in   = (const float*)d_in[0];
    const float* patch_in = (const float*)d_in[1];
    const float* qkv_w    = (const float*)d_in[2];
    const float* qkv_b    = (const float*)d_in[3];
    const float* proj_w   = (const float*)d_in[4];
    const float* proj_b   = (const float*)d_in[5];
    const float* rel_pos  = (const float*)d_in[6];
    const float* ln0w = (const float*)d_in[7];
    const float* ln0b = (const float*)d_in[8];
    const float* ln1w = (const float*)d_in[9];
    const float* ln1b = (const float*)d_in[10];
    const float* ln2w = (const float*)d_in[11];
    const float* ln2b = (const float*)d_in[12];
    const float* w1 = (const float*)d_in[13];
    const float* b1 = (const float*)d_in[14];
    const float* w2 = (const float*)d_in[15];
    const float* b2 = (const float*)d_in[16];

    float* OUT = (float*)d_ws;
    size_t avail = ws_size / 4;

    // bf16 weights region (in f32-slot units: 3,538,944 bf16 = 1,769,472 f32 slots)
    const size_t OUT_F = 39321600;          // 2048*50*384
    const size_t WB_F  = 1769472;
    __hip_bfloat16* WB = (__hip_bfloat16*)(OUT + OUT_F);
    __hip_bfloat16* qwb = WB;                                   // 2*1152*384 = 884736
    __hip_bfloat16* pwb = WB + 884736;                          // 2*384*384  = 294912
    __hip_bfloat16* w1b = WB + 1179648;                         // 2*1536*384 = 1179648
    __hip_bfloat16* w2b = WB + 2359296;                         // 2*384*1536 = 1179648

    int cw = 2048;
    // per-window f32 slots: Xb bf16 50*384 -> 9600 ; Qb f32 50*1152 -> 57600
    while (cw > 64 && OUT_F + WB_F + (size_t)cw * 67200 > avail) cw >>= 1;
    float* fbase = OUT + OUT_F + WB_F;
    __hip_bfloat16* Xb = (__hip_bfloat16*)fbase;
    float* Qb = fbase + (size_t)cw * 9600;
    __hip_bfloat16* Hb = (__hip_bfloat16*)Qb;   // MLP hidden reuses Qb as bf16
    const float scale = 0.17677669529663687f;

    // convert weights to bf16
    f2bf_kernel<<<dim3((884736 / 4 + 255) / 256), dim3(256), 0, stream>>>(qkv_w, qwb, 884736);
    f2bf_kernel<<<dim3((294912 / 4 + 255) / 256), dim3(256), 0, stream>>>(proj_w, pwb, 294912);
    f2bf_kernel<<<dim3((1179648 / 4 + 255) / 256), dim3(256), 0, stream>>>(w1, w1b, 1179648);
    f2bf_kernel<<<dim3((1179648 / 4 + 255) / 256), dim3(256), 0, stream>>>(w2, w2b, 1179648);

    pack_cls_kernel<<<dim3(BB * 6), dim3(256), 0, stream>>>(cls_in, OUT);
    pack_patch_kernel<<<dim3(BB * 56 * 6), dim3(256), 0, stream>>>(patch_in, OUT);

    for (int i = 0; i < NBB; ++i) {
        const __hip_bfloat16* qw = qwb + (size_t)i * N3 * CC;
        const float* qb = qkv_b + (size_t)i * N3;
        const __hip_bfloat16* pw = pwb + (size_t)i * CC * CC;
        const float* pb = proj_b + (size_t)i * CC;
        const float* rp = rel_pos + (size_t)i * NHH * 169;
        const __hip_bfloat16* w1i = w1b + (size_t)i * HIDD * CC;
        const float* b1i = b1 + (size_t)i * HIDD;
        const __hip_bfloat16* w2i = w2b + (size_t)i * CC * HIDD;
        const float* b2i = b2 + (size_t)i * CC;

        // ---- stage A: cls-token attention across the 64 windows of each image ----
        ln_kernel<<<dim3(2048 / 4), dim3(256), 0, stream>>>(OUT, LDOUT, ln0w + i * CC, ln0b + i * CC, Xb, CC, 2048);
        gemm_bf16_kernel<1, 0, 0, 0><<<dim3(N3 / 128, 2048 / 128), dim3(256), 0, stream>>>(
            Xb, CC, qw, qb, Qb, N3, nullptr, 0, 2048, N3, CC);
        attn_kernel<<<dim3(BB, NHH), dim3(256), 0, stream>>>(Qb, nullptr, Xb, 64, scale);
        gemm_bf16_kernel<1, 0, 1, 0><<<dim3(CC / 128, 2048 / 128), dim3(256), 0, stream>>>(
            Xb, CC, pw, pb, OUT, LDOUT, nullptr, 0, 2048, CC, CC);

        // ---- stage B: windowed attention with rel-pos bias ----
        for (int w0 = 0; w0 < NWW; w0 += cw) {
            float* outc = OUT + (size_t)w0 * LDOUT;
            int Mr = cw * NTT;
            ln_kernel<<<dim3(Mr / 4), dim3(256), 0, stream>>>(outc, CC, ln1w + i * CC, ln1b + i * CC, Xb, CC, Mr);
            gemm_bf16_kernel<1, 0, 0, 0><<<dim3(N3 / 128, Mr / 128), dim3(256), 0, stream>>>(
                Xb, CC, qw, qb, Qb, N3, nullptr, 0, Mr, N3, CC);
            attn_kernel<<<dim3(cw, NHH), dim3(256), 0, stream>>>(Qb, rp, Xb, NTT, scale);
            gemm_bf16_kernel<1, 0, 1, 0><<<dim3(CC / 128, Mr / 128), dim3(256), 0, stream>>>(
                Xb, CC, pw, pb, outc, CC, nullptr, 0, Mr, CC, CC);
        }

        // ---- stage C: MLP ----
        for (int w0 = 0; w0 < NWW; w0 += cw) {
            float* outc = OUT + (size_t)w0 * LDOUT;
            int Mr = cw * NTT;
            ln_kernel<<<dim3(Mr / 4), dim3(256), 0, stream>>>(outc, CC, ln2w + i * CC, ln2b + i * CC, Xb, CC, Mr);
            gemm_bf16_kernel<1, 1, 0, 1><<<dim3(HIDD / 128, Mr / 128), dim3(256), 0, stream>>>(
                Xb, CC, w1i, b1i, nullptr, 0, Hb, HIDD, Mr, HIDD, CC);
            gemm_bf16_kernel<1, 0, 1, 0><<<dim3(CC / 128, Mr / 128), dim3(256), 0, stream>>>(
                Hb, HIDD, w2i, b2i, outc, CC, nullptr, 0, Mr, CC, HIDD);
        }
    }

    unpack_cls_kernel<<<dim3(BB * 6), dim3(256), 0, stream>>>(OUT, (float*)d_out);
    unpack_patch_kernel<<<dim3(BB * 56 * 6), dim3(256), 0, stream>>>(OUT, (float*)d_out + 786432);
}

// Round 3
// 3223.954 us; speedup vs baseline: 3.7206x; 1.1780x over previous
//
#include <hip/hip_runtime.h>
#include <hip/hip_bf16.h>
#include <cstdint>
#include <cstddef>

// ---- problem constants ----
#define BB    32
#define CC    384
#define NHH   12
#define HDD   32
#define WSS   7
#define HKK   8
#define NBB   2
#define HIDD  1536
#define NTT   50          // tokens per window (1 cls + 49 patch)
#define NWW   2048        // B*HK*HK windows
#define LDOUT 19200       // 50*384
#define N3    1152        // 3*C

typedef __attribute__((ext_vector_type(8))) short short8v;
typedef __attribute__((ext_vector_type(4))) float f32x4;

static __device__ __forceinline__ float gelu_f(float x) {
    return 0.5f * x * (1.0f + erff(x * 0.70710678118654752440f));
}

static __device__ __forceinline__ short bf16s(float x) {
    __hip_bfloat16 b = __float2bfloat16(x);
    return *(short*)&b;
}

// ---------------- pack / unpack (fp32) ----------------
__global__ void pack_cls_kernel(const float* __restrict__ cls, float* __restrict__ out) {
    __shared__ float lds[64][65];
    int bid = blockIdx.x;
    int b = bid / 6, cc = bid % 6, c0 = cc * 64;
    int tid = threadIdx.x;
    for (int idx = tid; idx < 64 * 64; idx += 256) {
        int k = idx & 63, cl = idx >> 6;
        lds[cl][k] = cls[((size_t)b * CC + c0 + cl) * 64 + k];
    }
    __syncthreads();
    for (int idx = tid; idx < 64 * 64; idx += 256) {
        int cl = idx & 63, k = idx >> 6;
        out[(size_t)(b * 64 + k) * LDOUT + c0 + cl] = lds[cl][k];
    }
}

__global__ void pack_patch_kernel(const float* __restrict__ patch, float* __restrict__ out) {
    __shared__ float lds[64][57];
    int bid = blockIdx.x;
    int b = bid / 336, rem = bid % 336;
    int y = rem / 6, cc = rem % 6, c0 = cc * 64;
    int tid = threadIdx.x;
    for (int idx = tid; idx < 64 * 56; idx += 256) {
        int cl = idx / 56, x = idx % 56;
        lds[cl][x] = patch[(((size_t)b * CC + c0 + cl) * 56 + y) * 56 + x];
    }
    __syncthreads();
    int wsy = y % 7, hky = y / 7;
    for (int idx = tid; idx < 64 * 56; idx += 256) {
        int cl = idx & 63, x = idx >> 6;
        int tok = 1 + wsy * 7 + (x % 7);
        int win = b * 64 + hky * 8 + (x / 7);
        out[((size_t)win * NTT + tok) * CC + c0 + cl] = lds[cl][x];
    }
}

__global__ void unpack_cls_kernel(const float* __restrict__ out, float* __restrict__ cls_out) {
    __shared__ float lds[64][65];
    int bid = blockIdx.x;
    int b = bid / 6, cc = bid % 6, c0 = cc * 64;
    int tid = threadIdx.x;
    for (int idx = tid; idx < 64 * 64; idx += 256) {
        int cl = idx & 63, k = idx >> 6;
        lds[cl][k] = out[(size_t)(b * 64 + k) * LDOUT + c0 + cl];
    }
    __syncthreads();
    for (int idx = tid; idx < 64 * 64; idx += 256) {
        int k = idx & 63, cl = idx >> 6;
        cls_out[((size_t)b * CC + c0 + cl) * 64 + k] = lds[cl][k];
    }
}

__global__ void unpack_patch_kernel(const float* __restrict__ out, float* __restrict__ patch_out) {
    __shared__ float lds[64][57];
    int bid = blockIdx.x;
    int b = bid / 336, rem = bid % 336;
    int y = rem / 6, cc = rem % 6, c0 = cc * 64;
    int tid = threadIdx.x;
    int wsy = y % 7, hky = y / 7;
    for (int idx = tid; idx < 64 * 56; idx += 256) {
        int cl = idx & 63, x = idx >> 6;
        int tok = 1 + wsy * 7 + (x % 7);
        int win = b * 64 + hky * 8 + (x / 7);
        lds[cl][x] = out[((size_t)win * NTT + tok) * CC + c0 + cl];
    }
    __syncthreads();
    for (int idx = tid; idx < 64 * 56; idx += 256) {
        int cl = idx / 56, x = idx % 56;
        patch_out[((size_t)b * CC + c0 + cl) * 3136 + y * 56 + x] = lds[cl][x];
    }
}

// ---------------- fp32 -> bf16 weight conversion ----------------
__global__ void f2bf_kernel(const float* __restrict__ in, __hip_bfloat16* __restrict__ out, int n) {
    int i = (blockIdx.x * 256 + threadIdx.x) * 4;
    if (i + 3 < n) {
        float4 v = *(const float4*)(in + i);
        out[i + 0] = __float2bfloat16(v.x);
        out[i + 1] = __float2bfloat16(v.y);
        out[i + 2] = __float2bfloat16(v.z);
        out[i + 3] = __float2bfloat16(v.w);
    } else {
        for (; i < n; ++i) out[i] = __float2bfloat16(in[i]);
    }
}

// ---------------- rel-pos bias table: [12][64][64] fp32, zero-padded ----------------
__global__ void bias_precompute_kernel(const float* __restrict__ rp, float* __restrict__ biasT) {
    int h = blockIdx.x;
    for (int idx = threadIdx.x; idx < 4096; idx += 256) {
        int qt = idx >> 6, kt = idx & 63;
        float v = 0.f;
        if (qt >= 1 && qt < NTT && kt >= 1 && kt < NTT) {
            int qp = qt - 1, kp = kt - 1;
            int qy = qp / 7, qx = qp - qy * 7;
            int ky = kp / 7, kx = kp - ky * 7;
            int ridx = ((ky - qy + 16) % 13) * 13 + ((kx - qx + 16) % 13);
            v = rp[h * 169 + ridx];
        }
        biasT[h * 4096 + idx] = v;
    }
}

// ---------------- LayerNorm -> bf16 ----------------
__global__ void ln_kernel(const float* __restrict__ x, int ldx,
                          const float* __restrict__ w, const float* __restrict__ b,
                          __hip_bfloat16* __restrict__ y, int ldy, int M) {
    int wave = threadIdx.x >> 6, lane = threadIdx.x & 63;
    int row = blockIdx.x * 4 + wave;
    if (row >= M) return;
    const float* xr = x + (size_t)row * ldx;
    float vals[6];
    float s = 0.f;
#pragma unroll
    for (int j = 0; j < 6; ++j) { vals[j] = xr[lane + j * 64]; s += vals[j]; }
#pragma unroll
    for (int off = 32; off > 0; off >>= 1) s += __shfl_xor(s, off);
    float mean = s * (1.0f / 384.0f);
    float vs = 0.f;
#pragma unroll
    for (int j = 0; j < 6; ++j) { float d = vals[j] - mean; vs += d * d; }
#pragma unroll
    for (int off = 32; off > 0; off >>= 1) vs += __shfl_xor(vs, off);
    float inv = rsqrtf(vs * (1.0f / 384.0f) + 1e-6f);
    __hip_bfloat16* yr = y + (size_t)row * ldy;
#pragma unroll
    for (int j = 0; j < 6; ++j) {
        int c = lane + j * 64;
        yr[c] = __float2bfloat16((vals[j] - mean) * inv * w[c] + b[c]);
    }
}

// ---------------- bf16 MFMA GEMM: Y = A[M,K] @ W[N,K]^T ----------------
template <int BIAS, int GELU, int ACC, int OUTBF>
__global__ __launch_bounds__(256) void gemm_bf16_kernel(
    const __hip_bfloat16* __restrict__ A, int lda,
    const __hip_bfloat16* __restrict__ W,
    const float* __restrict__ bias,
    float* __restrict__ Y, int ldy,
    __hip_bfloat16* __restrict__ Yb, int ldyb,
    int M, int N, int K) {
    __shared__ short As[128 * 40];
    __shared__ short Bs[128 * 40];
    int tid = threadIdx.x;
    int lane = tid & 63;
    int wid = tid >> 6;
    int wr = wid >> 1, wc = wid & 1;
    int row0 = blockIdx.y * 128, col0 = blockIdx.x * 128;

    int srow = tid >> 2;             // 0..63
    int sk = (tid & 3) * 8;          // 0,8,16,24
    const short* Ag = (const short*)A + (size_t)(row0 + srow) * lda + sk;
    const short* Wg = (const short*)W + (size_t)(col0 + srow) * K + sk;
    size_t astep = (size_t)64 * lda;
    size_t wstep = (size_t)64 * K;

    f32x4 acc[4][4] = {};
    int frow_a = wr * 64 + (lane & 15);
    int frow_b = wc * 64 + (lane & 15);
    int fk = (lane >> 4) * 8;

    for (int k0 = 0; k0 < K; k0 += 32) {
        *(short8v*)&As[(srow)      * 40 + sk] = *(const short8v*)(Ag + k0);
        *(short8v*)&As[(srow + 64) * 40 + sk] = *(const short8v*)(Ag + astep + k0);
        *(short8v*)&Bs[(srow)      * 40 + sk] = *(const short8v*)(Wg + k0);
        *(short8v*)&Bs[(srow + 64) * 40 + sk] = *(const short8v*)(Wg + wstep + k0);
        __syncthreads();
        short8v a[4], b[4];
#pragma unroll
        for (int m = 0; m < 4; ++m) a[m] = *(const short8v*)&As[(frow_a + m * 16) * 40 + fk];
#pragma unroll
        for (int n = 0; n < 4; ++n) b[n] = *(const short8v*)&Bs[(frow_b + n * 16) * 40 + fk];
#pragma unroll
        for (int m = 0; m < 4; ++m)
#pragma unroll
            for (int n = 0; n < 4; ++n)
                acc[m][n] = __builtin_amdgcn_mfma_f32_16x16x32_bf16(a[m], b[n], acc[m][n], 0, 0, 0);
        __syncthreads();
    }

    int lr = (lane >> 4) * 4;
    int lc = lane & 15;
    int crow0 = row0 + wr * 64;
    int ccol0 = col0 + wc * 64;
#pragma unroll
    for (int n = 0; n < 4; ++n) {
        int c = ccol0 + n * 16 + lc;
        float bv = BIAS ? bias[c] : 0.0f;
#pragma unroll
        for (int m = 0; m < 4; ++m) {
#pragma unroll
            for (int j = 0; j < 4; ++j) {
                int r = crow0 + m * 16 + lr + j;
                float v = acc[m][n][j] + bv;
                if (GELU) v = gelu_f(v);
                if (OUTBF) {
                    Yb[(size_t)r * ldyb + c] = __float2bfloat16(v);
                } else {
                    float* yp = Y + (size_t)r * ldy + c;
                    if (ACC) v += *yp;
                    *yp = v;
                }
            }
        }
    }
}

// ---------------- MFMA attention ----------------
// block = (window p, head-group hg of 4); wave wv handles head h = hg*4+wv.
// qkv bf16 [P*T][1152]; biasT fp32 [12][64][64] or nullptr; o bf16 [P*T][384].
__global__ __launch_bounds__(256) void attn_mfma_kernel(
    const __hip_bfloat16* __restrict__ qkv,
    const float* __restrict__ biasT,
    __hip_bfloat16* __restrict__ o,
    int T, float scale) {
    __shared__ __align__(16) short Vt[4][32][72];   // [head][d][kt] transposed V
    __shared__ __align__(16) short Pl[4][64][72];   // per-wave P (bf16)
    const int tid = threadIdx.x, lane = tid & 63, wv = tid >> 6;
    const int p = blockIdx.x, hg = blockIdx.y;
    const int h = hg * 4 + wv;
    const short* q_base = (const short*)qkv + (size_t)p * T * N3;

    // zero Vt (covers kt >= T pad), then stage V transposed
    for (int idx = tid; idx < 4 * 32 * 72; idx += 256) (&Vt[0][0][0])[idx] = 0;
    __syncthreads();
    for (int t0 = 0; t0 < T; t0 += 2) {
        int t = t0 + (tid >> 7);
        int c = tid & 127;                 // 4 heads * 32 dims
        if (t < T) {
            Vt[c >> 5][c & 31][t] = q_base[(size_t)t * N3 + 768 + hg * 128 + c];
        }
    }
    __syncthreads();

    const int fr = lane & 15;
    const int fk = (lane >> 4) * 8;
    const int lg = lane >> 4;
    const int lc = lane & 15;

    // Q, K fragments straight from global
    short8v aq[4], bk[4];
#pragma unroll
    for (int m = 0; m < 4; ++m) {
        const short* qp = q_base + (size_t)(m * 16 + fr) * N3 + h * 32 + fk;
        aq[m] = *(const short8v*)qp;
        bk[m] = *(const short8v*)(qp + 384);
    }

    // S = Q @ K^T  (16 MFMAs)
    f32x4 acc[4][4] = {};
#pragma unroll
    for (int m = 0; m < 4; ++m)
#pragma unroll
        for (int n = 0; n < 4; ++n)
            acc[m][n] = __builtin_amdgcn_mfma_f32_16x16x32_bf16(aq[m], bk[n], acc[m][n], 0, 0, 0);

    // in-register softmax over rows; write P (bf16) to wave-local LDS
    const float* bh = biasT ? (biasT + (size_t)h * 4096) : nullptr;
#pragma unroll
    for (int m = 0; m < 4; ++m) {
#pragma unroll
        for (int j = 0; j < 4; ++j) {
            int r = m * 16 + lg * 4 + j;
            float v[4];
#pragma unroll
            for (int n = 0; n < 4; ++n) {
                float x = acc[m][n][j] * scale;
                if (bh) x += bh[r * 64 + n * 16 + lc];
                if (n * 16 + lc >= T) x = -1e30f;
                v[n] = x;
            }
            float mx = fmaxf(fmaxf(v[0], v[1]), fmaxf(v[2], v[3]));
#pragma unroll
            for (int off = 1; off < 16; off <<= 1) mx = fmaxf(mx, __shfl_xor(mx, off));
            float s = 0.f;
#pragma unroll
            for (int n = 0; n < 4; ++n) { v[n] = __expf(v[n] - mx); s += v[n]; }
#pragma unroll
            for (int off = 1; off < 16; off <<= 1) s += __shfl_xor(s, off);
            float inv = 1.0f / s;
#pragma unroll
            for (int n = 0; n < 4; ++n)
                Pl[wv][r][n * 16 + lc] = bf16s(v[n] * inv);
        }
    }

    // O = P @ V  (16 MFMAs); Pl/Vt reads are wave-local (compiler inserts lgkmcnt)
    f32x4 oacc[4][2] = {};
#pragma unroll
    for (int ks = 0; ks < 2; ++ks) {
        short8v ap[4], bv[2];
#pragma unroll
        for (int m = 0; m < 4; ++m)
            ap[m] = *(const short8v*)&Pl[wv][m * 16 + fr][ks * 32 + fk];
#pragma unroll
        for (int n = 0; n < 2; ++n)
            bv[n] = *(const short8v*)&Vt[wv][n * 16 + fr][ks * 32 + fk];
#pragma unroll
        for (int m = 0; m < 4; ++m)
#pragma unroll
            for (int n = 0; n < 2; ++n)
                oacc[m][n] = __builtin_amdgcn_mfma_f32_16x16x32_bf16(ap[m], bv[n], oacc[m][n], 0, 0, 0);
    }

    short* ob = (short*)o;
#pragma unroll
    for (int m = 0; m < 4; ++m)
#pragma unroll
        for (int j = 0; j < 4; ++j) {
            int r = m * 16 + lg * 4 + j;
            if (r < T) {
#pragma unroll
                for (int n = 0; n < 2; ++n)
                    ob[((size_t)p * T + r) * CC + h * 32 + n * 16 + lc] = bf16s(oacc[m][n][j]);
            }
        }
}

// ---------------- host ----------------
extern "C" void kernel_launch(void* const* d_in, const int* in_sizes, int n_in,
                              void* d_out, int out_size, void* d_ws, size_t ws_size,
                              hipStream_t stream) {
    const float* cls_in   = (const float*)d_in[0];
    const float* patch_in = (const float*)d_in[1];
    const float* qkv_w    = (const float*)d_in[2];
    const float* qkv_b    = (const float*)d_in[3];
    const float* proj_w   = (const float*)d_in[4];
    const float* proj_b   = (const float*)d_in[5];
    const float* rel_pos  = (const float*)d_in[6];
    const float* ln0w = (const float*)d_in[7];
    const float* ln0b = (const float*)d_in[8];
    const float* ln1w = (const float*)d_in[9];
    const float* ln1b = (const float*)d_in[10];
    const float* ln2w = (const float*)d_in[11];
    const float* ln2b = (const float*)d_in[12];
    const float* w1 = (const float*)d_in[13];
    const float* b1 = (const float*)d_in[14];
    const float* w2 = (const float*)d_in[15];
    const float* b2 = (const float*)d_in[16];

    float* OUT = (float*)d_ws;
    size_t avail = ws_size / 4;

    const size_t OUT_F = 39321600;          // 2048*50*384 fp32 residual stream
    const size_t WB_F  = 1769472;           // bf16 weights (f32 slots)
    const size_t BT_F  = 49152;             // bias table 12*64*64 fp32
    __hip_bfloat16* WB = (__hip_bfloat16*)(OUT + OUT_F);
    __hip_bfloat16* qwb = WB;                                   // 2*1152*384
    __hip_bfloat16* pwb = WB + 884736;                          // 2*384*384
    __hip_bfloat16* w1b = WB + 1179648;                         // 2*1536*384
    __hip_bfloat16* w2b = WB + 2359296;                         // 2*384*1536
    float* biasTbuf = OUT + OUT_F + WB_F;

    int cw = 2048;
    // per-window f32 slots: Xb bf16 19200 -> 9600 ; QH union bf16 max(57600,76800) -> 38400
    while (cw > 64 && OUT_F + WB_F + BT_F + (size_t)cw * 48000 > avail) cw >>= 1;
    float* fbase = OUT + OUT_F + WB_F + BT_F;
    __hip_bfloat16* Xb = (__hip_bfloat16*)fbase;
    __hip_bfloat16* Qb = (__hip_bfloat16*)(fbase + (size_t)cw * 9600);
    __hip_bfloat16* Hb = Qb;   // MLP hidden reuses Qb region
    const float scale = 0.17677669529663687f;

    f2bf_kernel<<<dim3((884736 / 4 + 255) / 256), dim3(256), 0, stream>>>(qkv_w, qwb, 884736);
    f2bf_kernel<<<dim3((294912 / 4 + 255) / 256), dim3(256), 0, stream>>>(proj_w, pwb, 294912);
    f2bf_kernel<<<dim3((1179648 / 4 + 255) / 256), dim3(256), 0, stream>>>(w1, w1b, 1179648);
    f2bf_kernel<<<dim3((1179648 / 4 + 255) / 256), dim3(256), 0, stream>>>(w2, w2b, 1179648);

    pack_cls_kernel<<<dim3(BB * 6), dim3(256), 0, stream>>>(cls_in, OUT);
    pack_patch_kernel<<<dim3(BB * 56 * 6), dim3(256), 0, stream>>>(patch_in, OUT);

    for (int i = 0; i < NBB; ++i) {
        const __hip_bfloat16* qw = qwb + (size_t)i * N3 * CC;
        const float* qb = qkv_b + (size_t)i * N3;
        const __hip_bfloat16* pw = pwb + (size_t)i * CC * CC;
        const float* pb = proj_b + (size_t)i * CC;
        const float* rp = rel_pos + (size_t)i * NHH * 169;
        const __hip_bfloat16* w1i = w1b + (size_t)i * HIDD * CC;
        const float* b1i = b1 + (size_t)i * HIDD;
        const __hip_bfloat16* w2i = w2b + (size_t)i * CC * HIDD;
        const float* b2i = b2 + (size_t)i * CC;

        bias_precompute_kernel<<<dim3(NHH), dim3(256), 0, stream>>>(rp, biasTbuf);

        // ---- stage A: cls attention across 64 windows of each image (T=64) ----
        ln_kernel<<<dim3(2048 / 4), dim3(256), 0, stream>>>(OUT, LDOUT, ln0w + i * CC, ln0b + i * CC, Xb, CC, 2048);
        gemm_bf16_kernel<1, 0, 0, 1><<<dim3(N3 / 128, 2048 / 128), dim3(256), 0, stream>>>(
            Xb, CC, qw, qb, nullptr, 0, Qb, N3, 2048, N3, CC);
        attn_mfma_kernel<<<dim3(BB, 3), dim3(256), 0, stream>>>(Qb, nullptr, Xb, 64, scale);
        gemm_bf16_kernel<1, 0, 1, 0><<<dim3(CC / 128, 2048 / 128), dim3(256), 0, stream>>>(
            Xb, CC, pw, pb, OUT, LDOUT, nullptr, 0, 2048, CC, CC);

        // ---- stage B: windowed attention with rel-pos bias (T=50) ----
        for (int w0 = 0; w0 < NWW; w0 += cw) {
            float* outc = OUT + (size_t)w0 * LDOUT;
            int Mr = cw * NTT;
            ln_kernel<<<dim3(Mr / 4), dim3(256), 0, stream>>>(outc, CC, ln1w + i * CC, ln1b + i * CC, Xb, CC, Mr);
            gemm_bf16_kernel<1, 0, 0, 1><<<dim3(N3 / 128, Mr / 128), dim3(256), 0, stream>>>(
                Xb, CC, qw, qb, nullptr, 0, Qb, N3, Mr, N3, CC);
            attn_mfma_kernel<<<dim3(cw, 3), dim3(256), 0, stream>>>(Qb, biasTbuf, Xb, NTT, scale);
            gemm_bf16_kernel<1, 0, 1, 0><<<dim3(CC / 128, Mr / 128), dim3(256), 0, stream>>>(
                Xb, CC, pw, pb, outc, CC, nullptr, 0, Mr, CC, CC);
        }

        // ---- stage C: MLP ----
        for (int w0 = 0; w0 < NWW; w0 += cw) {
            float* outc = OUT + (size_t)w0 * LDOUT;
            int Mr = cw * NTT;
            ln_kernel<<<dim3(Mr / 4), dim3(256), 0, stream>>>(outc, CC, ln2w + i * CC, ln2b + i * CC, Xb, CC, Mr);
            gemm_bf16_kernel<1, 1, 0, 1><<<dim3(HIDD / 128, Mr / 128), dim3(256), 0, stream>>>(
                Xb, CC, w1i, b1i, nullptr, 0, Hb, HIDD, Mr, HIDD, CC);
            gemm_bf16_kernel<1, 0, 1, 0><<<dim3(CC / 128, Mr / 128), dim3(256), 0, stream>>>(
                Hb, HIDD, w2i, b2i, outc, CC, nullptr, 0, Mr, CC, HIDD);
        }
    }

    unpack_cls_kernel<<<dim3(BB * 6), dim3(256), 0, stream>>>(OUT, (float*)d_out);
    unpack_patch_kernel<<<dim3(BB * 56 * 6), dim3(256), 0, stream>>>(OUT, (float*)d_out + 786432);
}

// Round 4
// 2721.234 us; speedup vs baseline: 4.4080x; 1.1847x over previous
//
#include <hip/hip_runtime.h>
#include <hip/hip_bf16.h>
#include <cstdint>
#include <cstddef>

// ---- problem constants ----
#define BB    32
#define CC    384
#define NHH   12
#define HDD   32
#define WSS   7
#define HKK   8
#define NBB   2
#define HIDD  1536
#define NTT   50          // tokens per window (1 cls + 49 patch)
#define NWW   2048        // B*HK*HK windows
#define LDOUT 19200       // 50*384
#define N3    1152        // 3*C

typedef __attribute__((ext_vector_type(8))) short short8v;
typedef __attribute__((ext_vector_type(4))) float f32x4;

#if defined(__has_builtin)
#if __has_builtin(__builtin_amdgcn_global_load_lds)
#define HAS_GLDS 1
#endif
#endif
#ifndef HAS_GLDS
#define HAS_GLDS 0
#endif

static __device__ __forceinline__ float gelu_f(float x) {
    return 0.5f * x * (1.0f + erff(x * 0.70710678118654752440f));
}

static __device__ __forceinline__ short bf16s(float x) {
    __hip_bfloat16 b = __float2bfloat16(x);
    return *(short*)&b;
}

#if HAS_GLDS
static __device__ __forceinline__ void glds16(const short* g, short* l) {
    __builtin_amdgcn_global_load_lds(
        (const __attribute__((address_space(1))) unsigned int*)g,
        (__attribute__((address_space(3))) unsigned int*)l,
        16, 0, 0);
}
#endif

// ---------------- pack / unpack (fp32) ----------------
__global__ void pack_cls_kernel(const float* __restrict__ cls, float* __restrict__ out) {
    __shared__ float lds[64][65];
    int bid = blockIdx.x;
    int b = bid / 6, cc = bid % 6, c0 = cc * 64;
    int tid = threadIdx.x;
    for (int idx = tid; idx < 64 * 64; idx += 256) {
        int k = idx & 63, cl = idx >> 6;
        lds[cl][k] = cls[((size_t)b * CC + c0 + cl) * 64 + k];
    }
    __syncthreads();
    for (int idx = tid; idx < 64 * 64; idx += 256) {
        int cl = idx & 63, k = idx >> 6;
        out[(size_t)(b * 64 + k) * LDOUT + c0 + cl] = lds[cl][k];
    }
}

__global__ void pack_patch_kernel(const float* __restrict__ patch, float* __restrict__ out) {
    __shared__ float lds[64][57];
    int bid = blockIdx.x;
    int b = bid / 336, rem = bid % 336;
    int y = rem / 6, cc = rem % 6, c0 = cc * 64;
    int tid = threadIdx.x;
    for (int idx = tid; idx < 64 * 56; idx += 256) {
        int cl = idx / 56, x = idx % 56;
        lds[cl][x] = patch[(((size_t)b * CC + c0 + cl) * 56 + y) * 56 + x];
    }
    __syncthreads();
    int wsy = y % 7, hky = y / 7;
    for (int idx = tid; idx < 64 * 56; idx += 256) {
        int cl = idx & 63, x = idx >> 6;
        int tok = 1 + wsy * 7 + (x % 7);
        int win = b * 64 + hky * 8 + (x / 7);
        out[((size_t)win * NTT + tok) * CC + c0 + cl] = lds[cl][x];
    }
}

__global__ void unpack_cls_kernel(const float* __restrict__ out, float* __restrict__ cls_out) {
    __shared__ float lds[64][65];
    int bid = blockIdx.x;
    int b = bid / 6, cc = bid % 6, c0 = cc * 64;
    int tid = threadIdx.x;
    for (int idx = tid; idx < 64 * 64; idx += 256) {
        int cl = idx & 63, k = idx >> 6;
        lds[cl][k] = out[(size_t)(b * 64 + k) * LDOUT + c0 + cl];
    }
    __syncthreads();
    for (int idx = tid; idx < 64 * 64; idx += 256) {
        int k = idx & 63, cl = idx >> 6;
        cls_out[((size_t)b * CC + c0 + cl) * 64 + k] = lds[cl][k];
    }
}

__global__ void unpack_patch_kernel(const float* __restrict__ out, float* __restrict__ patch_out) {
    __shared__ float lds[64][57];
    int bid = blockIdx.x;
    int b = bid / 336, rem = bid % 336;
    int y = rem / 6, cc = rem % 6, c0 = cc * 64;
    int tid = threadIdx.x;
    int wsy = y % 7, hky = y / 7;
    for (int idx = tid; idx < 64 * 56; idx += 256) {
        int cl = idx & 63, x = idx >> 6;
        int tok = 1 + wsy * 7 + (x % 7);
        int win = b * 64 + hky * 8 + (x / 7);
        lds[cl][x] = out[((size_t)win * NTT + tok) * CC + c0 + cl];
    }
    __syncthreads();
    for (int idx = tid; idx < 64 * 56; idx += 256) {
        int cl = idx / 56, x = idx % 56;
        patch_out[((size_t)b * CC + c0 + cl) * 3136 + y * 56 + x] = lds[cl][x];
    }
}

// ---------------- fp32 -> bf16 weight conversion ----------------
__global__ void f2bf_kernel(const float* __restrict__ in, __hip_bfloat16* __restrict__ out, int n) {
    int i = (blockIdx.x * 256 + threadIdx.x) * 4;
    if (i + 3 < n) {
        float4 v = *(const float4*)(in + i);
        out[i + 0] = __float2bfloat16(v.x);
        out[i + 1] = __float2bfloat16(v.y);
        out[i + 2] = __float2bfloat16(v.z);
        out[i + 3] = __float2bfloat16(v.w);
    } else {
        for (; i < n; ++i) out[i] = __float2bfloat16(in[i]);
    }
}

// ---------------- rel-pos bias table, fragment-ordered: [12][64 r][16 lc][4 n] fp32 ----------------
__global__ void bias_precompute_kernel(const float* __restrict__ rp, float* __restrict__ biasT) {
    int h = blockIdx.x;
    for (int idx = threadIdx.x; idx < 4096; idx += 256) {
        int qt = idx >> 6, kt = idx & 63;
        float v = 0.f;
        if (qt >= 1 && qt < NTT && kt >= 1 && kt < NTT) {
            int qp = qt - 1, kp = kt - 1;
            int qy = qp / 7, qx = qp - qy * 7;
            int ky = kp / 7, kx = kp - ky * 7;
            int ridx = ((ky - qy + 16) % 13) * 13 + ((kx - qx + 16) % 13);
            v = rp[h * 169 + ridx];
        }
        // fragment-order: [r][lc][n] so a lane's 4 cols are one float4
        biasT[h * 4096 + qt * 64 + (kt & 15) * 4 + (kt >> 4)] = v;
    }
}

// ---------------- LayerNorm -> bf16 ----------------
__global__ void ln_kernel(const float* __restrict__ x, int ldx,
                          const float* __restrict__ w, const float* __restrict__ b,
                          __hip_bfloat16* __restrict__ y, int ldy, int M) {
    int wave = threadIdx.x >> 6, lane = threadIdx.x & 63;
    int row = blockIdx.x * 4 + wave;
    if (row >= M) return;
    const float* xr = x + (size_t)row * ldx;
    float vals[6];
    float s = 0.f;
#pragma unroll
    for (int j = 0; j < 6; ++j) { vals[j] = xr[lane + j * 64]; s += vals[j]; }
#pragma unroll
    for (int off = 32; off > 0; off >>= 1) s += __shfl_xor(s, off);
    float mean = s * (1.0f / 384.0f);
    float vs = 0.f;
#pragma unroll
    for (int j = 0; j < 6; ++j) { float d = vals[j] - mean; vs += d * d; }
#pragma unroll
    for (int off = 32; off > 0; off >>= 1) vs += __shfl_xor(vs, off);
    float inv = rsqrtf(vs * (1.0f / 384.0f) + 1e-6f);
    __hip_bfloat16* yr = y + (size_t)row * ldy;
#pragma unroll
    for (int j = 0; j < 6; ++j) {
        int c = lane + j * 64;
        yr[c] = __float2bfloat16((vals[j] - mean) * inv * w[c] + b[c]);
    }
}

// ---------------- bf16 MFMA GEMM: Y = A[M,K] @ W[N,K]^T ----------------
// 128x128 tile, 4 waves (2x2), BK=32, linear LDS + global_load_lds width-16 (m97 structure).
template <int BIAS, int GELU, int ACC, int OUTBF>
__global__ __launch_bounds__(256) void gemm_bf16_kernel(
    const __hip_bfloat16* __restrict__ A, int lda,
    const __hip_bfloat16* __restrict__ W,
    const float* __restrict__ bias,
    float* __restrict__ Y, int ldy,
    __hip_bfloat16* __restrict__ Yb, int ldyb,
    int M, int N, int K) {
    __shared__ __align__(16) short As[128 * 32];
    __shared__ __align__(16) short Bs[128 * 32];
    int tid = threadIdx.x;
    int lane = tid & 63;
    int wid = tid >> 6;
    int wr = wid >> 1, wc = wid & 1;
    int row0 = blockIdx.y * 128, col0 = blockIdx.x * 128;

    // staging: per call-site, wave wid covers 16 rows; lane -> (row = lane>>2, kq = lane&3)
    const short* Ag = (const short*)A + (size_t)(row0 + wid * 16 + (lane >> 2)) * lda + (lane & 3) * 8;
    const short* Wg = (const short*)W + (size_t)(col0 + wid * 16 + (lane >> 2)) * K + (lane & 3) * 8;
    short* AsW = As + wid * 16 * 32;   // wave-uniform LDS base
    short* BsW = Bs + wid * 16 * 32;
    size_t astep = (size_t)64 * lda;
    size_t wstep = (size_t)64 * K;

    f32x4 acc[4][4] = {};
    int frow_a = wr * 64 + (lane & 15);
    int frow_b = wc * 64 + (lane & 15);
    int fk = (lane >> 4) * 8;

    for (int k0 = 0; k0 < K; k0 += 32) {
#if HAS_GLDS
        glds16(Ag + k0, AsW);
        glds16(Ag + astep + k0, AsW + 64 * 32);
        glds16(Wg + k0, BsW);
        glds16(Wg + wstep + k0, BsW + 64 * 32);
#else
        *(short8v*)(AsW + lane * 8)           = *(const short8v*)(Ag + k0);
        *(short8v*)(AsW + 64 * 32 + lane * 8) = *(const short8v*)(Ag + astep + k0);
        *(short8v*)(BsW + lane * 8)           = *(const short8v*)(Wg + k0);
        *(short8v*)(BsW + 64 * 32 + lane * 8) = *(const short8v*)(Wg + wstep + k0);
#endif
        __syncthreads();
        short8v a[4], b[4];
#pragma unroll
        for (int m = 0; m < 4; ++m) a[m] = *(const short8v*)&As[(frow_a + m * 16) * 32 + fk];
#pragma unroll
        for (int n = 0; n < 4; ++n) b[n] = *(const short8v*)&Bs[(frow_b + n * 16) * 32 + fk];
#pragma unroll
        for (int m = 0; m < 4; ++m)
#pragma unroll
            for (int n = 0; n < 4; ++n)
                acc[m][n] = __builtin_amdgcn_mfma_f32_16x16x32_bf16(a[m], b[n], acc[m][n], 0, 0, 0);
        __syncthreads();
    }

    int lr = (lane >> 4) * 4;
    int lc = lane & 15;
    int crow0 = row0 + wr * 64;
    int ccol0 = col0 + wc * 64;
#pragma unroll
    for (int n = 0; n < 4; ++n) {
        int c = ccol0 + n * 16 + lc;
        float bv = BIAS ? bias[c] : 0.0f;
#pragma unroll
        for (int m = 0; m < 4; ++m) {
#pragma unroll
            for (int j = 0; j < 4; ++j) {
                int r = crow0 + m * 16 + lr + j;
                float v = acc[m][n][j] + bv;
                if (GELU) v = gelu_f(v);
                if (OUTBF) {
                    Yb[(size_t)r * ldyb + c] = __float2bfloat16(v);
                } else {
                    float* yp = Y + (size_t)r * ldy + c;
                    if (ACC) v += *yp;
                    *yp = v;
                }
            }
        }
    }
}

// ---------------- MFMA attention, barrier-free ----------------
// block = (window p, head-group hg of 4); wave wv handles head h = hg*4+wv; everything wave-local.
// qkv bf16 [P*T][1152]; biasT fp32 [12][64][16][4] fragment-ordered or nullptr; o bf16 [P*T][384].
__global__ __launch_bounds__(256) void attn_mfma_kernel(
    const __hip_bfloat16* __restrict__ qkv,
    const float* __restrict__ biasT,
    __hip_bfloat16* __restrict__ o,
    int T, float scale) {
    __shared__ __align__(16) short Vt[4][32][72];   // [wave][d][kt]  (V transposed)
    __shared__ __align__(16) short Pl[4][64][40];   // [wave][r][half-K cols 0..31]
    const int tid = threadIdx.x, lane = tid & 63, wv = tid >> 6;
    const int p = blockIdx.x, hg = blockIdx.y;
    const int h = hg * 4 + wv;
    const short* q_base = (const short*)qkv + (size_t)p * T * N3;

    const int fr = lane & 15;
    const int fk = (lane >> 4) * 8;
    const int lg = lane >> 4;
    const int lc = lane & 15;

    // (1) issue Q,K fragment loads first (latency hides under V staging)
    short8v aq[4], bk[4];
#pragma unroll
    for (int m = 0; m < 4; ++m) {
        const short* qp = q_base + (size_t)(m * 16 + fr) * N3 + h * 32 + fk;
        aq[m] = *(const short8v*)qp;
        bk[m] = *(const short8v*)(qp + 384);
    }

    // (2) wave-local V staging (transposed), then zero the kt-tail
    for (int ch = lane; ch < T * 4; ch += 64) {
        int t = ch >> 2, cq = ch & 3;
        short8v v8 = *(const short8v*)(q_base + (size_t)t * N3 + 768 + h * 32 + cq * 8);
#pragma unroll
        for (int e = 0; e < 8; ++e) Vt[wv][cq * 8 + e][t] = v8[e];
    }
    for (int idx = lane; idx < (64 - T) * 32; idx += 64) {
        int t = T + (idx >> 5), d = idx & 31;
        Vt[wv][d][t] = 0;
    }

    // (3) S = Q @ K^T  (16 MFMAs, hd=32 -> single K-step)
    f32x4 acc[4][4] = {};
#pragma unroll
    for (int m = 0; m < 4; ++m)
#pragma unroll
        for (int n = 0; n < 4; ++n)
            acc[m][n] = __builtin_amdgcn_mfma_f32_16x16x32_bf16(aq[m], bk[n], acc[m][n], 0, 0, 0);

    // (4) in-register softmax; write P cols 0..31; keep cols 32..63 in regs
    const float* bh = biasT ? (biasT + (size_t)h * 4096) : nullptr;
    float p2[4][4], p3[4][4];
#pragma unroll
    for (int m = 0; m < 4; ++m) {
#pragma unroll
        for (int j = 0; j < 4; ++j) {
            int r = m * 16 + lg * 4 + j;
            float v[4];
            if (bh) {
                float4 bv4 = *(const float4*)(bh + r * 64 + lc * 4);
#pragma unroll
                for (int n = 0; n < 4; ++n) v[n] = acc[m][n][j] * scale + ((const float*)&bv4)[n];
            } else {
#pragma unroll
                for (int n = 0; n < 4; ++n) v[n] = acc[m][n][j] * scale;
            }
#pragma unroll
            for (int n = 0; n < 4; ++n)
                if (n * 16 + lc >= T) v[n] = -1e30f;
            float mx = fmaxf(fmaxf(v[0], v[1]), fmaxf(v[2], v[3]));
#pragma unroll
            for (int off = 1; off < 16; off <<= 1) mx = fmaxf(mx, __shfl_xor(mx, off));
            float s = 0.f;
#pragma unroll
            for (int n = 0; n < 4; ++n) { v[n] = __expf(v[n] - mx); s += v[n]; }
#pragma unroll
            for (int off = 1; off < 16; off <<= 1) s += __shfl_xor(s, off);
            float inv = 1.0f / s;
            Pl[wv][r][lc]      = bf16s(v[0] * inv);
            Pl[wv][r][16 + lc] = bf16s(v[1] * inv);
            p2[m][j] = v[2] * inv;
            p3[m][j] = v[3] * inv;
        }
    }

    // (5) O = P @ V, split-K halves through the half-size Pl buffer
    f32x4 oacc[4][2] = {};
    {
        short8v ap[4], bv[2];
#pragma unroll
        for (int m = 0; m < 4; ++m) ap[m] = *(const short8v*)&Pl[wv][m * 16 + fr][fk];
#pragma unroll
        for (int n = 0; n < 2; ++n) bv[n] = *(const short8v*)&Vt[wv][n * 16 + fr][fk];
#pragma unroll
        for (int m = 0; m < 4; ++m)
#pragma unroll
            for (int n = 0; n < 2; ++n)
                oacc[m][n] = __builtin_amdgcn_mfma_f32_16x16x32_bf16(ap[m], bv[n], oacc[m][n], 0, 0, 0);
    }
#pragma unroll
    for (int m = 0; m < 4; ++m)
#pragma unroll
        for (int j = 0; j < 4; ++j) {
            int r = m * 16 + lg * 4 + j;
            Pl[wv][r][lc]      = bf16s(p2[m][j]);
            Pl[wv][r][16 + lc] = bf16s(p3[m][j]);
        }
    {
        short8v ap[4], bv[2];
#pragma unroll
        for (int m = 0; m < 4; ++m) ap[m] = *(const short8v*)&Pl[wv][m * 16 + fr][fk];
#pragma unroll
        for (int n = 0; n < 2; ++n) bv[n] = *(const short8v*)&Vt[wv][n * 16 + fr][32 + fk];
#pragma unroll
        for (int m = 0; m < 4; ++m)
#pragma unroll
            for (int n = 0; n < 2; ++n)
                oacc[m][n] = __builtin_amdgcn_mfma_f32_16x16x32_bf16(ap[m], bv[n], oacc[m][n], 0, 0, 0);
    }

    short* ob = (short*)o;
#pragma unroll
    for (int m = 0; m < 4; ++m)
#pragma unroll
        for (int j = 0; j < 4; ++j) {
            int r = m * 16 + lg * 4 + j;
            if (r < T) {
#pragma unroll
                for (int n = 0; n < 2; ++n)
                    ob[((size_t)p * T + r) * CC + h * 32 + n * 16 + lc] = bf16s(oacc[m][n][j]);
            }
        }
}

// ---------------- host ----------------
extern "C" void kernel_launch(void* const* d_in, const int* in_sizes, int n_in,
                              void* d_out, int out_size, void* d_ws, size_t ws_size,
                              hipStream_t stream) {
    const float* cls_in   = (const float*)d_in[0];
    const float* patch_in = (const float*)d_in[1];
    const float* qkv_w    = (const float*)d_in[2];
    const float* qkv_b    = (const float*)d_in[3];
    const float* proj_w   = (const float*)d_in[4];
    const float* proj_b   = (const float*)d_in[5];
    const float* rel_pos  = (const float*)d_in[6];
    const float* ln0w = (const float*)d_in[7];
    const float* ln0b = (const float*)d_in[8];
    const float* ln1w = (const float*)d_in[9];
    const float* ln1b = (const float*)d_in[10];
    const float* ln2w = (const float*)d_in[11];
    const float* ln2b = (const float*)d_in[12];
    const float* w1 = (const float*)d_in[13];
    const float* b1 = (const float*)d_in[14];
    const float* w2 = (const float*)d_in[15];
    const float* b2 = (const float*)d_in[16];

    float* OUT = (float*)d_ws;
    size_t avail = ws_size / 4;

    const size_t OUT_F = 39321600;          // 2048*50*384 fp32 residual stream
    const size_t WB_F  = 1769472;           // bf16 weights (f32 slots)
    const size_t BT_F  = 49152;             // bias table 12*64*64 fp32
    __hip_bfloat16* WB = (__hip_bfloat16*)(OUT + OUT_F);
    __hip_bfloat16* qwb = WB;                                   // 2*1152*384
    __hip_bfloat16* pwb = WB + 884736;                          // 2*384*384
    __hip_bfloat16* w1b = WB + 1179648;                         // 2*1536*384
    __hip_bfloat16* w2b = WB + 2359296;                         // 2*384*1536
    float* biasTbuf = OUT + OUT_F + WB_F;

    int cw = 2048;
    // per-window f32 slots: Xb bf16 19200 -> 9600 ; QH union bf16 max(57600,76800) -> 38400
    while (cw > 64 && OUT_F + WB_F + BT_F + (size_t)cw * 48000 > avail) cw >>= 1;
    float* fbase = OUT + OUT_F + WB_F + BT_F;
    __hip_bfloat16* Xb = (__hip_bfloat16*)fbase;
    __hip_bfloat16* Qb = (__hip_bfloat16*)(fbase + (size_t)cw * 9600);
    __hip_bfloat16* Hb = Qb;   // MLP hidden reuses Qb region
    const float scale = 0.17677669529663687f;

    f2bf_kernel<<<dim3((884736 / 4 + 255) / 256), dim3(256), 0, stream>>>(qkv_w, qwb, 884736);
    f2bf_kernel<<<dim3((294912 / 4 + 255) / 256), dim3(256), 0, stream>>>(proj_w, pwb, 294912);
    f2bf_kernel<<<dim3((1179648 / 4 + 255) / 256), dim3(256), 0, stream>>>(w1, w1b, 1179648);
    f2bf_kernel<<<dim3((1179648 / 4 + 255) / 256), dim3(256), 0, stream>>>(w2, w2b, 1179648);

    pack_cls_kernel<<<dim3(BB * 6), dim3(256), 0, stream>>>(cls_in, OUT);
    pack_patch_kernel<<<dim3(BB * 56 * 6), dim3(256), 0, stream>>>(patch_in, OUT);

    for (int i = 0; i < NBB; ++i) {
        const __hip_bfloat16* qw = qwb + (size_t)i * N3 * CC;
        const float* qb = qkv_b + (size_t)i * N3;
        const __hip_bfloat16* pw = pwb + (size_t)i * CC * CC;
        const float* pb = proj_b + (size_t)i * CC;
        const float* rp = rel_pos + (size_t)i * NHH * 169;
        const __hip_bfloat16* w1i = w1b + (size_t)i * HIDD * CC;
        const float* b1i = b1 + (size_t)i * HIDD;
        const __hip_bfloat16* w2i = w2b + (size_t)i * CC * HIDD;
        const float* b2i = b2 + (size_t)i * CC;

        bias_precompute_kernel<<<dim3(NHH), dim3(256), 0, stream>>>(rp, biasTbuf);

        // ---- stage A: cls attention across 64 windows of each image (T=64) ----
        ln_kernel<<<dim3(2048 / 4), dim3(256), 0, stream>>>(OUT, LDOUT, ln0w + i * CC, ln0b + i * CC, Xb, CC, 2048);
        gemm_bf16_kernel<1, 0, 0, 1><<<dim3(N3 / 128, 2048 / 128), dim3(256), 0, stream>>>(
            Xb, CC, qw, qb, nullptr, 0, Qb, N3, 2048, N3, CC);
        attn_mfma_kernel<<<dim3(BB, 3), dim3(256), 0, stream>>>(Qb, nullptr, Xb, 64, scale);
        gemm_bf16_kernel<1, 0, 1, 0><<<dim3(CC / 128, 2048 / 128), dim3(256), 0, stream>>>(
            Xb, CC, pw, pb, OUT, LDOUT, nullptr, 0, 2048, CC, CC);

        // ---- stage B: windowed attention with rel-pos bias (T=50) ----
        for (int w0 = 0; w0 < NWW; w0 += cw) {
            float* outc = OUT + (size_t)w0 * LDOUT;
            int Mr = cw * NTT;
            ln_kernel<<<dim3(Mr / 4), dim3(256), 0, stream>>>(outc, CC, ln1w + i * CC, ln1b + i * CC, Xb, CC, Mr);
            gemm_bf16_kernel<1, 0, 0, 1><<<dim3(N3 / 128, Mr / 128), dim3(256), 0, stream>>>(
                Xb, CC, qw, qb, nullptr, 0, Qb, N3, Mr, N3, CC);
            attn_mfma_kernel<<<dim3(cw, 3), dim3(256), 0, stream>>>(Qb, biasTbuf, Xb, NTT, scale);
            gemm_bf16_kernel<1, 0, 1, 0><<<dim3(CC / 128, Mr / 128), dim3(256), 0, stream>>>(
                Xb, CC, pw, pb, outc, CC, nullptr, 0, Mr, CC, CC);
        }

        // ---- stage C: MLP ----
        for (int w0 = 0; w0 < NWW; w0 += cw) {
            float* outc = OUT + (size_t)w0 * LDOUT;
            int Mr = cw * NTT;
            ln_kernel<<<dim3(Mr / 4), dim3(256), 0, stream>>>(outc, CC, ln2w + i * CC, ln2b + i * CC, Xb, CC, Mr);
            gemm_bf16_kernel<1, 1, 0, 1><<<dim3(HIDD / 128, Mr / 128), dim3(256), 0, stream>>>(
                Xb, CC, w1i, b1i, nullptr, 0, Hb, HIDD, Mr, HIDD, CC);
            gemm_bf16_kernel<1, 0, 1, 0><<<dim3(CC / 128, Mr / 128), dim3(256), 0, stream>>>(
                Hb, HIDD, w2i, b2i, outc, CC, nullptr, 0, Mr, CC, HIDD);
        }
    }

    unpack_cls_kernel<<<dim3(BB * 6), dim3(256), 0, stream>>>(OUT, (float*)d_out);
    unpack_patch_kernel<<<dim3(BB * 56 * 6), dim3(256), 0, stream>>>(OUT, (float*)d_out + 786432);
}

// Round 5
// 2582.137 us; speedup vs baseline: 4.6454x; 1.0539x over previous
//
#include <hip/hip_runtime.h>
#include <hip/hip_bf16.h>
#include <cstdint>
#include <cstddef>

// ---- problem constants ----
#define BB    32
#define CC    384
#define NHH   12
#define HDD   32
#define WSS   7
#define HKK   8
#define NBB   2
#define HIDD  1536
#define NTT   50          // tokens per window (1 cls + 49 patch)
#define NWW   2048        // B*HK*HK windows
#define LDOUT 19200       // 50*384
#define N3    1152        // 3*C

typedef __attribute__((ext_vector_type(8))) short short8v;
typedef __attribute__((ext_vector_type(4))) float f32x4;

#if defined(__has_builtin)
#if __has_builtin(__builtin_amdgcn_global_load_lds)
#define HAS_GLDS 1
#endif
#endif
#ifndef HAS_GLDS
#define HAS_GLDS 0
#endif

static __device__ __forceinline__ float gelu_f(float x) {
    return 0.5f * x * (1.0f + erff(x * 0.70710678118654752440f));
}

static __device__ __forceinline__ short bf16s(float x) {
    __hip_bfloat16 b = __float2bfloat16(x);
    return *(short*)&b;
}

#if HAS_GLDS
static __device__ __forceinline__ void glds16(const short* g, short* l) {
    __builtin_amdgcn_global_load_lds(
        (const __attribute__((address_space(1))) unsigned int*)g,
        (__attribute__((address_space(3))) unsigned int*)l,
        16, 0, 0);
}
#endif

// XCD-aware decode: consecutive launched ids round-robin XCDs; keep all nx
// column-blocks of one row-panel on ONE XCD, temporally adjacent.
// Bijective when ny % 8 == 0 (all call sites), else identity fallback.
static __device__ __forceinline__ void swz_decode(int L, int nx, int ny, int& bx, int& by) {
    if (ny & 7) {
        bx = L % nx; by = L / nx;
    } else {
        int r = L & 7, pos = L >> 3;
        bx = pos % nx;
        by = (pos / nx) * 8 + r;
    }
}

// ---------------- pack / unpack (fp32) ----------------
__global__ void pack_cls_kernel(const float* __restrict__ cls, float* __restrict__ out) {
    __shared__ float lds[64][65];
    int bid = blockIdx.x;
    int b = bid / 6, cc = bid % 6, c0 = cc * 64;
    int tid = threadIdx.x;
    for (int idx = tid; idx < 64 * 64; idx += 256) {
        int k = idx & 63, cl = idx >> 6;
        lds[cl][k] = cls[((size_t)b * CC + c0 + cl) * 64 + k];
    }
    __syncthreads();
    for (int idx = tid; idx < 64 * 64; idx += 256) {
        int cl = idx & 63, k = idx >> 6;
        out[(size_t)(b * 64 + k) * LDOUT + c0 + cl] = lds[cl][k];
    }
}

__global__ void pack_patch_kernel(const float* __restrict__ patch, float* __restrict__ out) {
    __shared__ float lds[64][57];
    int bid = blockIdx.x;
    int b = bid / 336, rem = bid % 336;
    int y = rem / 6, cc = rem % 6, c0 = cc * 64;
    int tid = threadIdx.x;
    for (int idx = tid; idx < 64 * 56; idx += 256) {
        int cl = idx / 56, x = idx % 56;
        lds[cl][x] = patch[(((size_t)b * CC + c0 + cl) * 56 + y) * 56 + x];
    }
    __syncthreads();
    int wsy = y % 7, hky = y / 7;
    for (int idx = tid; idx < 64 * 56; idx += 256) {
        int cl = idx & 63, x = idx >> 6;
        int tok = 1 + wsy * 7 + (x % 7);
        int win = b * 64 + hky * 8 + (x / 7);
        out[((size_t)win * NTT + tok) * CC + c0 + cl] = lds[cl][x];
    }
}

__global__ void unpack_cls_kernel(const float* __restrict__ out, float* __restrict__ cls_out) {
    __shared__ float lds[64][65];
    int bid = blockIdx.x;
    int b = bid / 6, cc = bid % 6, c0 = cc * 64;
    int tid = threadIdx.x;
    for (int idx = tid; idx < 64 * 64; idx += 256) {
        int cl = idx & 63, k = idx >> 6;
        lds[cl][k] = out[(size_t)(b * 64 + k) * LDOUT + c0 + cl];
    }
    __syncthreads();
    for (int idx = tid; idx < 64 * 64; idx += 256) {
        int k = idx & 63, cl = idx >> 6;
        cls_out[((size_t)b * CC + c0 + cl) * 64 + k] = lds[cl][k];
    }
}

__global__ void unpack_patch_kernel(const float* __restrict__ out, float* __restrict__ patch_out) {
    __shared__ float lds[64][57];
    int bid = blockIdx.x;
    int b = bid / 336, rem = bid % 336;
    int y = rem / 6, cc = rem % 6, c0 = cc * 64;
    int tid = threadIdx.x;
    int wsy = y % 7, hky = y / 7;
    for (int idx = tid; idx < 64 * 56; idx += 256) {
        int cl = idx & 63, x = idx >> 6;
        int tok = 1 + wsy * 7 + (x % 7);
        int win = b * 64 + hky * 8 + (x / 7);
        lds[cl][x] = out[((size_t)win * NTT + tok) * CC + c0 + cl];
    }
    __syncthreads();
    for (int idx = tid; idx < 64 * 56; idx += 256) {
        int cl = idx / 56, x = idx % 56;
        patch_out[((size_t)b * CC + c0 + cl) * 3136 + y * 56 + x] = lds[cl][x];
    }
}

// ---------------- fp32 -> bf16 weight conversion ----------------
__global__ void f2bf_kernel(const float* __restrict__ in, __hip_bfloat16* __restrict__ out, int n) {
    int i = (blockIdx.x * 256 + threadIdx.x) * 4;
    if (i + 3 < n) {
        float4 v = *(const float4*)(in + i);
        out[i + 0] = __float2bfloat16(v.x);
        out[i + 1] = __float2bfloat16(v.y);
        out[i + 2] = __float2bfloat16(v.z);
        out[i + 3] = __float2bfloat16(v.w);
    } else {
        for (; i < n; ++i) out[i] = __float2bfloat16(in[i]);
    }
}

// ---------------- rel-pos bias table, fragment-ordered: [12][64 r][16 lc][4 n] fp32 ----------------
__global__ void bias_precompute_kernel(const float* __restrict__ rp, float* __restrict__ biasT) {
    int h = blockIdx.x;
    for (int idx = threadIdx.x; idx < 4096; idx += 256) {
        int qt = idx >> 6, kt = idx & 63;
        float v = 0.f;
        if (qt >= 1 && qt < NTT && kt >= 1 && kt < NTT) {
            int qp = qt - 1, kp = kt - 1;
            int qy = qp / 7, qx = qp - qy * 7;
            int ky = kp / 7, kx = kp - ky * 7;
            int ridx = ((ky - qy + 16) % 13) * 13 + ((kx - qx + 16) % 13);
            v = rp[h * 169 + ridx];
        }
        biasT[h * 4096 + qt * 64 + (kt & 15) * 4 + (kt >> 4)] = v;
    }
}

// ---------------- LayerNorm -> bf16 (float2-vectorized) ----------------
__global__ void ln_kernel(const float* __restrict__ x, int ldx,
                          const float* __restrict__ w, const float* __restrict__ b,
                          __hip_bfloat16* __restrict__ y, int ldy, int M) {
    int wave = threadIdx.x >> 6, lane = threadIdx.x & 63;
    int row = blockIdx.x * 4 + wave;
    if (row >= M) return;
    const float2* xr = (const float2*)(x + (size_t)row * ldx);
    float2 vals[3];
    float s = 0.f;
#pragma unroll
    for (int j = 0; j < 3; ++j) { vals[j] = xr[lane + j * 64]; s += vals[j].x + vals[j].y; }
#pragma unroll
    for (int off = 32; off > 0; off >>= 1) s += __shfl_xor(s, off);
    float mean = s * (1.0f / 384.0f);
    float vs = 0.f;
#pragma unroll
    for (int j = 0; j < 3; ++j) {
        float dx = vals[j].x - mean, dy = vals[j].y - mean;
        vs += dx * dx + dy * dy;
    }
#pragma unroll
    for (int off = 32; off > 0; off >>= 1) vs += __shfl_xor(vs, off);
    float inv = rsqrtf(vs * (1.0f / 384.0f) + 1e-6f);
    const float2* w2 = (const float2*)w;
    const float2* b2 = (const float2*)b;
    ushort* yr = (ushort*)(y + (size_t)row * ldy);
#pragma unroll
    for (int j = 0; j < 3; ++j) {
        int c = lane + j * 64;
        float2 wv = w2[c], bv = b2[c];
        ushort2 o;
        o.x = (ushort)bf16s((vals[j].x - mean) * inv * wv.x + bv.x);
        o.y = (ushort)bf16s((vals[j].y - mean) * inv * wv.y + bv.y);
        *(ushort2*)(yr + c * 2) = o;
    }
}

// ---------------- bf16 MFMA GEMM: Y = A[M,K] @ W[N,K]^T ----------------
// 128x128 tile, 4 waves (2x2), BK=32, double-buffered global_load_lds staging,
// XCD-swizzled 1D grid (same row-panel -> same XCD).
template <int BIAS, int GELU, int ACC, int OUTBF>
__global__ __launch_bounds__(256) void gemm_bf16_kernel(
    const __hip_bfloat16* __restrict__ A, int lda,
    const __hip_bfloat16* __restrict__ W,
    const float* __restrict__ bias,
    float* __restrict__ Y, int ldy,
    __hip_bfloat16* __restrict__ Yb, int ldyb,
    int M, int N, int K, int nx) {
    __shared__ __align__(16) short As[2][128 * 32];
    __shared__ __align__(16) short Bs[2][128 * 32];
    int tid = threadIdx.x;
    int lane = tid & 63;
    int wid = tid >> 6;
    int wr = wid >> 1, wc = wid & 1;
    int bx, by;
    swz_decode(blockIdx.x, nx, M >> 7, bx, by);
    int row0 = by * 128, col0 = bx * 128;

    // staging: wave wid covers rows [wid*16, wid*16+16); lane -> (row=lane>>2, kq=lane&3)
    const short* Ag = (const short*)A + (size_t)(row0 + wid * 16 + (lane >> 2)) * lda + (lane & 3) * 8;
    const short* Wg = (const short*)W + (size_t)(col0 + wid * 16 + (lane >> 2)) * K + (lane & 3) * 8;
    size_t astep = (size_t)64 * lda;
    size_t wstep = (size_t)64 * K;
    int ldsoff = wid * 16 * 32;   // wave-uniform; HW adds lane*16B (== row-major layout)

#if HAS_GLDS
#define STAGE(buf, k0)                                      \
    do {                                                    \
        glds16(Ag + (k0), &As[buf][ldsoff]);                \
        glds16(Ag + astep + (k0), &As[buf][64 * 32 + ldsoff]); \
        glds16(Wg + (k0), &Bs[buf][ldsoff]);                \
        glds16(Wg + wstep + (k0), &Bs[buf][64 * 32 + ldsoff]); \
    } while (0)
#else
#define STAGE(buf, k0)                                                          \
    do {                                                                        \
        *(short8v*)(&As[buf][ldsoff] + lane * 8) = *(const short8v*)(Ag + (k0)); \
        *(short8v*)(&As[buf][64 * 32 + ldsoff] + lane * 8) = *(const short8v*)(Ag + astep + (k0)); \
        *(short8v*)(&Bs[buf][ldsoff] + lane * 8) = *(const short8v*)(Wg + (k0)); \
        *(short8v*)(&Bs[buf][64 * 32 + ldsoff] + lane * 8) = *(const short8v*)(Wg + wstep + (k0)); \
    } while (0)
#endif

    f32x4 acc[4][4] = {};
    int frow_a = wr * 64 + (lane & 15);
    int frow_b = wc * 64 + (lane & 15);
    int fk = (lane >> 4) * 8;

    STAGE(0, 0);
    __syncthreads();
    int nt = K >> 5;
    int cur = 0;
    for (int t = 0; t < nt; ++t) {
        if (t + 1 < nt) STAGE(cur ^ 1, (t + 1) << 5);   // prefetch next K-tile (issue-early)
        short8v a[4], b[4];
#pragma unroll
        for (int m = 0; m < 4; ++m) a[m] = *(const short8v*)&As[cur][(frow_a + m * 16) * 32 + fk];
#pragma unroll
        for (int n = 0; n < 4; ++n) b[n] = *(const short8v*)&Bs[cur][(frow_b + n * 16) * 32 + fk];
#pragma unroll
        for (int m = 0; m < 4; ++m)
#pragma unroll
            for (int n = 0; n < 4; ++n)
                acc[m][n] = __builtin_amdgcn_mfma_f32_16x16x32_bf16(a[m], b[n], acc[m][n], 0, 0, 0);
        if (t + 1 < nt) {
            __syncthreads();   // drains vmcnt (prefetch) + lgkmcnt; one barrier per K-step
            cur ^= 1;
        }
    }
#undef STAGE

    int lr = (lane >> 4) * 4;
    int lc = lane & 15;
    int crow0 = row0 + wr * 64;
    int ccol0 = col0 + wc * 64;
#pragma unroll
    for (int n = 0; n < 4; ++n) {
        int c = ccol0 + n * 16 + lc;
        float bv = BIAS ? bias[c] : 0.0f;
#pragma unroll
        for (int m = 0; m < 4; ++m) {
#pragma unroll
            for (int j = 0; j < 4; ++j) {
                int r = crow0 + m * 16 + lr + j;
                float v = acc[m][n][j] + bv;
                if (GELU) v = gelu_f(v);
                if (OUTBF) {
                    Yb[(size_t)r * ldyb + c] = __float2bfloat16(v);
                } else {
                    float* yp = Y + (size_t)r * ldy + c;
                    if (ACC) v += *yp;
                    *yp = v;
                }
            }
        }
    }
}

// ---------------- MFMA attention, barrier-free, XCD-swizzled ----------------
// 1D grid over (window p, head-group hg of 4); wave wv handles head h = hg*4+wv.
__global__ __launch_bounds__(256) void attn_mfma_kernel(
    const __hip_bfloat16* __restrict__ qkv,
    const float* __restrict__ biasT,
    __hip_bfloat16* __restrict__ o,
    int T, float scale, int nwin) {
    __shared__ __align__(16) short Vt[4][32][72];   // [wave][d][kt]  (V transposed)
    __shared__ __align__(16) short Pl[4][64][40];   // [wave][r][half-K cols]
    const int tid = threadIdx.x, lane = tid & 63, wv = tid >> 6;
    int p, hg;
    {
        int L = blockIdx.x;
        if (nwin & 7) { hg = L % 3; p = L / 3; }
        else { int r = L & 7, pos = L >> 3; hg = pos % 3; p = (pos / 3) * 8 + r; }
    }
    const int h = hg * 4 + wv;
    const short* q_base = (const short*)qkv + (size_t)p * T * N3;

    const int fr = lane & 15;
    const int fk = (lane >> 4) * 8;
    const int lg = lane >> 4;
    const int lc = lane & 15;

    // (1) issue Q,K fragment loads first (latency hides under V staging)
    short8v aq[4], bk[4];
#pragma unroll
    for (int m = 0; m < 4; ++m) {
        const short* qp = q_base + (size_t)(m * 16 + fr) * N3 + h * 32 + fk;
        aq[m] = *(const short8v*)qp;
        bk[m] = *(const short8v*)(qp + 384);
    }

    // (2) wave-local V staging (transposed), then zero the kt-tail
    for (int ch = lane; ch < T * 4; ch += 64) {
        int t = ch >> 2, cq = ch & 3;
        short8v v8 = *(const short8v*)(q_base + (size_t)t * N3 + 768 + h * 32 + cq * 8);
#pragma unroll
        for (int e = 0; e < 8; ++e) Vt[wv][cq * 8 + e][t] = v8[e];
    }
    for (int idx = lane; idx < (64 - T) * 32; idx += 64) {
        int t = T + (idx >> 5), d = idx & 31;
        Vt[wv][d][t] = 0;
    }

    // (3) S = Q @ K^T  (16 MFMAs, hd=32 -> single K-step)
    f32x4 acc[4][4] = {};
#pragma unroll
    for (int m = 0; m < 4; ++m)
#pragma unroll
        for (int n = 0; n < 4; ++n)
            acc[m][n] = __builtin_amdgcn_mfma_f32_16x16x32_bf16(aq[m], bk[n], acc[m][n], 0, 0, 0);

    // (4) in-register softmax; write P cols 0..31; keep cols 32..63 in regs
    const float* bh = biasT ? (biasT + (size_t)h * 4096) : nullptr;
    float p2[4][4], p3[4][4];
#pragma unroll
    for (int m = 0; m < 4; ++m) {
#pragma unroll
        for (int j = 0; j < 4; ++j) {
            int r = m * 16 + lg * 4 + j;
            float v[4];
            if (bh) {
                float4 bv4 = *(const float4*)(bh + r * 64 + lc * 4);
#pragma unroll
                for (int n = 0; n < 4; ++n) v[n] = acc[m][n][j] * scale + ((const float*)&bv4)[n];
            } else {
#pragma unroll
                for (int n = 0; n < 4; ++n) v[n] = acc[m][n][j] * scale;
            }
#pragma unroll
            for (int n = 0; n < 4; ++n)
                if (n * 16 + lc >= T) v[n] = -1e30f;
            float mx = fmaxf(fmaxf(v[0], v[1]), fmaxf(v[2], v[3]));
#pragma unroll
            for (int off = 1; off < 16; off <<= 1) mx = fmaxf(mx, __shfl_xor(mx, off));
            float s = 0.f;
#pragma unroll
            for (int n = 0; n < 4; ++n) { v[n] = __expf(v[n] - mx); s += v[n]; }
#pragma unroll
            for (int off = 1; off < 16; off <<= 1) s += __shfl_xor(s, off);
            float inv = 1.0f / s;
            Pl[wv][r][lc]      = bf16s(v[0] * inv);
            Pl[wv][r][16 + lc] = bf16s(v[1] * inv);
            p2[m][j] = v[2] * inv;
            p3[m][j] = v[3] * inv;
        }
    }

    // (5) O = P @ V, split-K halves through the half-size Pl buffer
    f32x4 oacc[4][2] = {};
    {
        short8v ap[4], bv[2];
#pragma unroll
        for (int m = 0; m < 4; ++m) ap[m] = *(const short8v*)&Pl[wv][m * 16 + fr][fk];
#pragma unroll
        for (int n = 0; n < 2; ++n) bv[n] = *(const short8v*)&Vt[wv][n * 16 + fr][fk];
#pragma unroll
        for (int m = 0; m < 4; ++m)
#pragma unroll
            for (int n = 0; n < 2; ++n)
                oacc[m][n] = __builtin_amdgcn_mfma_f32_16x16x32_bf16(ap[m], bv[n], oacc[m][n], 0, 0, 0);
    }
#pragma unroll
    for (int m = 0; m < 4; ++m)
#pragma unroll
        for (int j = 0; j < 4; ++j) {
            int r = m * 16 + lg * 4 + j;
            Pl[wv][r][lc]      = bf16s(p2[m][j]);
            Pl[wv][r][16 + lc] = bf16s(p3[m][j]);
        }
    {
        short8v ap[4], bv[2];
#pragma unroll
        for (int m = 0; m < 4; ++m) ap[m] = *(const short8v*)&Pl[wv][m * 16 + fr][fk];
#pragma unroll
        for (int n = 0; n < 2; ++n) bv[n] = *(const short8v*)&Vt[wv][n * 16 + fr][32 + fk];
#pragma unroll
        for (int m = 0; m < 4; ++m)
#pragma unroll
            for (int n = 0; n < 2; ++n)
                oacc[m][n] = __builtin_amdgcn_mfma_f32_16x16x32_bf16(ap[m], bv[n], oacc[m][n], 0, 0, 0);
    }

    short* ob = (short*)o;
#pragma unroll
    for (int m = 0; m < 4; ++m)
#pragma unroll
        for (int j = 0; j < 4; ++j) {
            int r = m * 16 + lg * 4 + j;
            if (r < T) {
#pragma unroll
                for (int n = 0; n < 2; ++n)
                    ob[((size_t)p * T + r) * CC + h * 32 + n * 16 + lc] = bf16s(oacc[m][n][j]);
            }
        }
}

// ---------------- host ----------------
extern "C" void kernel_launch(void* const* d_in, const int* in_sizes, int n_in,
                              void* d_out, int out_size, void* d_ws, size_t ws_size,
                              hipStream_t stream) {
    const float* cls_in   = (const float*)d_in[0];
    const float* patch_in = (const float*)d_in[1];
    const float* qkv_w    = (const float*)d_in[2];
    const float* qkv_b    = (const float*)d_in[3];
    const float* proj_w   = (const float*)d_in[4];
    const float* proj_b   = (const float*)d_in[5];
    const float* rel_pos  = (const float*)d_in[6];
    const float* ln0w = (const float*)d_in[7];
    const float* ln0b = (const float*)d_in[8];
    const float* ln1w = (const float*)d_in[9];
    const float* ln1b = (const float*)d_in[10];
    const float* ln2w = (const float*)d_in[11];
    const float* ln2b = (const float*)d_in[12];
    const float* w1 = (const float*)d_in[13];
    const float* b1 = (const float*)d_in[14];
    const float* w2 = (const float*)d_in[15];
    const float* b2 = (const float*)d_in[16];

    float* OUT = (float*)d_ws;
    size_t avail = ws_size / 4;

    const size_t OUT_F = 39321600;          // 2048*50*384 fp32 residual stream
    const size_t WB_F  = 1769472;           // bf16 weights (f32 slots)
    const size_t BT_F  = 49152;             // bias table 12*64*64 fp32
    __hip_bfloat16* WB = (__hip_bfloat16*)(OUT + OUT_F);
    __hip_bfloat16* qwb = WB;                                   // 2*1152*384
    __hip_bfloat16* pwb = WB + 884736;                          // 2*384*384
    __hip_bfloat16* w1b = WB + 1179648;                         // 2*1536*384
    __hip_bfloat16* w2b = WB + 2359296;                         // 2*384*1536
    float* biasTbuf = OUT + OUT_F + WB_F;

    int cw = 2048;
    // per-window f32 slots: Xb bf16 19200 -> 9600 ; QH union bf16 max(57600,76800) -> 38400
    while (cw > 64 && OUT_F + WB_F + BT_F + (size_t)cw * 48000 > avail) cw >>= 1;
    float* fbase = OUT + OUT_F + WB_F + BT_F;
    __hip_bfloat16* Xb = (__hip_bfloat16*)fbase;
    __hip_bfloat16* Qb = (__hip_bfloat16*)(fbase + (size_t)cw * 9600);
    __hip_bfloat16* Hb = Qb;   // MLP hidden reuses Qb region
    const float scale = 0.17677669529663687f;

    f2bf_kernel<<<dim3((884736 / 4 + 255) / 256), dim3(256), 0, stream>>>(qkv_w, qwb, 884736);
    f2bf_kernel<<<dim3((294912 / 4 + 255) / 256), dim3(256), 0, stream>>>(proj_w, pwb, 294912);
    f2bf_kernel<<<dim3((1179648 / 4 + 255) / 256), dim3(256), 0, stream>>>(w1, w1b, 1179648);
    f2bf_kernel<<<dim3((1179648 / 4 + 255) / 256), dim3(256), 0, stream>>>(w2, w2b, 1179648);

    pack_cls_kernel<<<dim3(BB * 6), dim3(256), 0, stream>>>(cls_in, OUT);
    pack_patch_kernel<<<dim3(BB * 56 * 6), dim3(256), 0, stream>>>(patch_in, OUT);

    for (int i = 0; i < NBB; ++i) {
        const __hip_bfloat16* qw = qwb + (size_t)i * N3 * CC;
        const float* qb = qkv_b + (size_t)i * N3;
        const __hip_bfloat16* pw = pwb + (size_t)i * CC * CC;
        const float* pb = proj_b + (size_t)i * CC;
        const float* rp = rel_pos + (size_t)i * NHH * 169;
        const __hip_bfloat16* w1i = w1b + (size_t)i * HIDD * CC;
        const float* b1i = b1 + (size_t)i * HIDD;
        const __hip_bfloat16* w2i = w2b + (size_t)i * CC * HIDD;
        const float* b2i = b2 + (size_t)i * CC;

        bias_precompute_kernel<<<dim3(NHH), dim3(256), 0, stream>>>(rp, biasTbuf);

        // ---- stage A: cls attention across 64 windows of each image (T=64) ----
        ln_kernel<<<dim3(2048 / 4), dim3(256), 0, stream>>>(OUT, LDOUT, ln0w + i * CC, ln0b + i * CC, Xb, CC, 2048);
        gemm_bf16_kernel<1, 0, 0, 1><<<dim3((N3 / 128) * (2048 / 128)), dim3(256), 0, stream>>>(
            Xb, CC, qw, qb, nullptr, 0, Qb, N3, 2048, N3, CC, N3 / 128);
        attn_mfma_kernel<<<dim3(BB * 3), dim3(256), 0, stream>>>(Qb, nullptr, Xb, 64, scale, BB);
        gemm_bf16_kernel<1, 0, 1, 0><<<dim3((CC / 128) * (2048 / 128)), dim3(256), 0, stream>>>(
            Xb, CC, pw, pb, OUT, LDOUT, nullptr, 0, 2048, CC, CC, CC / 128);

        // ---- stage B: windowed attention with rel-pos bias (T=50) ----
        for (int w0 = 0; w0 < NWW; w0 += cw) {
            float* outc = OUT + (size_t)w0 * LDOUT;
            int Mr = cw * NTT;
            ln_kernel<<<dim3(Mr / 4), dim3(256), 0, stream>>>(outc, CC, ln1w + i * CC, ln1b + i * CC, Xb, CC, Mr);
            gemm_bf16_kernel<1, 0, 0, 1><<<dim3((N3 / 128) * (Mr / 128)), dim3(256), 0, stream>>>(
                Xb, CC, qw, qb, nullptr, 0, Qb, N3, Mr, N3, CC, N3 / 128);
            attn_mfma_kernel<<<dim3(cw * 3), dim3(256), 0, stream>>>(Qb, biasTbuf, Xb, NTT, scale, cw);
            gemm_bf16_kernel<1, 0, 1, 0><<<dim3((CC / 128) * (Mr / 128)), dim3(256), 0, stream>>>(
                Xb, CC, pw, pb, outc, CC, nullptr, 0, Mr, CC, CC, CC / 128);
        }

        // ---- stage C: MLP ----
        for (int w0 = 0; w0 < NWW; w0 += cw) {
            float* outc = OUT + (size_t)w0 * LDOUT;
            int Mr = cw * NTT;
            ln_kernel<<<dim3(Mr / 4), dim3(256), 0, stream>>>(outc, CC, ln2w + i * CC, ln2b + i * CC, Xb, CC, Mr);
            gemm_bf16_kernel<1, 1, 0, 1><<<dim3((HIDD / 128) * (Mr / 128)), dim3(256), 0, stream>>>(
                Xb, CC, w1i, b1i, nullptr, 0, Hb, HIDD, Mr, HIDD, CC, HIDD / 128);
            gemm_bf16_kernel<1, 0, 1, 0><<<dim3((CC / 128) * (Mr / 128)), dim3(256), 0, stream>>>(
                Hb, HIDD, w2i, b2i, outc, CC, nullptr, 0, Mr, CC, HIDD, CC / 128);
        }
    }

    unpack_cls_kernel<<<dim3(BB * 6), dim3(256), 0, stream>>>(OUT, (float*)d_out);
    unpack_patch_kernel<<<dim3(BB * 56 * 6), dim3(256), 0, stream>>>(OUT, (float*)d_out + 786432);
}

// Round 6
// 2580.065 us; speedup vs baseline: 4.6491x; 1.0008x over previous
//
#include <hip/hip_runtime.h>
#include <hip/hip_bf16.h>
#include <cstdint>
#include <cstddef>

// ---- problem constants ----
#define BB    32
#define CC    384
#define NHH   12
#define HDD   32
#define WSS   7
#define HKK   8
#define NBB   2
#define HIDD  1536
#define NTT   50          // tokens per window (1 cls + 49 patch)
#define NWW   2048        // B*HK*HK windows
#define LDOUT 19200       // 50*384
#define N3    1152        // 3*C

typedef __attribute__((ext_vector_type(8))) short short8v;
typedef __attribute__((ext_vector_type(4))) float f32x4;

#if defined(__has_builtin)
#if __has_builtin(__builtin_amdgcn_global_load_lds)
#define HAS_GLDS 1
#endif
#endif
#ifndef HAS_GLDS
#define HAS_GLDS 0
#endif

static __device__ __forceinline__ float gelu_f(float x) {
    return 0.5f * x * (1.0f + erff(x * 0.70710678118654752440f));
}

static __device__ __forceinline__ short bf16s(float x) {
    __hip_bfloat16 b = __float2bfloat16(x);
    return *(short*)&b;
}

#if HAS_GLDS
static __device__ __forceinline__ void glds16(const short* g, short* l) {
    __builtin_amdgcn_global_load_lds(
        (const __attribute__((address_space(1))) unsigned int*)g,
        (__attribute__((address_space(3))) unsigned int*)l,
        16, 0, 0);
}
#endif

// XCD-aware decode: consecutive launched ids round-robin XCDs; keep all nx
// column-blocks of one row-panel on ONE XCD, temporally adjacent.
// Bijective when ny % 8 == 0 (all call sites), else identity fallback.
static __device__ __forceinline__ void swz_decode(int L, int nx, int ny, int& bx, int& by) {
    if (ny & 7) {
        bx = L % nx; by = L / nx;
    } else {
        int r = L & 7, pos = L >> 3;
        bx = pos % nx;
        by = (pos / nx) * 8 + r;
    }
}

// ---------------- pack / unpack (fp32) ----------------
__global__ void pack_cls_kernel(const float* __restrict__ cls, float* __restrict__ out) {
    __shared__ float lds[64][65];
    int bid = blockIdx.x;
    int b = bid / 6, cc = bid % 6, c0 = cc * 64;
    int tid = threadIdx.x;
    for (int idx = tid; idx < 64 * 64; idx += 256) {
        int k = idx & 63, cl = idx >> 6;
        lds[cl][k] = cls[((size_t)b * CC + c0 + cl) * 64 + k];
    }
    __syncthreads();
    for (int idx = tid; idx < 64 * 64; idx += 256) {
        int cl = idx & 63, k = idx >> 6;
        out[(size_t)(b * 64 + k) * LDOUT + c0 + cl] = lds[cl][k];
    }
}

__global__ void pack_patch_kernel(const float* __restrict__ patch, float* __restrict__ out) {
    __shared__ float lds[64][57];
    int bid = blockIdx.x;
    int b = bid / 336, rem = bid % 336;
    int y = rem / 6, cc = rem % 6, c0 = cc * 64;
    int tid = threadIdx.x;
    for (int idx = tid; idx < 64 * 56; idx += 256) {
        int cl = idx / 56, x = idx % 56;
        lds[cl][x] = patch[(((size_t)b * CC + c0 + cl) * 56 + y) * 56 + x];
    }
    __syncthreads();
    int wsy = y % 7, hky = y / 7;
    for (int idx = tid; idx < 64 * 56; idx += 256) {
        int cl = idx & 63, x = idx >> 6;
        int tok = 1 + wsy * 7 + (x % 7);
        int win = b * 64 + hky * 8 + (x / 7);
        out[((size_t)win * NTT + tok) * CC + c0 + cl] = lds[cl][x];
    }
}

__global__ void unpack_cls_kernel(const float* __restrict__ out, float* __restrict__ cls_out) {
    __shared__ float lds[64][65];
    int bid = blockIdx.x;
    int b = bid / 6, cc = bid % 6, c0 = cc * 64;
    int tid = threadIdx.x;
    for (int idx = tid; idx < 64 * 64; idx += 256) {
        int cl = idx & 63, k = idx >> 6;
        lds[cl][k] = out[(size_t)(b * 64 + k) * LDOUT + c0 + cl];
    }
    __syncthreads();
    for (int idx = tid; idx < 64 * 64; idx += 256) {
        int k = idx & 63, cl = idx >> 6;
        cls_out[((size_t)b * CC + c0 + cl) * 64 + k] = lds[cl][k];
    }
}

__global__ void unpack_patch_kernel(const float* __restrict__ out, float* __restrict__ patch_out) {
    __shared__ float lds[64][57];
    int bid = blockIdx.x;
    int b = bid / 336, rem = bid % 336;
    int y = rem / 6, cc = rem % 6, c0 = cc * 64;
    int tid = threadIdx.x;
    int wsy = y % 7, hky = y / 7;
    for (int idx = tid; idx < 64 * 56; idx += 256) {
        int cl = idx & 63, x = idx >> 6;
        int tok = 1 + wsy * 7 + (x % 7);
        int win = b * 64 + hky * 8 + (x / 7);
        lds[cl][x] = out[((size_t)win * NTT + tok) * CC + c0 + cl];
    }
    __syncthreads();
    for (int idx = tid; idx < 64 * 56; idx += 256) {
        int cl = idx / 56, x = idx % 56;
        patch_out[((size_t)b * CC + c0 + cl) * 3136 + y * 56 + x] = lds[cl][x];
    }
}

// ---------------- fp32 -> bf16 weight conversion ----------------
__global__ void f2bf_kernel(const float* __restrict__ in, __hip_bfloat16* __restrict__ out, int n) {
    int i = (blockIdx.x * 256 + threadIdx.x) * 4;
    if (i + 3 < n) {
        float4 v = *(const float4*)(in + i);
        out[i + 0] = __float2bfloat16(v.x);
        out[i + 1] = __float2bfloat16(v.y);
        out[i + 2] = __float2bfloat16(v.z);
        out[i + 3] = __float2bfloat16(v.w);
    } else {
        for (; i < n; ++i) out[i] = __float2bfloat16(in[i]);
    }
}

// ---------------- rel-pos bias table, fragment-ordered: [12][64 r][16 lc][4 n] fp32 ----------------
__global__ void bias_precompute_kernel(const float* __restrict__ rp, float* __restrict__ biasT) {
    int h = blockIdx.x;
    for (int idx = threadIdx.x; idx < 4096; idx += 256) {
        int qt = idx >> 6, kt = idx & 63;
        float v = 0.f;
        if (qt >= 1 && qt < NTT && kt >= 1 && kt < NTT) {
            int qp = qt - 1, kp = kt - 1;
            int qy = qp / 7, qx = qp - qy * 7;
            int ky = kp / 7, kx = kp - ky * 7;
            int ridx = ((ky - qy + 16) % 13) * 13 + ((kx - qx + 16) % 13);
            v = rp[h * 169 + ridx];
        }
        biasT[h * 4096 + qt * 64 + (kt & 15) * 4 + (kt >> 4)] = v;
    }
}

// ---------------- LayerNorm -> bf16 (float2-vectorized) ----------------
__global__ void ln_kernel(const float* __restrict__ x, int ldx,
                          const float* __restrict__ w, const float* __restrict__ b,
                          __hip_bfloat16* __restrict__ y, int ldy, int M) {
    int wave = threadIdx.x >> 6, lane = threadIdx.x & 63;
    int row = blockIdx.x * 4 + wave;
    if (row >= M) return;
    const float2* xr = (const float2*)(x + (size_t)row * ldx);
    float2 vals[3];
    float s = 0.f;
#pragma unroll
    for (int j = 0; j < 3; ++j) { vals[j] = xr[lane + j * 64]; s += vals[j].x + vals[j].y; }
#pragma unroll
    for (int off = 32; off > 0; off >>= 1) s += __shfl_xor(s, off);
    float mean = s * (1.0f / 384.0f);
    float vs = 0.f;
#pragma unroll
    for (int j = 0; j < 3; ++j) {
        float dx = vals[j].x - mean, dy = vals[j].y - mean;
        vs += dx * dx + dy * dy;
    }
#pragma unroll
    for (int off = 32; off > 0; off >>= 1) vs += __shfl_xor(vs, off);
    float inv = rsqrtf(vs * (1.0f / 384.0f) + 1e-6f);
    const float2* w2 = (const float2*)w;
    const float2* b2 = (const float2*)b;
    ushort* yr = (ushort*)(y + (size_t)row * ldy);
#pragma unroll
    for (int j = 0; j < 3; ++j) {
        int c = lane + j * 64;
        float2 wv = w2[c], bv = b2[c];
        ushort2 o;
        o.x = (ushort)bf16s((vals[j].x - mean) * inv * wv.x + bv.x);
        o.y = (ushort)bf16s((vals[j].y - mean) * inv * wv.y + bv.y);
        *(ushort2*)(yr + c * 2) = o;
    }
}

// ---------------- bf16 MFMA GEMM: Y = A[M,K] @ W[N,K]^T ----------------
// 128x128 tile, 4 waves (2x2), BK=32. 3-slot LDS ring, depth-2 prefetch with
// COUNTED vmcnt (never drains to 0 in-loop), raw barriers (T3+T4), setprio (T5),
// XCD-swizzled 1D grid.
//
// Hazard ledger (depth 2, 3 slots):
//  - iter t stages slot (t+2)%3 == slot (t-1)%3. All waves consumed buffer t-1
//    (lgkmcnt-complete before its MFMAs, which precede barrier B of t-1) and all
//    passed barrier B(t-1) before any wave reaches iter-t STAGE. Safe.
//  - vmcnt(8): waits my 4 loads of buffer t (2 newer stages * 4 loads remain).
//    Tail ladder: 4 when one stage outstanding, 0 on the last iter.
//  - barrier A after vmcnt: all waves' buffer-t loads landed before ds_read.
//  - sched_barrier(0) pins ds_read below barrier A and MFMA above barrier B.
template <int BIAS, int GELU, int ACC, int OUTBF>
__global__ __launch_bounds__(256) void gemm_bf16_kernel(
    const __hip_bfloat16* __restrict__ A, int lda,
    const __hip_bfloat16* __restrict__ W,
    const float* __restrict__ bias,
    float* __restrict__ Y, int ldy,
    __hip_bfloat16* __restrict__ Yb, int ldyb,
    int M, int N, int K, int nx) {
    __shared__ __align__(16) short As[3][128 * 32];
    __shared__ __align__(16) short Bs[3][128 * 32];
    int tid = threadIdx.x;
    int lane = tid & 63;
    int wid = tid >> 6;
    int wr = wid >> 1, wc = wid & 1;
    int bx, by;
    swz_decode(blockIdx.x, nx, M >> 7, bx, by);
    int row0 = by * 128, col0 = bx * 128;

    // staging: wave wid covers rows [wid*16, wid*16+16); lane -> (row=lane>>2, kq=lane&3)
    const short* Ag = (const short*)A + (size_t)(row0 + wid * 16 + (lane >> 2)) * lda + (lane & 3) * 8;
    const short* Wg = (const short*)W + (size_t)(col0 + wid * 16 + (lane >> 2)) * K + (lane & 3) * 8;
    size_t astep = (size_t)64 * lda;
    size_t wstep = (size_t)64 * K;
    int ldsoff = wid * 16 * 32;   // wave-uniform; HW adds lane*16B (== row-major layout)

#if HAS_GLDS
#define STAGE(buf, k0)                                      \
    do {                                                    \
        glds16(Ag + (k0), &As[buf][ldsoff]);                \
        glds16(Ag + astep + (k0), &As[buf][64 * 32 + ldsoff]); \
        glds16(Wg + (k0), &Bs[buf][ldsoff]);                \
        glds16(Wg + wstep + (k0), &Bs[buf][64 * 32 + ldsoff]); \
    } while (0)
#else
#define STAGE(buf, k0)                                                          \
    do {                                                                        \
        *(short8v*)(&As[buf][ldsoff] + lane * 8) = *(const short8v*)(Ag + (k0)); \
        *(short8v*)(&As[buf][64 * 32 + ldsoff] + lane * 8) = *(const short8v*)(Ag + astep + (k0)); \
        *(short8v*)(&Bs[buf][ldsoff] + lane * 8) = *(const short8v*)(Wg + (k0)); \
        *(short8v*)(&Bs[buf][64 * 32 + ldsoff] + lane * 8) = *(const short8v*)(Wg + wstep + (k0)); \
    } while (0)
#endif

    f32x4 acc[4][4] = {};
    int frow_a = wr * 64 + (lane & 15);
    int frow_b = wc * 64 + (lane & 15);
    int fk = (lane >> 4) * 8;

    int nt = K >> 5;
#if HAS_GLDS
    // -------- counted-vmcnt pipeline --------
    STAGE(0, 0);
    if (nt > 1) STAGE(1, 32);
    int sc = 0;   // slot holding K-tile t
    for (int t = 0; t < nt; ++t) {
        int sn = sc + 2; if (sn >= 3) sn -= 3;
        if (t + 2 < nt) {
            STAGE(sn, (t + 2) << 5);
            asm volatile("s_waitcnt vmcnt(8)" ::: "memory");
        } else if (t + 1 < nt) {
            asm volatile("s_waitcnt vmcnt(4)" ::: "memory");
        } else {
            asm volatile("s_waitcnt vmcnt(0)" ::: "memory");
        }
        __builtin_amdgcn_s_barrier();          // A: everyone's tile-t loads landed
        __builtin_amdgcn_sched_barrier(0);
        short8v a[4], b[4];
#pragma unroll
        for (int m = 0; m < 4; ++m) a[m] = *(const short8v*)&As[sc][(frow_a + m * 16) * 32 + fk];
#pragma unroll
        for (int n = 0; n < 4; ++n) b[n] = *(const short8v*)&Bs[sc][(frow_b + n * 16) * 32 + fk];
        __builtin_amdgcn_s_setprio(1);
#pragma unroll
        for (int m = 0; m < 4; ++m)
#pragma unroll
            for (int n = 0; n < 4; ++n)
                acc[m][n] = __builtin_amdgcn_mfma_f32_16x16x32_bf16(a[m], b[n], acc[m][n], 0, 0, 0);
        __builtin_amdgcn_s_setprio(0);
        __builtin_amdgcn_sched_barrier(0);
        __builtin_amdgcn_s_barrier();          // B: all waves consumed tile t
        ++sc; if (sc >= 3) sc = 0;
    }
#else
    // -------- fallback: reg staging + __syncthreads (2 slots of the ring) --------
    STAGE(0, 0);
    __syncthreads();
    int cur = 0;
    for (int t = 0; t < nt; ++t) {
        if (t + 1 < nt) STAGE(cur ^ 1, (t + 1) << 5);
        short8v a[4], b[4];
#pragma unroll
        for (int m = 0; m < 4; ++m) a[m] = *(const short8v*)&As[cur][(frow_a + m * 16) * 32 + fk];
#pragma unroll
        for (int n = 0; n < 4; ++n) b[n] = *(const short8v*)&Bs[cur][(frow_b + n * 16) * 32 + fk];
#pragma unroll
        for (int m = 0; m < 4; ++m)
#pragma unroll
            for (int n = 0; n < 4; ++n)
                acc[m][n] = __builtin_amdgcn_mfma_f32_16x16x32_bf16(a[m], b[n], acc[m][n], 0, 0, 0);
        if (t + 1 < nt) { __syncthreads(); cur ^= 1; }
    }
#endif
#undef STAGE

    int lr = (lane >> 4) * 4;
    int lc = lane & 15;
    int crow0 = row0 + wr * 64;
    int ccol0 = col0 + wc * 64;
#pragma unroll
    for (int n = 0; n < 4; ++n) {
        int c = ccol0 + n * 16 + lc;
        float bv = BIAS ? bias[c] : 0.0f;
#pragma unroll
        for (int m = 0; m < 4; ++m) {
#pragma unroll
            for (int j = 0; j < 4; ++j) {
                int r = crow0 + m * 16 + lr + j;
                float v = acc[m][n][j] + bv;
                if (GELU) v = gelu_f(v);
                if (OUTBF) {
                    Yb[(size_t)r * ldyb + c] = __float2bfloat16(v);
                } else {
                    float* yp = Y + (size_t)r * ldy + c;
                    if (ACC) v += *yp;
                    *yp = v;
                }
            }
        }
    }
}

// ---------------- MFMA attention, barrier-free, XCD-swizzled ----------------
// 1D grid over (window p, head-group hg of 4); wave wv handles head h = hg*4+wv.
__global__ __launch_bounds__(256) void attn_mfma_kernel(
    const __hip_bfloat16* __restrict__ qkv,
    const float* __restrict__ biasT,
    __hip_bfloat16* __restrict__ o,
    int T, float scale, int nwin) {
    __shared__ __align__(16) short Vt[4][32][72];   // [wave][d][kt]  (V transposed)
    __shared__ __align__(16) short Pl[4][64][40];   // [wave][r][half-K cols]
    const int tid = threadIdx.x, lane = tid & 63, wv = tid >> 6;
    int p, hg;
    {
        int L = blockIdx.x;
        if (nwin & 7) { hg = L % 3; p = L / 3; }
        else { int r = L & 7, pos = L >> 3; hg = pos % 3; p = (pos / 3) * 8 + r; }
    }
    const int h = hg * 4 + wv;
    const short* q_base = (const short*)qkv + (size_t)p * T * N3;

    const int fr = lane & 15;
    const int fk = (lane >> 4) * 8;
    const int lg = lane >> 4;
    const int lc = lane & 15;

    // (1) issue Q,K fragment loads first (latency hides under V staging)
    short8v aq[4], bk[4];
#pragma unroll
    for (int m = 0; m < 4; ++m) {
        const short* qp = q_base + (size_t)(m * 16 + fr) * N3 + h * 32 + fk;
        aq[m] = *(const short8v*)qp;
        bk[m] = *(const short8v*)(qp + 384);
    }

    // (2) wave-local V staging (transposed), then zero the kt-tail
    for (int ch = lane; ch < T * 4; ch += 64) {
        int t = ch >> 2, cq = ch & 3;
        short8v v8 = *(const short8v*)(q_base + (size_t)t * N3 + 768 + h * 32 + cq * 8);
#pragma unroll
        for (int e = 0; e < 8; ++e) Vt[wv][cq * 8 + e][t] = v8[e];
    }
    for (int idx = lane; idx < (64 - T) * 32; idx += 64) {
        int t = T + (idx >> 5), d = idx & 31;
        Vt[wv][d][t] = 0;
    }

    // (3) S = Q @ K^T  (16 MFMAs, hd=32 -> single K-step)
    f32x4 acc[4][4] = {};
#pragma unroll
    for (int m = 0; m < 4; ++m)
#pragma unroll
        for (int n = 0; n < 4; ++n)
            acc[m][n] = __builtin_amdgcn_mfma_f32_16x16x32_bf16(aq[m], bk[n], acc[m][n], 0, 0, 0);

    // (4) in-register softmax; write P cols 0..31; keep cols 32..63 in regs
    const float* bh = biasT ? (biasT + (size_t)h * 4096) : nullptr;
    float p2[4][4], p3[4][4];
#pragma unroll
    for (int m = 0; m < 4; ++m) {
#pragma unroll
        for (int j = 0; j < 4; ++j) {
            int r = m * 16 + lg * 4 + j;
            float v[4];
            if (bh) {
                float4 bv4 = *(const float4*)(bh + r * 64 + lc * 4);
#pragma unroll
                for (int n = 0; n < 4; ++n) v[n] = acc[m][n][j] * scale + ((const float*)&bv4)[n];
            } else {
#pragma unroll
                for (int n = 0; n < 4; ++n) v[n] = acc[m][n][j] * scale;
            }
#pragma unroll
            for (int n = 0; n < 4; ++n)
                if (n * 16 + lc >= T) v[n] = -1e30f;
            float mx = fmaxf(fmaxf(v[0], v[1]), fmaxf(v[2], v[3]));
#pragma unroll
            for (int off = 1; off < 16; off <<= 1) mx = fmaxf(mx, __shfl_xor(mx, off));
            float s = 0.f;
#pragma unroll
            for (int n = 0; n < 4; ++n) { v[n] = __expf(v[n] - mx); s += v[n]; }
#pragma unroll
            for (int off = 1; off < 16; off <<= 1) s += __shfl_xor(s, off);
            float inv = 1.0f / s;
            Pl[wv][r][lc]      = bf16s(v[0] * inv);
            Pl[wv][r][16 + lc] = bf16s(v[1] * inv);
            p2[m][j] = v[2] * inv;
            p3[m][j] = v[3] * inv;
        }
    }

    // (5) O = P @ V, split-K halves through the half-size Pl buffer
    f32x4 oacc[4][2] = {};
    {
        short8v ap[4], bv[2];
#pragma unroll
        for (int m = 0; m < 4; ++m) ap[m] = *(const short8v*)&Pl[wv][m * 16 + fr][fk];
#pragma unroll
        for (int n = 0; n < 2; ++n) bv[n] = *(const short8v*)&Vt[wv][n * 16 + fr][fk];
#pragma unroll
        for (int m = 0; m < 4; ++m)
#pragma unroll
            for (int n = 0; n < 2; ++n)
                oacc[m][n] = __builtin_amdgcn_mfma_f32_16x16x32_bf16(ap[m], bv[n], oacc[m][n], 0, 0, 0);
    }
#pragma unroll
    for (int m = 0; m < 4; ++m)
#pragma unroll
        for (int j = 0; j < 4; ++j) {
            int r = m * 16 + lg * 4 + j;
            Pl[wv][r][lc]      = bf16s(p2[m][j]);
            Pl[wv][r][16 + lc] = bf16s(p3[m][j]);
        }
    {
        short8v ap[4], bv[2];
#pragma unroll
        for (int m = 0; m < 4; ++m) ap[m] = *(const short8v*)&Pl[wv][m * 16 + fr][fk];
#pragma unroll
        for (int n = 0; n < 2; ++n) bv[n] = *(const short8v*)&Vt[wv][n * 16 + fr][32 + fk];
#pragma unroll
        for (int m = 0; m < 4; ++m)
#pragma unroll
            for (int n = 0; n < 2; ++n)
                oacc[m][n] = __builtin_amdgcn_mfma_f32_16x16x32_bf16(ap[m], bv[n], oacc[m][n], 0, 0, 0);
    }

    short* ob = (short*)o;
#pragma unroll
    for (int m = 0; m < 4; ++m)
#pragma unroll
        for (int j = 0; j < 4; ++j) {
            int r = m * 16 + lg * 4 + j;
            if (r < T) {
#pragma unroll
                for (int n = 0; n < 2; ++n)
                    ob[((size_t)p * T + r) * CC + h * 32 + n * 16 + lc] = bf16s(oacc[m][n][j]);
            }
        }
}

// ---------------- host ----------------
extern "C" void kernel_launch(void* const* d_in, const int* in_sizes, int n_in,
                              void* d_out, int out_size, void* d_ws, size_t ws_size,
                              hipStream_t stream) {
    const float* cls_in   = (const float*)d_in[0];
    const float* patch_in = (const float*)d_in[1];
    const float* qkv_w    = (const float*)d_in[2];
    const float* qkv_b    = (const float*)d_in[3];
    const float* proj_w   = (const float*)d_in[4];
    const float* proj_b   = (const float*)d_in[5];
    const float* rel_pos  = (const float*)d_in[6];
    const float* ln0w = (const float*)d_in[7];
    const float* ln0b = (const float*)d_in[8];
    const float* ln1w = (const float*)d_in[9];
    const float* ln1b = (const float*)d_in[10];
    const float* ln2w = (const float*)d_in[11];
    const float* ln2b = (const float*)d_in[12];
    const float* w1 = (const float*)d_in[13];
    const float* b1 = (const float*)d_in[14];
    const float* w2 = (const float*)d_in[15];
    const float* b2 = (const float*)d_in[16];

    float* OUT = (float*)d_ws;
    size_t avail = ws_size / 4;

    const size_t OUT_F = 39321600;          // 2048*50*384 fp32 residual stream
    const size_t WB_F  = 1769472;           // bf16 weights (f32 slots)
    const size_t BT_F  = 49152;             // bias table 12*64*64 fp32
    __hip_bfloat16* WB = (__hip_bfloat16*)(OUT + OUT_F);
    __hip_bfloat16* qwb = WB;                                   // 2*1152*384
    __hip_bfloat16* pwb = WB + 884736;                          // 2*384*384
    __hip_bfloat16* w1b = WB + 1179648;                         // 2*1536*384
    __hip_bfloat16* w2b = WB + 2359296;                         // 2*384*1536
    float* biasTbuf = OUT + OUT_F + WB_F;

    int cw = 2048;
    // per-window f32 slots: Xb bf16 19200 -> 9600 ; QH union bf16 max(57600,76800) -> 38400
    while (cw > 64 && OUT_F + WB_F + BT_F + (size_t)cw * 48000 > avail) cw >>= 1;
    float* fbase = OUT + OUT_F + WB_F + BT_F;
    __hip_bfloat16* Xb = (__hip_bfloat16*)fbase;
    __hip_bfloat16* Qb = (__hip_bfloat16*)(fbase + (size_t)cw * 9600);
    __hip_bfloat16* Hb = Qb;   // MLP hidden reuses Qb region
    const float scale = 0.17677669529663687f;

    f2bf_kernel<<<dim3((884736 / 4 + 255) / 256), dim3(256), 0, stream>>>(qkv_w, qwb, 884736);
    f2bf_kernel<<<dim3((294912 / 4 + 255) / 256), dim3(256), 0, stream>>>(proj_w, pwb, 294912);
    f2bf_kernel<<<dim3((1179648 / 4 + 255) / 256), dim3(256), 0, stream>>>(w1, w1b, 1179648);
    f2bf_kernel<<<dim3((1179648 / 4 + 255) / 256), dim3(256), 0, stream>>>(w2, w2b, 1179648);

    pack_cls_kernel<<<dim3(BB * 6), dim3(256), 0, stream>>>(cls_in, OUT);
    pack_patch_kernel<<<dim3(BB * 56 * 6), dim3(256), 0, stream>>>(patch_in, OUT);

    for (int i = 0; i < NBB; ++i) {
        const __hip_bfloat16* qw = qwb + (size_t)i * N3 * CC;
        const float* qb = qkv_b + (size_t)i * N3;
        const __hip_bfloat16* pw = pwb + (size_t)i * CC * CC;
        const float* pb = proj_b + (size_t)i * CC;
        const float* rp = rel_pos + (size_t)i * NHH * 169;
        const __hip_bfloat16* w1i = w1b + (size_t)i * HIDD * CC;
        const float* b1i = b1 + (size_t)i * HIDD;
        const __hip_bfloat16* w2i = w2b + (size_t)i * CC * HIDD;
        const float* b2i = b2 + (size_t)i * CC;

        bias_precompute_kernel<<<dim3(NHH), dim3(256), 0, stream>>>(rp, biasTbuf);

        // ---- stage A: cls attention across 64 windows of each image (T=64) ----
        ln_kernel<<<dim3(2048 / 4), dim3(256), 0, stream>>>(OUT, LDOUT, ln0w + i * CC, ln0b + i * CC, Xb, CC, 2048);
        gemm_bf16_kernel<1, 0, 0, 1><<<dim3((N3 / 128) * (2048 / 128)), dim3(256), 0, stream>>>(
            Xb, CC, qw, qb, nullptr, 0, Qb, N3, 2048, N3, CC, N3 / 128);
        attn_mfma_kernel<<<dim3(BB * 3), dim3(256), 0, stream>>>(Qb, nullptr, Xb, 64, scale, BB);
        gemm_bf16_kernel<1, 0, 1, 0><<<dim3((CC / 128) * (2048 / 128)), dim3(256), 0, stream>>>(
            Xb, CC, pw, pb, OUT, LDOUT, nullptr, 0, 2048, CC, CC, CC / 128);

        // ---- stage B: windowed attention with rel-pos bias (T=50) ----
        for (int w0 = 0; w0 < NWW; w0 += cw) {
            float* outc = OUT + (size_t)w0 * LDOUT;
            int Mr = cw * NTT;
            ln_kernel<<<dim3(Mr / 4), dim3(256), 0, stream>>>(outc, CC, ln1w + i * CC, ln1b + i * CC, Xb, CC, Mr);
            gemm_bf16_kernel<1, 0, 0, 1><<<dim3((N3 / 128) * (Mr / 128)), dim3(256), 0, stream>>>(
                Xb, CC, qw, qb, nullptr, 0, Qb, N3, Mr, N3, CC, N3 / 128);
            attn_mfma_kernel<<<dim3(cw * 3), dim3(256), 0, stream>>>(Qb, biasTbuf, Xb, NTT, scale, cw);
            gemm_bf16_kernel<1, 0, 1, 0><<<dim3((CC / 128) * (Mr / 128)), dim3(256), 0, stream>>>(
                Xb, CC, pw, pb, outc, CC, nullptr, 0, Mr, CC, CC, CC / 128);
        }

        // ---- stage C: MLP ----
        for (int w0 = 0; w0 < NWW; w0 += cw) {
            float* outc = OUT + (size_t)w0 * LDOUT;
            int Mr = cw * NTT;
            ln_kernel<<<dim3(Mr / 4), dim3(256), 0, stream>>>(outc, CC, ln2w + i * CC, ln2b + i * CC, Xb, CC, Mr);
            gemm_bf16_kernel<1, 1, 0, 1><<<dim3((HIDD / 128) * (Mr / 128)), dim3(256), 0, stream>>>(
                Xb, CC, w1i, b1i, nullptr, 0, Hb, HIDD, Mr, HIDD, CC, HIDD / 128);
            gemm_bf16_kernel<1, 0, 1, 0><<<dim3((CC / 128) * (Mr / 128)), dim3(256), 0, stream>>>(
                Hb, HIDD, w2i, b2i, outc, CC, nullptr, 0, Mr, CC, HIDD, CC / 128);
        }
    }

    unpack_cls_kernel<<<dim3(BB * 6), dim3(256), 0, stream>>>(OUT, (float*)d_out);
    unpack_patch_kernel<<<dim3(BB * 56 * 6), dim3(256), 0, stream>>>(OUT, (float*)d_out + 786432);
}

// Round 7
// 2118.208 us; speedup vs baseline: 5.6628x; 1.2180x over previous
//
#include <hip/hip_runtime.h>
#include <hip/hip_bf16.h>
#include <cstdint>
#include <cstddef>

// ---- problem constants ----
#define BB    32
#define CC    384
#define NHH   12
#define HDD   32
#define WSS   7
#define HKK   8
#define NBB   2
#define HIDD  1536
#define NTT   50          // tokens per window (1 cls + 49 patch)
#define NWW   2048        // B*HK*HK windows
#define LDOUT 19200       // 50*384
#define N3    1152        // 3*C

typedef __attribute__((ext_vector_type(8))) short short8v;
typedef __attribute__((ext_vector_type(4))) float f32x4;

#if defined(__has_builtin)
#if __has_builtin(__builtin_amdgcn_global_load_lds)
#define HAS_GLDS 1
#endif
#endif
#ifndef HAS_GLDS
#define HAS_GLDS 0
#endif

static __device__ __forceinline__ float gelu_f(float x) {
    return 0.5f * x * (1.0f + erff(x * 0.70710678118654752440f));
}

static __device__ __forceinline__ short bf16s(float x) {
    __hip_bfloat16 b = __float2bfloat16(x);
    return *(short*)&b;
}

#if HAS_GLDS
static __device__ __forceinline__ void glds16(const short* g, short* l) {
    __builtin_amdgcn_global_load_lds(
        (const __attribute__((address_space(1))) unsigned int*)g,
        (__attribute__((address_space(3))) unsigned int*)l,
        16, 0, 0);
}
#endif

// XCD-aware decode: consecutive launched ids round-robin XCDs; keep all nx
// column-blocks of one row-panel on ONE XCD, temporally adjacent.
static __device__ __forceinline__ void swz_decode(int L, int nx, int ny, int& bx, int& by) {
    if (ny & 7) {
        bx = L % nx; by = L / nx;
    } else {
        int r = L & 7, pos = L >> 3;
        bx = pos % nx;
        by = (pos / nx) * 8 + r;
    }
}

// ---------------- pack / unpack (fp32) ----------------
__global__ void pack_cls_kernel(const float* __restrict__ cls, float* __restrict__ out) {
    __shared__ float lds[64][65];
    int bid = blockIdx.x;
    int b = bid / 6, cc = bid % 6, c0 = cc * 64;
    int tid = threadIdx.x;
    for (int idx = tid; idx < 64 * 64; idx += 256) {
        int k = idx & 63, cl = idx >> 6;
        lds[cl][k] = cls[((size_t)b * CC + c0 + cl) * 64 + k];
    }
    __syncthreads();
    for (int idx = tid; idx < 64 * 64; idx += 256) {
        int cl = idx & 63, k = idx >> 6;
        out[(size_t)(b * 64 + k) * LDOUT + c0 + cl] = lds[cl][k];
    }
}

__global__ void pack_patch_kernel(const float* __restrict__ patch, float* __restrict__ out) {
    __shared__ float lds[64][57];
    int bid = blockIdx.x;
    int b = bid / 336, rem = bid % 336;
    int y = rem / 6, cc = rem % 6, c0 = cc * 64;
    int tid = threadIdx.x;
    for (int idx = tid; idx < 64 * 56; idx += 256) {
        int cl = idx / 56, x = idx % 56;
        lds[cl][x] = patch[(((size_t)b * CC + c0 + cl) * 56 + y) * 56 + x];
    }
    __syncthreads();
    int wsy = y % 7, hky = y / 7;
    for (int idx = tid; idx < 64 * 56; idx += 256) {
        int cl = idx & 63, x = idx >> 6;
        int tok = 1 + wsy * 7 + (x % 7);
        int win = b * 64 + hky * 8 + (x / 7);
        out[((size_t)win * NTT + tok) * CC + c0 + cl] = lds[cl][x];
    }
}

__global__ void unpack_cls_kernel(const float* __restrict__ out, float* __restrict__ cls_out) {
    __shared__ float lds[64][65];
    int bid = blockIdx.x;
    int b = bid / 6, cc = bid % 6, c0 = cc * 64;
    int tid = threadIdx.x;
    for (int idx = tid; idx < 64 * 64; idx += 256) {
        int cl = idx & 63, k = idx >> 6;
        lds[cl][k] = out[(size_t)(b * 64 + k) * LDOUT + c0 + cl];
    }
    __syncthreads();
    for (int idx = tid; idx < 64 * 64; idx += 256) {
        int k = idx & 63, cl = idx >> 6;
        cls_out[((size_t)b * CC + c0 + cl) * 64 + k] = lds[cl][k];
    }
}

__global__ void unpack_patch_kernel(const float* __restrict__ out, float* __restrict__ patch_out) {
    __shared__ float lds[64][57];
    int bid = blockIdx.x;
    int b = bid / 336, rem = bid % 336;
    int y = rem / 6, cc = rem % 6, c0 = cc * 64;
    int tid = threadIdx.x;
    int wsy = y % 7, hky = y / 7;
    for (int idx = tid; idx < 64 * 56; idx += 256) {
        int cl = idx & 63, x = idx >> 6;
        int tok = 1 + wsy * 7 + (x % 7);
        int win = b * 64 + hky * 8 + (x / 7);
        lds[cl][x] = out[((size_t)win * NTT + tok) * CC + c0 + cl];
    }
    __syncthreads();
    for (int idx = tid; idx < 64 * 56; idx += 256) {
        int cl = idx / 56, x = idx % 56;
        patch_out[((size_t)b * CC + c0 + cl) * 3136 + y * 56 + x] = lds[cl][x];
    }
}

// ---------------- fp32 -> bf16 weight conversion ----------------
__global__ void f2bf_kernel(const float* __restrict__ in, __hip_bfloat16* __restrict__ out, int n) {
    int i = (blockIdx.x * 256 + threadIdx.x) * 4;
    if (i + 3 < n) {
        float4 v = *(const float4*)(in + i);
        out[i + 0] = __float2bfloat16(v.x);
        out[i + 1] = __float2bfloat16(v.y);
        out[i + 2] = __float2bfloat16(v.z);
        out[i + 3] = __float2bfloat16(v.w);
    } else {
        for (; i < n; ++i) out[i] = __float2bfloat16(in[i]);
    }
}

// ---------------- rel-pos bias table, fragment-ordered: [12][64 r][16 lc][4 n] fp32 ----------------
__global__ void bias_precompute_kernel(const float* __restrict__ rp, float* __restrict__ biasT) {
    int h = blockIdx.x;
    for (int idx = threadIdx.x; idx < 4096; idx += 256) {
        int qt = idx >> 6, kt = idx & 63;
        float v = 0.f;
        if (qt >= 1 && qt < NTT && kt >= 1 && kt < NTT) {
            int qp = qt - 1, kp = kt - 1;
            int qy = qp / 7, qx = qp - qy * 7;
            int ky = kp / 7, kx = kp - ky * 7;
            int ridx = ((ky - qy + 16) % 13) * 13 + ((kx - qx + 16) % 13);
            v = rp[h * 169 + ridx];
        }
        biasT[h * 4096 + qt * 64 + (kt & 15) * 4 + (kt >> 4)] = v;
    }
}

// ---------------- LayerNorm -> bf16 (float2-vectorized) ----------------
__global__ void ln_kernel(const float* __restrict__ x, int ldx,
                          const float* __restrict__ w, const float* __restrict__ b,
                          __hip_bfloat16* __restrict__ y, int ldy, int M) {
    int wave = threadIdx.x >> 6, lane = threadIdx.x & 63;
    int row = blockIdx.x * 4 + wave;
    if (row >= M) return;
    const float2* xr = (const float2*)(x + (size_t)row * ldx);
    float2 vals[3];
    float s = 0.f;
#pragma unroll
    for (int j = 0; j < 3; ++j) { vals[j] = xr[lane + j * 64]; s += vals[j].x + vals[j].y; }
#pragma unroll
    for (int off = 32; off > 0; off >>= 1) s += __shfl_xor(s, off);
    float mean = s * (1.0f / 384.0f);
    float vs = 0.f;
#pragma unroll
    for (int j = 0; j < 3; ++j) {
        float dx = vals[j].x - mean, dy = vals[j].y - mean;
        vs += dx * dx + dy * dy;
    }
#pragma unroll
    for (int off = 32; off > 0; off >>= 1) vs += __shfl_xor(vs, off);
    float inv = rsqrtf(vs * (1.0f / 384.0f) + 1e-6f);
    const float2* w2 = (const float2*)w;
    const float2* b2 = (const float2*)b;
    ushort* yr = (ushort*)(y + (size_t)row * ldy);
#pragma unroll
    for (int j = 0; j < 3; ++j) {
        int c = lane + j * 64;
        float2 wv = w2[c], bv = b2[c];
        ushort2 o;
        o.x = (ushort)bf16s((vals[j].x - mean) * inv * wv.x + bv.x);
        o.y = (ushort)bf16s((vals[j].y - mean) * inv * wv.y + bv.y);
        *(ushort2*)(yr + c * 2) = o;
    }
}

// ---------------- bf16 MFMA GEMM: Y = A[M,K] @ W[N,K]^T ----------------
// 128x128 tile, 4 waves (2x2), BK=32, 3-slot counted-vmcnt pipeline,
// XCD-swizzled 1D grid. Epilogue: LDS-staged COALESCED stores (the staging
// ring is dead after the K-loop; union-overlaid output buffer, zero extra LDS).
template <int BIAS, int GELU, int ACC, int OUTBF>
__global__ __launch_bounds__(256) void gemm_bf16_kernel(
    const __hip_bfloat16* __restrict__ A, int lda,
    const __hip_bfloat16* __restrict__ W,
    const float* __restrict__ bias,
    float* __restrict__ Y, int ldy,
    __hip_bfloat16* __restrict__ Yb, int ldyb,
    int M, int N, int K, int nx) {
    __shared__ __align__(16) union SMemU {
        struct { short As[3][128 * 32]; short Bs[3][128 * 32]; } st;  // 48 KB staging ring
        short obf[128][132];   // 33.8 KB bf16 output tile (pad 132: conflict-free)
        float off[64][132];    // 33.8 KB fp32 half-tile
    } sm;
    int tid = threadIdx.x;
    int lane = tid & 63;
    int wid = tid >> 6;
    int wr = wid >> 1, wc = wid & 1;
    int bx, by;
    swz_decode(blockIdx.x, nx, M >> 7, bx, by);
    int row0 = by * 128, col0 = bx * 128;

    const short* Ag = (const short*)A + (size_t)(row0 + wid * 16 + (lane >> 2)) * lda + (lane & 3) * 8;
    const short* Wg = (const short*)W + (size_t)(col0 + wid * 16 + (lane >> 2)) * K + (lane & 3) * 8;
    size_t astep = (size_t)64 * lda;
    size_t wstep = (size_t)64 * K;
    int ldsoff = wid * 16 * 32;   // wave-uniform; HW adds lane*16B

#if HAS_GLDS
#define STAGE(buf, k0)                                            \
    do {                                                          \
        glds16(Ag + (k0), &sm.st.As[buf][ldsoff]);                \
        glds16(Ag + astep + (k0), &sm.st.As[buf][64 * 32 + ldsoff]); \
        glds16(Wg + (k0), &sm.st.Bs[buf][ldsoff]);                \
        glds16(Wg + wstep + (k0), &sm.st.Bs[buf][64 * 32 + ldsoff]); \
    } while (0)
#else
#define STAGE(buf, k0)                                                             \
    do {                                                                           \
        *(short8v*)(&sm.st.As[buf][ldsoff] + lane * 8) = *(const short8v*)(Ag + (k0)); \
        *(short8v*)(&sm.st.As[buf][64 * 32 + ldsoff] + lane * 8) = *(const short8v*)(Ag + astep + (k0)); \
        *(short8v*)(&sm.st.Bs[buf][ldsoff] + lane * 8) = *(const short8v*)(Wg + (k0)); \
        *(short8v*)(&sm.st.Bs[buf][64 * 32 + ldsoff] + lane * 8) = *(const short8v*)(Wg + wstep + (k0)); \
    } while (0)
#endif

    f32x4 acc[4][4] = {};
    int frow_a = wr * 64 + (lane & 15);
    int frow_b = wc * 64 + (lane & 15);
    int fk = (lane >> 4) * 8;

    int nt = K >> 5;
#if HAS_GLDS
    STAGE(0, 0);
    if (nt > 1) STAGE(1, 32);
    int sc = 0;
    for (int t = 0; t < nt; ++t) {
        int sn = sc + 2; if (sn >= 3) sn -= 3;
        if (t + 2 < nt) {
            STAGE(sn, (t + 2) << 5);
            asm volatile("s_waitcnt vmcnt(8)" ::: "memory");
        } else if (t + 1 < nt) {
            asm volatile("s_waitcnt vmcnt(4)" ::: "memory");
        } else {
            asm volatile("s_waitcnt vmcnt(0)" ::: "memory");
        }
        __builtin_amdgcn_s_barrier();
        __builtin_amdgcn_sched_barrier(0);
        short8v a[4], b[4];
#pragma unroll
        for (int m = 0; m < 4; ++m) a[m] = *(const short8v*)&sm.st.As[sc][(frow_a + m * 16) * 32 + fk];
#pragma unroll
        for (int n = 0; n < 4; ++n) b[n] = *(const short8v*)&sm.st.Bs[sc][(frow_b + n * 16) * 32 + fk];
        __builtin_amdgcn_s_setprio(1);
#pragma unroll
        for (int m = 0; m < 4; ++m)
#pragma unroll
            for (int n = 0; n < 4; ++n)
                acc[m][n] = __builtin_amdgcn_mfma_f32_16x16x32_bf16(a[m], b[n], acc[m][n], 0, 0, 0);
        __builtin_amdgcn_s_setprio(0);
        __builtin_amdgcn_sched_barrier(0);
        __builtin_amdgcn_s_barrier();
        ++sc; if (sc >= 3) sc = 0;
    }
#else
    STAGE(0, 0);
    __syncthreads();
    int cur = 0;
    for (int t = 0; t < nt; ++t) {
        if (t + 1 < nt) STAGE(cur ^ 1, (t + 1) << 5);
        short8v a[4], b[4];
#pragma unroll
        for (int m = 0; m < 4; ++m) a[m] = *(const short8v*)&sm.st.As[cur][(frow_a + m * 16) * 32 + fk];
#pragma unroll
        for (int n = 0; n < 4; ++n) b[n] = *(const short8v*)&sm.st.Bs[cur][(frow_b + n * 16) * 32 + fk];
#pragma unroll
        for (int m = 0; m < 4; ++m)
#pragma unroll
            for (int n = 0; n < 4; ++n)
                acc[m][n] = __builtin_amdgcn_mfma_f32_16x16x32_bf16(a[m], b[n], acc[m][n], 0, 0, 0);
        if (t + 1 < nt) { __syncthreads(); cur ^= 1; }
    }
#endif
#undef STAGE

    // ---- epilogue: LDS-staged coalesced stores ----
    __syncthreads();   // staging ring dead; safe to overlay output buffer
    int lr = (lane >> 4) * 4;
    int lc = lane & 15;
    if (OUTBF) {
#pragma unroll
        for (int n = 0; n < 4; ++n) {
            int c = wc * 64 + n * 16 + lc;
            float bv = BIAS ? bias[col0 + c] : 0.0f;
#pragma unroll
            for (int m = 0; m < 4; ++m) {
#pragma unroll
                for (int j = 0; j < 4; ++j) {
                    float v = acc[m][n][j] + bv;
                    if (GELU) v = gelu_f(v);
                    sm.obf[wr * 64 + m * 16 + lr + j][c] = bf16s(v);
                }
            }
        }
        __syncthreads();
        short* yb = (short*)Yb + (size_t)row0 * ldyb + col0;
#pragma unroll
        for (int it = 0; it < 8; ++it) {
            int r = (tid >> 4) + it * 16;
            int c8 = (tid & 15) * 8;
            *(short8v*)(yb + (size_t)r * ldyb + c8) = *(const short8v*)&sm.obf[r][c8];
        }
    } else {
#pragma unroll
        for (int half = 0; half < 2; ++half) {
            if (half) __syncthreads();   // readers of half 0 done before overwrite
            if (wr == half) {
#pragma unroll
                for (int n = 0; n < 4; ++n) {
                    int c = wc * 64 + n * 16 + lc;
                    float bv = BIAS ? bias[col0 + c] : 0.0f;
#pragma unroll
                    for (int m = 0; m < 4; ++m)
#pragma unroll
                        for (int j = 0; j < 4; ++j) {
                            float v = acc[m][n][j] + bv;
                            if (GELU) v = gelu_f(v);
                            sm.off[m * 16 + lr + j][c] = v;
                        }
                }
            }
            __syncthreads();
            float* yp0 = Y + (size_t)(row0 + half * 64) * ldy + col0;
#pragma unroll
            for (int it = 0; it < 8; ++it) {
                int r = (tid >> 5) + it * 8;
                int c4 = (tid & 31) * 4;
                float4 v = *(const float4*)&sm.off[r][c4];
                float* yp = yp0 + (size_t)r * ldy + c4;
                if (ACC) {
                    float4 o = *(const float4*)yp;
                    v.x += o.x; v.y += o.y; v.z += o.z; v.w += o.w;
                }
                *(float4*)yp = v;
            }
        }
    }
}

// ---------------- MFMA attention, barrier-free, XCD-swizzled ----------------
__global__ __launch_bounds__(256) void attn_mfma_kernel(
    const __hip_bfloat16* __restrict__ qkv,
    const float* __restrict__ biasT,
    __hip_bfloat16* __restrict__ o,
    int T, float scale, int nwin) {
    __shared__ __align__(16) short Vt[4][32][72];   // [wave][d][kt]  (V transposed)
    __shared__ __align__(16) short Pl[4][64][40];   // [wave][r][half-K cols]
    const int tid = threadIdx.x, lane = tid & 63, wv = tid >> 6;
    int p, hg;
    {
        int L = blockIdx.x;
        if (nwin & 7) { hg = L % 3; p = L / 3; }
        else { int r = L & 7, pos = L >> 3; hg = pos % 3; p = (pos / 3) * 8 + r; }
    }
    const int h = hg * 4 + wv;
    const short* q_base = (const short*)qkv + (size_t)p * T * N3;

    const int fr = lane & 15;
    const int fk = (lane >> 4) * 8;
    const int lg = lane >> 4;
    const int lc = lane & 15;

    short8v aq[4], bk[4];
#pragma unroll
    for (int m = 0; m < 4; ++m) {
        const short* qp = q_base + (size_t)(m * 16 + fr) * N3 + h * 32 + fk;
        aq[m] = *(const short8v*)qp;
        bk[m] = *(const short8v*)(qp + 384);
    }

    for (int ch = lane; ch < T * 4; ch += 64) {
        int t = ch >> 2, cq = ch & 3;
        short8v v8 = *(const short8v*)(q_base + (size_t)t * N3 + 768 + h * 32 + cq * 8);
#pragma unroll
        for (int e = 0; e < 8; ++e) Vt[wv][cq * 8 + e][t] = v8[e];
    }
    for (int idx = lane; idx < (64 - T) * 32; idx += 64) {
        int t = T + (idx >> 5), d = idx & 31;
        Vt[wv][d][t] = 0;
    }

    f32x4 acc[4][4] = {};
#pragma unroll
    for (int m = 0; m < 4; ++m)
#pragma unroll
        for (int n = 0; n < 4; ++n)
            acc[m][n] = __builtin_amdgcn_mfma_f32_16x16x32_bf16(aq[m], bk[n], acc[m][n], 0, 0, 0);

    const float* bh = biasT ? (biasT + (size_t)h * 4096) : nullptr;
    float p2[4][4], p3[4][4];
#pragma unroll
    for (int m = 0; m < 4; ++m) {
#pragma unroll
        for (int j = 0; j < 4; ++j) {
            int r = m * 16 + lg * 4 + j;
            float v[4];
            if (bh) {
                float4 bv4 = *(const float4*)(bh + r * 64 + lc * 4);
#pragma unroll
                for (int n = 0; n < 4; ++n) v[n] = acc[m][n][j] * scale + ((const float*)&bv4)[n];
            } else {
#pragma unroll
                for (int n = 0; n < 4; ++n) v[n] = acc[m][n][j] * scale;
            }
#pragma unroll
            for (int n = 0; n < 4; ++n)
                if (n * 16 + lc >= T) v[n] = -1e30f;
            float mx = fmaxf(fmaxf(v[0], v[1]), fmaxf(v[2], v[3]));
#pragma unroll
            for (int off = 1; off < 16; off <<= 1) mx = fmaxf(mx, __shfl_xor(mx, off));
            float s = 0.f;
#pragma unroll
            for (int n = 0; n < 4; ++n) { v[n] = __expf(v[n] - mx); s += v[n]; }
#pragma unroll
            for (int off = 1; off < 16; off <<= 1) s += __shfl_xor(s, off);
            float inv = 1.0f / s;
            Pl[wv][r][lc]      = bf16s(v[0] * inv);
            Pl[wv][r][16 + lc] = bf16s(v[1] * inv);
            p2[m][j] = v[2] * inv;
            p3[m][j] = v[3] * inv;
        }
    }

    f32x4 oacc[4][2] = {};
    {
        short8v ap[4], bv[2];
#pragma unroll
        for (int m = 0; m < 4; ++m) ap[m] = *(const short8v*)&Pl[wv][m * 16 + fr][fk];
#pragma unroll
        for (int n = 0; n < 2; ++n) bv[n] = *(const short8v*)&Vt[wv][n * 16 + fr][fk];
#pragma unroll
        for (int m = 0; m < 4; ++m)
#pragma unroll
            for (int n = 0; n < 2; ++n)
                oacc[m][n] = __builtin_amdgcn_mfma_f32_16x16x32_bf16(ap[m], bv[n], oacc[m][n], 0, 0, 0);
    }
#pragma unroll
    for (int m = 0; m < 4; ++m)
#pragma unroll
        for (int j = 0; j < 4; ++j) {
            int r = m * 16 + lg * 4 + j;
            Pl[wv][r][lc]      = bf16s(p2[m][j]);
            Pl[wv][r][16 + lc] = bf16s(p3[m][j]);
        }
    {
        short8v ap[4], bv[2];
#pragma unroll
        for (int m = 0; m < 4; ++m) ap[m] = *(const short8v*)&Pl[wv][m * 16 + fr][fk];
#pragma unroll
        for (int n = 0; n < 2; ++n) bv[n] = *(const short8v*)&Vt[wv][n * 16 + fr][32 + fk];
#pragma unroll
        for (int m = 0; m < 4; ++m)
#pragma unroll
            for (int n = 0; n < 2; ++n)
                oacc[m][n] = __builtin_amdgcn_mfma_f32_16x16x32_bf16(ap[m], bv[n], oacc[m][n], 0, 0, 0);
    }

    short* ob = (short*)o;
#pragma unroll
    for (int m = 0; m < 4; ++m)
#pragma unroll
        for (int j = 0; j < 4; ++j) {
            int r = m * 16 + lg * 4 + j;
            if (r < T) {
#pragma unroll
                for (int n = 0; n < 2; ++n)
                    ob[((size_t)p * T + r) * CC + h * 32 + n * 16 + lc] = bf16s(oacc[m][n][j]);
            }
        }
}

// ---------------- host ----------------
extern "C" void kernel_launch(void* const* d_in, const int* in_sizes, int n_in,
                              void* d_out, int out_size, void* d_ws, size_t ws_size,
                              hipStream_t stream) {
    const float* cls_in   = (const float*)d_in[0];
    const float* patch_in = (const float*)d_in[1];
    const float* qkv_w    = (const float*)d_in[2];
    const float* qkv_b    = (const float*)d_in[3];
    const float* proj_w   = (const float*)d_in[4];
    const float* proj_b   = (const float*)d_in[5];
    const float* rel_pos  = (const float*)d_in[6];
    const float* ln0w = (const float*)d_in[7];
    const float* ln0b = (const float*)d_in[8];
    const float* ln1w = (const float*)d_in[9];
    const float* ln1b = (const float*)d_in[10];
    const float* ln2w = (const float*)d_in[11];
    const float* ln2b = (const float*)d_in[12];
    const float* w1 = (const float*)d_in[13];
    const float* b1 = (const float*)d_in[14];
    const float* w2 = (const float*)d_in[15];
    const float* b2 = (const float*)d_in[16];

    float* OUT = (float*)d_ws;
    size_t avail = ws_size / 4;

    const size_t OUT_F = 39321600;          // 2048*50*384 fp32 residual stream
    const size_t WB_F  = 1769472;           // bf16 weights (f32 slots)
    const size_t BT_F  = 49152;             // bias table 12*64*64 fp32
    __hip_bfloat16* WB = (__hip_bfloat16*)(OUT + OUT_F);
    __hip_bfloat16* qwb = WB;                                   // 2*1152*384
    __hip_bfloat16* pwb = WB + 884736;                          // 2*384*384
    __hip_bfloat16* w1b = WB + 1179648;                         // 2*1536*384
    __hip_bfloat16* w2b = WB + 2359296;                         // 2*384*1536
    float* biasTbuf = OUT + OUT_F + WB_F;

    int cw = 2048;
    while (cw > 64 && OUT_F + WB_F + BT_F + (size_t)cw * 48000 > avail) cw >>= 1;
    float* fbase = OUT + OUT_F + WB_F + BT_F;
    __hip_bfloat16* Xb = (__hip_bfloat16*)fbase;
    __hip_bfloat16* Qb = (__hip_bfloat16*)(fbase + (size_t)cw * 9600);
    __hip_bfloat16* Hb = Qb;   // MLP hidden reuses Qb region
    const float scale = 0.17677669529663687f;

    f2bf_kernel<<<dim3((884736 / 4 + 255) / 256), dim3(256), 0, stream>>>(qkv_w, qwb, 884736);
    f2bf_kernel<<<dim3((294912 / 4 + 255) / 256), dim3(256), 0, stream>>>(proj_w, pwb, 294912);
    f2bf_kernel<<<dim3((1179648 / 4 + 255) / 256), dim3(256), 0, stream>>>(w1, w1b, 1179648);
    f2bf_kernel<<<dim3((1179648 / 4 + 255) / 256), dim3(256), 0, stream>>>(w2, w2b, 1179648);

    pack_cls_kernel<<<dim3(BB * 6), dim3(256), 0, stream>>>(cls_in, OUT);
    pack_patch_kernel<<<dim3(BB * 56 * 6), dim3(256), 0, stream>>>(patch_in, OUT);

    for (int i = 0; i < NBB; ++i) {
        const __hip_bfloat16* qw = qwb + (size_t)i * N3 * CC;
        const float* qb = qkv_b + (size_t)i * N3;
        const __hip_bfloat16* pw = pwb + (size_t)i * CC * CC;
        const float* pb = proj_b + (size_t)i * CC;
        const float* rp = rel_pos + (size_t)i * NHH * 169;
        const __hip_bfloat16* w1i = w1b + (size_t)i * HIDD * CC;
        const float* b1i = b1 + (size_t)i * HIDD;
        const __hip_bfloat16* w2i = w2b + (size_t)i * CC * HIDD;
        const float* b2i = b2 + (size_t)i * CC;

        bias_precompute_kernel<<<dim3(NHH), dim3(256), 0, stream>>>(rp, biasTbuf);

        // ---- stage A: cls attention across 64 windows of each image (T=64) ----
        ln_kernel<<<dim3(2048 / 4), dim3(256), 0, stream>>>(OUT, LDOUT, ln0w + i * CC, ln0b + i * CC, Xb, CC, 2048);
        gemm_bf16_kernel<1, 0, 0, 1><<<dim3((N3 / 128) * (2048 / 128)), dim3(256), 0, stream>>>(
            Xb, CC, qw, qb, nullptr, 0, Qb, N3, 2048, N3, CC, N3 / 128);
        attn_mfma_kernel<<<dim3(BB * 3), dim3(256), 0, stream>>>(Qb, nullptr, Xb, 64, scale, BB);
        gemm_bf16_kernel<1, 0, 1, 0><<<dim3((CC / 128) * (2048 / 128)), dim3(256), 0, stream>>>(
            Xb, CC, pw, pb, OUT, LDOUT, nullptr, 0, 2048, CC, CC, CC / 128);

        // ---- stage B: windowed attention with rel-pos bias (T=50) ----
        for (int w0 = 0; w0 < NWW; w0 += cw) {
            float* outc = OUT + (size_t)w0 * LDOUT;
            int Mr = cw * NTT;
            ln_kernel<<<dim3(Mr / 4), dim3(256), 0, stream>>>(outc, CC, ln1w + i * CC, ln1b + i * CC, Xb, CC, Mr);
            gemm_bf16_kernel<1, 0, 0, 1><<<dim3((N3 / 128) * (Mr / 128)), dim3(256), 0, stream>>>(
                Xb, CC, qw, qb, nullptr, 0, Qb, N3, Mr, N3, CC, N3 / 128);
            attn_mfma_kernel<<<dim3(cw * 3), dim3(256), 0, stream>>>(Qb, biasTbuf, Xb, NTT, scale, cw);
            gemm_bf16_kernel<1, 0, 1, 0><<<dim3((CC / 128) * (Mr / 128)), dim3(256), 0, stream>>>(
                Xb, CC, pw, pb, outc, CC, nullptr, 0, Mr, CC, CC, CC / 128);
        }

        // ---- stage C: MLP ----
        for (int w0 = 0; w0 < NWW; w0 += cw) {
            float* outc = OUT + (size_t)w0 * LDOUT;
            int Mr = cw * NTT;
            ln_kernel<<<dim3(Mr / 4), dim3(256), 0, stream>>>(outc, CC, ln2w + i * CC, ln2b + i * CC, Xb, CC, Mr);
            gemm_bf16_kernel<1, 1, 0, 1><<<dim3((HIDD / 128) * (Mr / 128)), dim3(256), 0, stream>>>(
                Xb, CC, w1i, b1i, nullptr, 0, Hb, HIDD, Mr, HIDD, CC, HIDD / 128);
            gemm_bf16_kernel<1, 0, 1, 0><<<dim3((CC / 128) * (Mr / 128)), dim3(256), 0, stream>>>(
                Hb, HIDD, w2i, b2i, outc, CC, nullptr, 0, Mr, CC, HIDD, CC / 128);
        }
    }

    unpack_cls_kernel<<<dim3(BB * 6), dim3(256), 0, stream>>>(OUT, (float*)d_out);
    unpack_patch_kernel<<<dim3(BB * 56 * 6), dim3(256), 0, stream>>>(OUT, (float*)d_out + 786432);
}

// Round 8
// 2072.792 us; speedup vs baseline: 5.7869x; 1.0219x over previous
//
#include <hip/hip_runtime.h>
#include <hip/hip_bf16.h>
#include <cstdint>
#include <cstddef>

// ---- problem constants ----
#define BB    32
#define CC    384
#define NHH   12
#define HDD   32
#define WSS   7
#define HKK   8
#define NBB   2
#define HIDD  1536
#define NTT   50          // tokens per window (1 cls + 49 patch)
#define NWW   2048        // B*HK*HK windows
#define LDOUT 19200       // 50*384
#define N3    1152        // 3*C

typedef __attribute__((ext_vector_type(8))) short short8v;
typedef __attribute__((ext_vector_type(4))) float f32x4;

#if defined(__has_builtin)
#if __has_builtin(__builtin_amdgcn_global_load_lds)
#define HAS_GLDS 1
#endif
#endif
#ifndef HAS_GLDS
#define HAS_GLDS 0
#endif

static __device__ __forceinline__ float gelu_f(float x) {
    return 0.5f * x * (1.0f + erff(x * 0.70710678118654752440f));
}

static __device__ __forceinline__ short bf16s(float x) {
    __hip_bfloat16 b = __float2bfloat16(x);
    return *(short*)&b;
}

#if HAS_GLDS
static __device__ __forceinline__ void glds16(const short* g, short* l) {
    __builtin_amdgcn_global_load_lds(
        (const __attribute__((address_space(1))) unsigned int*)g,
        (__attribute__((address_space(3))) unsigned int*)l,
        16, 0, 0);
}
#endif

// XCD-aware decode: keep all nx column-blocks of one row-panel on ONE XCD.
static __device__ __forceinline__ void swz_decode(int L, int nx, int ny, int& bx, int& by) {
    if (ny & 7) {
        bx = L % nx; by = L / nx;
    } else {
        int r = L & 7, pos = L >> 3;
        bx = pos % nx;
        by = (pos / nx) * 8 + r;
    }
}

// ---------------- pack / unpack (fp32) ----------------
__global__ void pack_cls_kernel(const float* __restrict__ cls, float* __restrict__ out) {
    __shared__ float lds[64][65];
    int bid = blockIdx.x;
    int b = bid / 6, cc = bid % 6, c0 = cc * 64;
    int tid = threadIdx.x;
    for (int idx = tid; idx < 64 * 64; idx += 256) {
        int k = idx & 63, cl = idx >> 6;
        lds[cl][k] = cls[((size_t)b * CC + c0 + cl) * 64 + k];
    }
    __syncthreads();
    for (int idx = tid; idx < 64 * 64; idx += 256) {
        int cl = idx & 63, k = idx >> 6;
        out[(size_t)(b * 64 + k) * LDOUT + c0 + cl] = lds[cl][k];
    }
}

__global__ void pack_patch_kernel(const float* __restrict__ patch, float* __restrict__ out) {
    __shared__ float lds[64][57];
    int bid = blockIdx.x;
    int b = bid / 336, rem = bid % 336;
    int y = rem / 6, cc = rem % 6, c0 = cc * 64;
    int tid = threadIdx.x;
    for (int idx = tid; idx < 64 * 56; idx += 256) {
        int cl = idx / 56, x = idx % 56;
        lds[cl][x] = patch[(((size_t)b * CC + c0 + cl) * 56 + y) * 56 + x];
    }
    __syncthreads();
    int wsy = y % 7, hky = y / 7;
    for (int idx = tid; idx < 64 * 56; idx += 256) {
        int cl = idx & 63, x = idx >> 6;
        int tok = 1 + wsy * 7 + (x % 7);
        int win = b * 64 + hky * 8 + (x / 7);
        out[((size_t)win * NTT + tok) * CC + c0 + cl] = lds[cl][x];
    }
}

__global__ void unpack_cls_kernel(const float* __restrict__ out, float* __restrict__ cls_out) {
    __shared__ float lds[64][65];
    int bid = blockIdx.x;
    int b = bid / 6, cc = bid % 6, c0 = cc * 64;
    int tid = threadIdx.x;
    for (int idx = tid; idx < 64 * 64; idx += 256) {
        int cl = idx & 63, k = idx >> 6;
        lds[cl][k] = out[(size_t)(b * 64 + k) * LDOUT + c0 + cl];
    }
    __syncthreads();
    for (int idx = tid; idx < 64 * 64; idx += 256) {
        int k = idx & 63, cl = idx >> 6;
        cls_out[((size_t)b * CC + c0 + cl) * 64 + k] = lds[cl][k];
    }
}

__global__ void unpack_patch_kernel(const float* __restrict__ out, float* __restrict__ patch_out) {
    __shared__ float lds[64][57];
    int bid = blockIdx.x;
    int b = bid / 336, rem = bid % 336;
    int y = rem / 6, cc = rem % 6, c0 = cc * 64;
    int tid = threadIdx.x;
    int wsy = y % 7, hky = y / 7;
    for (int idx = tid; idx < 64 * 56; idx += 256) {
        int cl = idx & 63, x = idx >> 6;
        int tok = 1 + wsy * 7 + (x % 7);
        int win = b * 64 + hky * 8 + (x / 7);
        lds[cl][x] = out[((size_t)win * NTT + tok) * CC + c0 + cl];
    }
    __syncthreads();
    for (int idx = tid; idx < 64 * 56; idx += 256) {
        int cl = idx / 56, x = idx % 56;
        patch_out[((size_t)b * CC + c0 + cl) * 3136 + y * 56 + x] = lds[cl][x];
    }
}

// ---------------- fp32 -> bf16 weight conversion ----------------
__global__ void f2bf_kernel(const float* __restrict__ in, __hip_bfloat16* __restrict__ out, int n) {
    int i = (blockIdx.x * 256 + threadIdx.x) * 4;
    if (i + 3 < n) {
        float4 v = *(const float4*)(in + i);
        out[i + 0] = __float2bfloat16(v.x);
        out[i + 1] = __float2bfloat16(v.y);
        out[i + 2] = __float2bfloat16(v.z);
        out[i + 3] = __float2bfloat16(v.w);
    } else {
        for (; i < n; ++i) out[i] = __float2bfloat16(in[i]);
    }
}

// ---------------- rel-pos bias table, fragment-ordered: [12][64 r][16 lc][4 n] fp32 ----------------
__global__ void bias_precompute_kernel(const float* __restrict__ rp, float* __restrict__ biasT) {
    int h = blockIdx.x;
    for (int idx = threadIdx.x; idx < 4096; idx += 256) {
        int qt = idx >> 6, kt = idx & 63;
        float v = 0.f;
        if (qt >= 1 && qt < NTT && kt >= 1 && kt < NTT) {
            int qp = qt - 1, kp = kt - 1;
            int qy = qp / 7, qx = qp - qy * 7;
            int ky = kp / 7, kx = kp - ky * 7;
            int ridx = ((ky - qy + 16) % 13) * 13 + ((kx - qx + 16) % 13);
            v = rp[h * 169 + ridx];
        }
        biasT[h * 4096 + qt * 64 + (kt & 15) * 4 + (kt >> 4)] = v;
    }
}

// ---------------- LayerNorm -> bf16 (float2-vectorized) ----------------
__global__ void ln_kernel(const float* __restrict__ x, int ldx,
                          const float* __restrict__ w, const float* __restrict__ b,
                          __hip_bfloat16* __restrict__ y, int ldy, int M) {
    int wave = threadIdx.x >> 6, lane = threadIdx.x & 63;
    int row = blockIdx.x * 4 + wave;
    if (row >= M) return;
    const float2* xr = (const float2*)(x + (size_t)row * ldx);
    float2 vals[3];
    float s = 0.f;
#pragma unroll
    for (int j = 0; j < 3; ++j) { vals[j] = xr[lane + j * 64]; s += vals[j].x + vals[j].y; }
#pragma unroll
    for (int off = 32; off > 0; off >>= 1) s += __shfl_xor(s, off);
    float mean = s * (1.0f / 384.0f);
    float vs = 0.f;
#pragma unroll
    for (int j = 0; j < 3; ++j) {
        float dx = vals[j].x - mean, dy = vals[j].y - mean;
        vs += dx * dx + dy * dy;
    }
#pragma unroll
    for (int off = 32; off > 0; off >>= 1) vs += __shfl_xor(vs, off);
    float inv = rsqrtf(vs * (1.0f / 384.0f) + 1e-6f);
    const float2* w2 = (const float2*)w;
    const float2* b2 = (const float2*)b;
    ushort* yr = (ushort*)(y + (size_t)row * ldy);
#pragma unroll
    for (int j = 0; j < 3; ++j) {
        int c = lane + j * 64;
        float2 wv = w2[c], bv = b2[c];
        ushort2 o;
        o.x = (ushort)bf16s((vals[j].x - mean) * inv * wv.x + bv.x);
        o.y = (ushort)bf16s((vals[j].y - mean) * inv * wv.y + bv.y);
        *(ushort2*)(yr + c * 2) = o;
    }
}

// ---------------- bf16 MFMA GEMM v2: Y = A[M,K] @ W[N,K]^T ----------------
// 256x128 tile, 8 waves (4x2), wave = 64x64 (16 frags), BK=32.
// 3-slot ring (72 KB -> 2 blocks/CU), counted-vmcnt depth-2 (6/3/0),
// XCD-swizzled 1D grid, LDS-staged coalesced epilogue.
template <int BIAS, int GELU, int ACC, int OUTBF>
__global__ __launch_bounds__(512, 4) void gemm_bf16_kernel(
    const __hip_bfloat16* __restrict__ A, int lda,
    const __hip_bfloat16* __restrict__ W,
    const float* __restrict__ bias,
    float* __restrict__ Y, int ldy,
    __hip_bfloat16* __restrict__ Yb, int ldyb,
    int M, int N, int K, int nx) {
    __shared__ __align__(16) union SMemU {
        struct { short As[3][256 * 32]; short Bs[3][128 * 32]; } st;  // 72 KB ring
        short obf[256][132];   // 67.6 KB bf16 output tile
        float off[128][132];   // 67.6 KB fp32 half-tile (128 rows)
    } sm;
    int tid = threadIdx.x;
    int lane = tid & 63;
    int wid = tid >> 6;               // 0..7
    int wr = wid >> 1, wc = wid & 1;  // wr: 64-row band (0..3), wc: 64-col band (0..1)
    int bx, by;
    swz_decode(blockIdx.x, nx, M >> 8, bx, by);
    int row0 = by * 256, col0 = bx * 128;

    // staging: wave wid covers A rows [wid*32, wid*32+32) (2 glds) and
    // B rows [wid*16, wid*16+16) (1 glds). lane -> (row = lane>>2, kq = lane&3).
    const short* Ag = (const short*)A + (size_t)(row0 + wid * 32 + (lane >> 2)) * lda + (lane & 3) * 8;
    const short* Wg = (const short*)W + (size_t)(col0 + wid * 16 + (lane >> 2)) * K + (lane & 3) * 8;
    size_t astep16 = (size_t)16 * lda;
    int ldsA = wid * 32 * 32;   // wave-uniform element offsets; HW adds lane*16B
    int ldsB = wid * 16 * 32;

#if HAS_GLDS
#define STAGE(buf, k0)                                                \
    do {                                                              \
        glds16(Ag + (k0), &sm.st.As[buf][ldsA]);                      \
        glds16(Ag + astep16 + (k0), &sm.st.As[buf][ldsA + 16 * 32]);  \
        glds16(Wg + (k0), &sm.st.Bs[buf][ldsB]);                      \
    } while (0)
#else
#define STAGE(buf, k0)                                                               \
    do {                                                                             \
        *(short8v*)(&sm.st.As[buf][ldsA] + lane * 8) = *(const short8v*)(Ag + (k0)); \
        *(short8v*)(&sm.st.As[buf][ldsA + 16 * 32] + lane * 8) = *(const short8v*)(Ag + astep16 + (k0)); \
        *(short8v*)(&sm.st.Bs[buf][ldsB] + lane * 8) = *(const short8v*)(Wg + (k0)); \
    } while (0)
#endif

    f32x4 acc[4][4] = {};
    int frow_a = wr * 64 + (lane & 15);
    int frow_b = wc * 64 + (lane & 15);
    int fk = (lane >> 4) * 8;

    int nt = K >> 5;
#if HAS_GLDS
    // counted-vmcnt pipeline, depth 2, 3 slots. Per-wave loads per stage = 3.
    STAGE(0, 0);
    if (nt > 1) STAGE(1, 32);
    int sc = 0;
    for (int t = 0; t < nt; ++t) {
        int sn = sc + 2; if (sn >= 3) sn -= 3;
        if (t + 2 < nt) {
            STAGE(sn, (t + 2) << 5);
            asm volatile("s_waitcnt vmcnt(6)" ::: "memory");
        } else if (t + 1 < nt) {
            asm volatile("s_waitcnt vmcnt(3)" ::: "memory");
        } else {
            asm volatile("s_waitcnt vmcnt(0)" ::: "memory");
        }
        __builtin_amdgcn_s_barrier();          // A: everyone's tile-t loads landed
        __builtin_amdgcn_sched_barrier(0);
        short8v a[4], b[4];
#pragma unroll
        for (int m = 0; m < 4; ++m) a[m] = *(const short8v*)&sm.st.As[sc][(frow_a + m * 16) * 32 + fk];
#pragma unroll
        for (int n = 0; n < 4; ++n) b[n] = *(const short8v*)&sm.st.Bs[sc][(frow_b + n * 16) * 32 + fk];
        __builtin_amdgcn_s_setprio(1);
#pragma unroll
        for (int m = 0; m < 4; ++m)
#pragma unroll
            for (int n = 0; n < 4; ++n)
                acc[m][n] = __builtin_amdgcn_mfma_f32_16x16x32_bf16(a[m], b[n], acc[m][n], 0, 0, 0);
        __builtin_amdgcn_s_setprio(0);
        __builtin_amdgcn_sched_barrier(0);
        __builtin_amdgcn_s_barrier();          // B: all waves consumed tile t
        ++sc; if (sc >= 3) sc = 0;
    }
#else
    STAGE(0, 0);
    __syncthreads();
    int cur = 0;
    for (int t = 0; t < nt; ++t) {
        if (t + 1 < nt) STAGE(cur ^ 1, (t + 1) << 5);
        short8v a[4], b[4];
#pragma unroll
        for (int m = 0; m < 4; ++m) a[m] = *(const short8v*)&sm.st.As[cur][(frow_a + m * 16) * 32 + fk];
#pragma unroll
        for (int n = 0; n < 4; ++n) b[n] = *(const short8v*)&sm.st.Bs[cur][(frow_b + n * 16) * 32 + fk];
#pragma unroll
        for (int m = 0; m < 4; ++m)
#pragma unroll
            for (int n = 0; n < 4; ++n)
                acc[m][n] = __builtin_amdgcn_mfma_f32_16x16x32_bf16(a[m], b[n], acc[m][n], 0, 0, 0);
        if (t + 1 < nt) { __syncthreads(); cur ^= 1; }
    }
#endif
#undef STAGE

    // ---- epilogue: LDS-staged coalesced stores ----
    __syncthreads();   // staging ring dead; overlay output buffer
    int lr = (lane >> 4) * 4;
    int lc = lane & 15;
    if (OUTBF) {
#pragma unroll
        for (int n = 0; n < 4; ++n) {
            int c = wc * 64 + n * 16 + lc;
            float bv = BIAS ? bias[col0 + c] : 0.0f;
#pragma unroll
            for (int m = 0; m < 4; ++m) {
#pragma unroll
                for (int j = 0; j < 4; ++j) {
                    float v = acc[m][n][j] + bv;
                    if (GELU) v = gelu_f(v);
                    sm.obf[wr * 64 + m * 16 + lr + j][c] = bf16s(v);
                }
            }
        }
        __syncthreads();
        short* yb = (short*)Yb + (size_t)row0 * ldyb + col0;
#pragma unroll
        for (int it = 0; it < 8; ++it) {
            int r = (tid >> 4) + it * 32;
            int c8 = (tid & 15) * 8;
            *(short8v*)(yb + (size_t)r * ldyb + c8) = *(const short8v*)&sm.obf[r][c8];
        }
    } else {
#pragma unroll
        for (int half = 0; half < 2; ++half) {
            if (half) __syncthreads();   // readers of half 0 done before overwrite
            if ((wr >> 1) == half) {
#pragma unroll
                for (int n = 0; n < 4; ++n) {
                    int c = wc * 64 + n * 16 + lc;
                    float bv = BIAS ? bias[col0 + c] : 0.0f;
#pragma unroll
                    for (int m = 0; m < 4; ++m)
#pragma unroll
                        for (int j = 0; j < 4; ++j) {
                            float v = acc[m][n][j] + bv;
                            if (GELU) v = gelu_f(v);
                            sm.off[(wr & 1) * 64 + m * 16 + lr + j][c] = v;
                        }
                }
            }
            __syncthreads();
            float* yp0 = Y + (size_t)(row0 + half * 128) * ldy + col0;
#pragma unroll
            for (int it = 0; it < 8; ++it) {
                int r = (tid >> 5) + it * 16;
                int c4 = (tid & 31) * 4;
                float4 v = *(const float4*)&sm.off[r][c4];
                float* yp = yp0 + (size_t)r * ldy + c4;
                if (ACC) {
                    float4 o = *(const float4*)yp;
                    v.x += o.x; v.y += o.y; v.z += o.z; v.w += o.w;
                }
                *(float4*)yp = v;
            }
        }
    }
}

// ---------------- MFMA attention, barrier-free, XCD-swizzled ----------------
__global__ __launch_bounds__(256) void attn_mfma_kernel(
    const __hip_bfloat16* __restrict__ qkv,
    const float* __restrict__ biasT,
    __hip_bfloat16* __restrict__ o,
    int T, float scale, int nwin) {
    __shared__ __align__(16) short Vt[4][32][72];   // [wave][d][kt]  (V transposed)
    __shared__ __align__(16) short Pl[4][64][40];   // [wave][r][half-K cols]
    const int tid = threadIdx.x, lane = tid & 63, wv = tid >> 6;
    int p, hg;
    {
        int L = blockIdx.x;
        if (nwin & 7) { hg = L % 3; p = L / 3; }
        else { int r = L & 7, pos = L >> 3; hg = pos % 3; p = (pos / 3) * 8 + r; }
    }
    const int h = hg * 4 + wv;
    const short* q_base = (const short*)qkv + (size_t)p * T * N3;

    const int fr = lane & 15;
    const int fk = (lane >> 4) * 8;
    const int lg = lane >> 4;
    const int lc = lane & 15;

    short8v aq[4], bk[4];
#pragma unroll
    for (int m = 0; m < 4; ++m) {
        const short* qp = q_base + (size_t)(m * 16 + fr) * N3 + h * 32 + fk;
        aq[m] = *(const short8v*)qp;
        bk[m] = *(const short8v*)(qp + 384);
    }

    for (int ch = lane; ch < T * 4; ch += 64) {
        int t = ch >> 2, cq = ch & 3;
        short8v v8 = *(const short8v*)(q_base + (size_t)t * N3 + 768 + h * 32 + cq * 8);
#pragma unroll
        for (int e = 0; e < 8; ++e) Vt[wv][cq * 8 + e][t] = v8[e];
    }
    for (int idx = lane; idx < (64 - T) * 32; idx += 64) {
        int t = T + (idx >> 5), d = idx & 31;
        Vt[wv][d][t] = 0;
    }

    f32x4 acc[4][4] = {};
#pragma unroll
    for (int m = 0; m < 4; ++m)
#pragma unroll
        for (int n = 0; n < 4; ++n)
            acc[m][n] = __builtin_amdgcn_mfma_f32_16x16x32_bf16(aq[m], bk[n], acc[m][n], 0, 0, 0);

    const float* bh = biasT ? (biasT + (size_t)h * 4096) : nullptr;
    float p2[4][4], p3[4][4];
#pragma unroll
    for (int m = 0; m < 4; ++m) {
#pragma unroll
        for (int j = 0; j < 4; ++j) {
            int r = m * 16 + lg * 4 + j;
            float v[4];
            if (bh) {
                float4 bv4 = *(const float4*)(bh + r * 64 + lc * 4);
#pragma unroll
                for (int n = 0; n < 4; ++n) v[n] = acc[m][n][j] * scale + ((const float*)&bv4)[n];
            } else {
#pragma unroll
                for (int n = 0; n < 4; ++n) v[n] = acc[m][n][j] * scale;
            }
#pragma unroll
            for (int n = 0; n < 4; ++n)
                if (n * 16 + lc >= T) v[n] = -1e30f;
            float mx = fmaxf(fmaxf(v[0], v[1]), fmaxf(v[2], v[3]));
#pragma unroll
            for (int off = 1; off < 16; off <<= 1) mx = fmaxf(mx, __shfl_xor(mx, off));
            float s = 0.f;
#pragma unroll
            for (int n = 0; n < 4; ++n) { v[n] = __expf(v[n] - mx); s += v[n]; }
#pragma unroll
            for (int off = 1; off < 16; off <<= 1) s += __shfl_xor(s, off);
            float inv = 1.0f / s;
            Pl[wv][r][lc]      = bf16s(v[0] * inv);
            Pl[wv][r][16 + lc] = bf16s(v[1] * inv);
            p2[m][j] = v[2] * inv;
            p3[m][j] = v[3] * inv;
        }
    }

    f32x4 oacc[4][2] = {};
    {
        short8v ap[4], bv[2];
#pragma unroll
        for (int m = 0; m < 4; ++m) ap[m] = *(const short8v*)&Pl[wv][m * 16 + fr][fk];
#pragma unroll
        for (int n = 0; n < 2; ++n) bv[n] = *(const short8v*)&Vt[wv][n * 16 + fr][fk];
#pragma unroll
        for (int m = 0; m < 4; ++m)
#pragma unroll
            for (int n = 0; n < 2; ++n)
                oacc[m][n] = __builtin_amdgcn_mfma_f32_16x16x32_bf16(ap[m], bv[n], oacc[m][n], 0, 0, 0);
    }
#pragma unroll
    for (int m = 0; m < 4; ++m)
#pragma unroll
        for (int j = 0; j < 4; ++j) {
            int r = m * 16 + lg * 4 + j;
            Pl[wv][r][lc]      = bf16s(p2[m][j]);
            Pl[wv][r][16 + lc] = bf16s(p3[m][j]);
        }
    {
        short8v ap[4], bv[2];
#pragma unroll
        for (int m = 0; m < 4; ++m) ap[m] = *(const short8v*)&Pl[wv][m * 16 + fr][fk];
#pragma unroll
        for (int n = 0; n < 2; ++n) bv[n] = *(const short8v*)&Vt[wv][n * 16 + fr][32 + fk];
#pragma unroll
        for (int m = 0; m < 4; ++m)
#pragma unroll
            for (int n = 0; n < 2; ++n)
                oacc[m][n] = __builtin_amdgcn_mfma_f32_16x16x32_bf16(ap[m], bv[n], oacc[m][n], 0, 0, 0);
    }

    short* ob = (short*)o;
#pragma unroll
    for (int m = 0; m < 4; ++m)
#pragma unroll
        for (int j = 0; j < 4; ++j) {
            int r = m * 16 + lg * 4 + j;
            if (r < T) {
#pragma unroll
                for (int n = 0; n < 2; ++n)
                    ob[((size_t)p * T + r) * CC + h * 32 + n * 16 + lc] = bf16s(oacc[m][n][j]);
            }
        }
}

// ---------------- host ----------------
extern "C" void kernel_launch(void* const* d_in, const int* in_sizes, int n_in,
                              void* d_out, int out_size, void* d_ws, size_t ws_size,
                              hipStream_t stream) {
    const float* cls_in   = (const float*)d_in[0];
    const float* patch_in = (const float*)d_in[1];
    const float* qkv_w    = (const float*)d_in[2];
    const float* qkv_b    = (const float*)d_in[3];
    const float* proj_w   = (const float*)d_in[4];
    const float* proj_b   = (const float*)d_in[5];
    const float* rel_pos  = (const float*)d_in[6];
    const float* ln0w = (const float*)d_in[7];
    const float* ln0b = (const float*)d_in[8];
    const float* ln1w = (const float*)d_in[9];
    const float* ln1b = (const float*)d_in[10];
    const float* ln2w = (const float*)d_in[11];
    const float* ln2b = (const float*)d_in[12];
    const float* w1 = (const float*)d_in[13];
    const float* b1 = (const float*)d_in[14];
    const float* w2 = (const float*)d_in[15];
    const float* b2 = (const float*)d_in[16];

    float* OUT = (float*)d_ws;
    size_t avail = ws_size / 4;

    const size_t OUT_F = 39321600;          // 2048*50*384 fp32 residual stream
    const size_t WB_F  = 1769472;           // bf16 weights (f32 slots)
    const size_t BT_F  = 49152;             // bias table 12*64*64 fp32
    __hip_bfloat16* WB = (__hip_bfloat16*)(OUT + OUT_F);
    __hip_bfloat16* qwb = WB;                                   // 2*1152*384
    __hip_bfloat16* pwb = WB + 884736;                          // 2*384*384
    __hip_bfloat16* w1b = WB + 1179648;                         // 2*1536*384
    __hip_bfloat16* w2b = WB + 2359296;                         // 2*384*1536
    float* biasTbuf = OUT + OUT_F + WB_F;

    // cw = 1024: Hb chunk (157 MB) + OUT chunk stay Infinity-Cache-resident
    // between producer and consumer. cw*NTT must be a multiple of 256 (cw >= 128).
    int cw = 1024;
    while (cw > 128 && OUT_F + WB_F + BT_F + (size_t)cw * 48000 > avail) cw >>= 1;
    float* fbase = OUT + OUT_F + WB_F + BT_F;
    __hip_bfloat16* Xb = (__hip_bfloat16*)fbase;
    __hip_bfloat16* Qb = (__hip_bfloat16*)(fbase + (size_t)cw * 9600);
    __hip_bfloat16* Hb = Qb;   // MLP hidden reuses Qb region
    const float scale = 0.17677669529663687f;

    f2bf_kernel<<<dim3((884736 / 4 + 255) / 256), dim3(256), 0, stream>>>(qkv_w, qwb, 884736);
    f2bf_kernel<<<dim3((294912 / 4 + 255) / 256), dim3(256), 0, stream>>>(proj_w, pwb, 294912);
    f2bf_kernel<<<dim3((1179648 / 4 + 255) / 256), dim3(256), 0, stream>>>(w1, w1b, 1179648);
    f2bf_kernel<<<dim3((1179648 / 4 + 255) / 256), dim3(256), 0, stream>>>(w2, w2b, 1179648);

    pack_cls_kernel<<<dim3(BB * 6), dim3(256), 0, stream>>>(cls_in, OUT);
    pack_patch_kernel<<<dim3(BB * 56 * 6), dim3(256), 0, stream>>>(patch_in, OUT);

    for (int i = 0; i < NBB; ++i) {
        const __hip_bfloat16* qw = qwb + (size_t)i * N3 * CC;
        const float* qb = qkv_b + (size_t)i * N3;
        const __hip_bfloat16* pw = pwb + (size_t)i * CC * CC;
        const float* pb = proj_b + (size_t)i * CC;
        const float* rp = rel_pos + (size_t)i * NHH * 169;
        const __hip_bfloat16* w1i = w1b + (size_t)i * HIDD * CC;
        const float* b1i = b1 + (size_t)i * HIDD;
        const __hip_bfloat16* w2i = w2b + (size_t)i * CC * HIDD;
        const float* b2i = b2 + (size_t)i * CC;

        bias_precompute_kernel<<<dim3(NHH), dim3(256), 0, stream>>>(rp, biasTbuf);

        // ---- stage A: cls attention across 64 windows of each image (T=64) ----
        ln_kernel<<<dim3(2048 / 4), dim3(256), 0, stream>>>(OUT, LDOUT, ln0w + i * CC, ln0b + i * CC, Xb, CC, 2048);
        gemm_bf16_kernel<1, 0, 0, 1><<<dim3((N3 / 128) * (2048 / 256)), dim3(512), 0, stream>>>(
            Xb, CC, qw, qb, nullptr, 0, Qb, N3, 2048, N3, CC, N3 / 128);
        attn_mfma_kernel<<<dim3(BB * 3), dim3(256), 0, stream>>>(Qb, nullptr, Xb, 64, scale, BB);
        gemm_bf16_kernel<1, 0, 1, 0><<<dim3((CC / 128) * (2048 / 256)), dim3(512), 0, stream>>>(
            Xb, CC, pw, pb, OUT, LDOUT, nullptr, 0, 2048, CC, CC, CC / 128);

        // ---- stage B: windowed attention with rel-pos bias (T=50) ----
        for (int w0 = 0; w0 < NWW; w0 += cw) {
            float* outc = OUT + (size_t)w0 * LDOUT;
            int Mr = cw * NTT;
            ln_kernel<<<dim3(Mr / 4), dim3(256), 0, stream>>>(outc, CC, ln1w + i * CC, ln1b + i * CC, Xb, CC, Mr);
            gemm_bf16_kernel<1, 0, 0, 1><<<dim3((N3 / 128) * (Mr / 256)), dim3(512), 0, stream>>>(
                Xb, CC, qw, qb, nullptr, 0, Qb, N3, Mr, N3, CC, N3 / 128);
            attn_mfma_kernel<<<dim3(cw * 3), dim3(256), 0, stream>>>(Qb, biasTbuf, Xb, NTT, scale, cw);
            gemm_bf16_kernel<1, 0, 1, 0><<<dim3((CC / 128) * (Mr / 256)), dim3(512), 0, stream>>>(
                Xb, CC, pw, pb, outc, CC, nullptr, 0, Mr, CC, CC, CC / 128);
        }

        // ---- stage C: MLP ----
        for (int w0 = 0; w0 < NWW; w0 += cw) {
            float* outc = OUT + (size_t)w0 * LDOUT;
            int Mr = cw * NTT;
            ln_kernel<<<dim3(Mr / 4), dim3(256), 0, stream>>>(outc, CC, ln2w + i * CC, ln2b + i * CC, Xb, CC, Mr);
            gemm_bf16_kernel<1, 1, 0, 1><<<dim3((HIDD / 128) * (Mr / 256)), dim3(512), 0, stream>>>(
                Xb, CC, w1i, b1i, nullptr, 0, Hb, HIDD, Mr, HIDD, CC, HIDD / 128);
            gemm_bf16_kernel<1, 0, 1, 0><<<dim3((CC / 128) * (Mr / 256)), dim3(512), 0, stream>>>(
                Hb, HIDD, w2i, b2i, outc, CC, nullptr, 0, Mr, CC, HIDD, CC / 128);
        }
    }

    unpack_cls_kernel<<<dim3(BB * 6), dim3(256), 0, stream>>>(OUT, (float*)d_out);
    unpack_patch_kernel<<<dim3(BB * 56 * 6), dim3(256), 0, stream>>>(OUT, (float*)d_out + 786432);
}